// Round 3
// baseline (5995.663 us; speedup 1.0000x reference)
//
#include <hip/hip_runtime.h>

typedef unsigned short u16;

__device__ __forceinline__ float bf2f(u16 u){
  union { unsigned int i; float f; } v; v.i = ((unsigned int)u) << 16; return v.f;
}
__device__ __forceinline__ u16 f2bf(float f){
  union { float f; unsigned int u; } v; v.f = f;
  unsigned int r = (v.u + 0x7fffu + ((v.u >> 16) & 1u)) >> 16;
  return (u16)r;
}
__device__ __forceinline__ float gelu_f(float x){
  return 0.5f * x * (1.f + erff(x * 0.70710678118654752440f));
}
// flag-aware loads: fl=1 -> src is bf16, fl=0 -> src is fp32
__device__ __forceinline__ float ldw(const void* p, long i, int fl){
  return fl ? bf2f(((const u16*)p)[i]) : ((const float*)p)[i];
}
__device__ __forceinline__ float4 ldw4(const void* p, long i, int fl){
  if (fl){
    ushort4 w = *(const ushort4*)((const u16*)p + i);
    return make_float4(bf2f(w.x), bf2f(w.y), bf2f(w.z), bf2f(w.w));
  }
  return *(const float4*)((const float*)p + i);
}

// ---------------- dtype sniffer ----------------
// First n 32-bit words of desc0. bf16-packed N(0,1): bits[14:7] = low-half
// exponent, in [120,127] ~95% of words. fp32: mantissa bits -> ~3%.
__global__ __launch_bounds__(256) void k_sniff(const unsigned int* __restrict__ w,
                                               int n, int* __restrict__ flag){
  __shared__ int cnt[256];
  int c = 0;
  for (int i = threadIdx.x; i < n; i += 256){
    unsigned e = (w[i] >> 7) & 0xFFu;
    c += (e >= 120u && e <= 127u) ? 1 : 0;
  }
  cnt[threadIdx.x] = c; __syncthreads();
  for (int s = 128; s > 0; s >>= 1){
    if (threadIdx.x < s) cnt[threadIdx.x] += cnt[threadIdx.x + s];
    __syncthreads();
  }
  if (threadIdx.x == 0) *flag = (2 * cnt[0] > n) ? 1 : 0;
}

// ---------------- convert input activations -> f32 ----------------
__global__ __launch_bounds__(256) void k_cvt(const void* __restrict__ src,
                                             float* __restrict__ dst, long n,
                                             const int* __restrict__ flagp){
  int fl = *flagp;
  long i = (long)blockIdx.x * 256 + threadIdx.x;
  if (i < n) dst[i] = ldw(src, i, fl);
}

// ---- copy f32 (M x 256 contiguous) into dst[m*ldc + c] (concat helper) ----
__global__ __launch_bounds__(256) void k_copyc(const float* __restrict__ src,
                                               float* __restrict__ dst, int ldc){
  long i = (long)blockIdx.x * 256 + threadIdx.x;
  long m = i >> 8; int c = (int)(i & 255);
  dst[m * (long)ldc + c] = src[i];
}

// ---------------- generic GEMM: C = act(A) @ W^T (+bias)*oscale (+resid) ----
// A: M x K fp32 (lda), W: N x K (bf16/f32 per flag), out per outmode:
//   0: fp32 -> Cf    1: (unused)    2: dynamic -> fl ? bf16 Cb : fp32 Cf
__global__ __launch_bounds__(256) void k_gemm(
  const float* __restrict__ A, int lda, int K, int N,
  const void* __restrict__ W, const void* __restrict__ bias,
  float* __restrict__ Cf, u16* __restrict__ Cb, int ldc,
  const float* __restrict__ resid, int ldr,
  float oscale, int act_gelu, int outmode, const int* __restrict__ flagp)
{
  const int fl = *flagp;
  __shared__ float As[16][65];
  __shared__ float Bs[16][65];
  int tid = threadIdx.x;
  int m0 = blockIdx.y << 6, n0 = blockIdx.x << 6;
  int tx = tid & 15, ty = tid >> 4;
  int ar = tid >> 2;            // 0..63 (row within tile)
  int ak = (tid & 3) << 2;      // 0,4,8,12 (k within tile)
  float acc[4][4];
  #pragma unroll
  for (int i = 0; i < 4; ++i)
    #pragma unroll
    for (int j = 0; j < 4; ++j) acc[i][j] = 0.f;

  for (int k0 = 0; k0 < K; k0 += 16){
    float4 av = *(const float4*)(A + (long)(m0 + ar) * lda + k0 + ak);
    if (act_gelu){ av.x = gelu_f(av.x); av.y = gelu_f(av.y);
                   av.z = gelu_f(av.z); av.w = gelu_f(av.w); }
    As[ak+0][ar] = av.x; As[ak+1][ar] = av.y;
    As[ak+2][ar] = av.z; As[ak+3][ar] = av.w;
    int gn = n0 + ar;
    float4 bv = make_float4(0.f, 0.f, 0.f, 0.f);
    if (gn < N) bv = ldw4(W, (long)gn * K + k0 + ak, fl);
    Bs[ak+0][ar] = bv.x; Bs[ak+1][ar] = bv.y;
    Bs[ak+2][ar] = bv.z; Bs[ak+3][ar] = bv.w;
    __syncthreads();
    #pragma unroll
    for (int kk = 0; kk < 16; ++kk){
      float a[4], b[4];
      #pragma unroll
      for (int i = 0; i < 4; ++i){ a[i] = As[kk][ty + 16*i]; b[i] = Bs[kk][tx + 16*i]; }
      #pragma unroll
      for (int i = 0; i < 4; ++i)
        #pragma unroll
        for (int j = 0; j < 4; ++j) acc[i][j] += a[i] * b[j];
    }
    __syncthreads();
  }
  #pragma unroll
  for (int i = 0; i < 4; ++i){
    int gm = m0 + ty + 16*i;
    #pragma unroll
    for (int j = 0; j < 4; ++j){
      int gn = n0 + tx + 16*j;
      if (gn < N){
        float v = acc[i][j];
        if (bias) v += ldw(bias, gn, fl);
        v *= oscale;
        if (resid) v += resid[(long)gm * ldr + gn];
        long off = (long)gm * ldc + gn;
        if (outmode == 2){
          if (fl) Cb[off] = f2bf(v); else Cf[off] = v;
        } else {
          Cf[off] = v;
        }
      }
    }
  }
}

// ---------------- QKV extract + rotary ----------------
// qkv: (B,L,768) packed as (h, d, 3). pe: (2,B,1,L,64).
// outputs q,k,v: (B*H, L, 64) fp32.
__global__ __launch_bounds__(256) void k_rope(
  const float* __restrict__ qkv, const void* __restrict__ pe,
  float* __restrict__ q, float* __restrict__ k, float* __restrict__ v,
  int L, int B, int H, const int* __restrict__ flagp)
{
  int fl = *flagp;
  int tid = threadIdx.x;
  int lq = tid >> 6, d = tid & 63;
  int l = blockIdx.x * 4 + lq;
  int bh = blockIdx.y; int b = bh / H; int h = bh % H;
  const float* row = qkv + ((long)b * L + l) * 768 + h * 192;
  float qv = row[d*3+0], kv = row[d*3+1], vv = row[d*3+2];
  int dn = (d & 1) ? (d - 1) : (d + 1);
  float qn = row[dn*3+0], kn = row[dn*3+1];
  float rq = (d & 1) ? qn : -qn;   // rotate_half: even d -> -x[d+1], odd d -> x[d-1]
  float rk = (d & 1) ? kn : -kn;
  long peo = ((long)b * L + l) * 64 + d;
  float p0 = ldw(pe, peo, fl);
  float p1 = ldw(pe, (long)B * L * 64 + peo, fl);
  long o = ((long)bh * L + l) * 64 + d;
  q[o] = qv * p0 + rq * p1;
  k[o] = kv * p0 + rk * p1;
  v[o] = vv;
}

// ---------------- attention (online softmax), DH=64 ----------------
// Q/K/V rows addressed as base + b*sb + h*sh + l*sl + d.
// O written (B,L,E): ((b*L+l)*H*64 + h*64 + d).
// grid: (L/4, B*H), block 256 (4 waves; wave = one query row).
__global__ __launch_bounds__(256) void k_attn(
  const float* __restrict__ Q, long qsb, long qsh, long qsl,
  const float* __restrict__ Kp, long ksb, long ksh, long ksl,
  const float* __restrict__ Vp, long vsb, long vsh, long vsl,
  float* __restrict__ O, float scale, int L, int H)
{
  __shared__ float Kt[64][65];
  __shared__ float Vt[64][65];
  __shared__ float Qs[4][64];
  __shared__ float Ps[4][64];
  int tid = threadIdx.x;
  int qi = tid >> 6, lane = tid & 63;
  int bh = blockIdx.y; int b = bh / H; int h = bh % H;
  int iq = blockIdx.x * 4 + qi;
  Qs[qi][lane] = Q[b*qsb + h*qsh + (long)iq*qsl + lane] * scale;
  const float* Kb = Kp + b*ksb + h*ksh;
  const float* Vb = Vp + b*vsb + h*vsh;
  float m = -1e30f, lsum = 0.f, oacc = 0.f;
  int r = tid >> 2, c4 = (tid & 3) << 4;
  for (int j0 = 0; j0 < L; j0 += 64){
    const float* kr = Kb + (long)(j0 + r)*ksl + c4;
    const float* vr = Vb + (long)(j0 + r)*vsl + c4;
    #pragma unroll
    for (int u = 0; u < 4; ++u){
      float4 kv = *(const float4*)(kr + u*4);
      Kt[r][c4+u*4+0] = kv.x; Kt[r][c4+u*4+1] = kv.y;
      Kt[r][c4+u*4+2] = kv.z; Kt[r][c4+u*4+3] = kv.w;
      float4 vv = *(const float4*)(vr + u*4);
      Vt[r][c4+u*4+0] = vv.x; Vt[r][c4+u*4+1] = vv.y;
      Vt[r][c4+u*4+2] = vv.z; Vt[r][c4+u*4+3] = vv.w;
    }
    __syncthreads();
    float s = 0.f;
    #pragma unroll 16
    for (int dd = 0; dd < 64; ++dd) s += Qs[qi][dd] * Kt[lane][dd];
    float tmax = s;
    #pragma unroll
    for (int off = 32; off > 0; off >>= 1) tmax = fmaxf(tmax, __shfl_xor(tmax, off));
    float newm = fmaxf(m, tmax);
    float p = __expf(s - newm);
    float psum = p;
    #pragma unroll
    for (int off = 32; off > 0; off >>= 1) psum += __shfl_xor(psum, off);
    float f = __expf(m - newm);
    lsum = lsum * f + psum;
    oacc *= f;
    m = newm;
    Ps[qi][lane] = p;
    __syncthreads();
    float add = 0.f;
    #pragma unroll 16
    for (int jj = 0; jj < 64; ++jj) add += Ps[qi][jj] * Vt[jj][lane];
    oacc += add;
    __syncthreads();
  }
  O[((long)b*L + iq)*((long)H*64) + h*64 + lane] = oacc / lsum;
}

// ---------------- depthwise conv K=5 SAME + silu ----------------
__global__ __launch_bounds__(256) void k_conv(
  const float* __restrict__ xz, int choff, const void* __restrict__ w,
  float* __restrict__ out, int L, const int* __restrict__ flagp)
{
  int fl = *flagp;
  int c = threadIdx.x;
  int bl = blockIdx.x; int b = bl / L, l = bl % L;
  const float* base = xz + ((long)b * L) * 512 + choff + c;
  float s = 0.f;
  #pragma unroll
  for (int kk = 0; kk < 5; ++kk){
    int ll = l + kk - 2;
    if (ll >= 0 && ll < L) s += base[(long)ll * 512] * ldw(w, c*5 + kk, fl);
  }
  out[((long)b * L + l) * 256 + c] = s / (1.f + __expf(-s));   // silu
}

// ---------------- selective scan ----------------
// lane = n (16 states); 4 (b,d) groups per wave; grid 128 x 64 thr.
// dt already contains +dt_bias from the dt GEMM; reference adds dt_bias
// AGAIN inside the scan — replicated faithfully.
__global__ __launch_bounds__(64) void k_scan(
  const float* __restrict__ xc,    // (B,L,256)
  const float* __restrict__ dt,    // (B,L,256)
  const float* __restrict__ xdbl,  // (B,L,48): [16:32)=Bm, [32:48)=Cm
  const void* __restrict__ Alog,   // (256,16)
  const void* __restrict__ Dp,     // (256)
  const void* __restrict__ dtb,    // (256)
  float* __restrict__ y,           // (B,L,256)
  int L, const int* __restrict__ flagp)
{
  int fl = *flagp;
  int tid = threadIdx.x;
  int g = tid >> 4, n = tid & 15;
  int p = blockIdx.x * 4 + g;
  int b = p >> 8, d = p & 255;
  float A = -__expf(ldw(Alog, d*16 + n, fl));
  float Dv = ldw(Dp, d, fl);
  float dtbv = ldw(dtb, d, fl);
  float h = 0.f;
  const float* xcb = xc + (long)b*L*256 + d;
  const float* dtp = dt + (long)b*L*256 + d;
  const float* xdb = xdbl + (long)b*L*48;
  float* yb = y + (long)b*L*256 + d;
  for (int l = 0; l < L; ++l){
    float dtv = dtp[(long)l*256];
    float xv  = xcb[(long)l*256];
    float Bm  = xdb[l*48 + 16 + n];
    float Cm  = xdb[l*48 + 32 + n];
    float dl = dtv + dtbv;
    float delta = (dl > 20.f) ? dl : log1pf(__expf(dl));  // softplus
    float e = __expf(delta * A);
    h = e * h + (delta * xv) * Bm;
    float part = h * Cm;
    part += __shfl_xor(part, 1, 16);
    part += __shfl_xor(part, 2, 16);
    part += __shfl_xor(part, 4, 16);
    part += __shfl_xor(part, 8, 16);
    if (n == 0) yb[(long)l*256] = part + Dv * xv;
  }
}

// ---------------- LayerNorm over rows of 512 (in place) ----------------
__global__ __launch_bounds__(256) void k_ln(float* __restrict__ h,
                                            const void* __restrict__ g,
                                            const void* __restrict__ beta,
                                            const int* __restrict__ flagp)
{
  int fl = *flagp;
  int row = blockIdx.x * 4 + (threadIdx.x >> 6);
  int lane = threadIdx.x & 63;
  float* hr = h + (long)row * 512;
  float v[8]; float s = 0.f, ss = 0.f;
  #pragma unroll
  for (int i = 0; i < 8; ++i){ v[i] = hr[lane + 64*i]; s += v[i]; ss += v[i]*v[i]; }
  #pragma unroll
  for (int off = 1; off < 64; off <<= 1){ s += __shfl_xor(s, off); ss += __shfl_xor(ss, off); }
  float mean = s * (1.f/512.f);
  float var  = ss * (1.f/512.f) - mean * mean;
  float rs = rsqrtf(var + 1e-5f);
  #pragma unroll
  for (int i = 0; i < 8; ++i){
    int c = lane + 64*i;
    hr[c] = (v[i] - mean) * rs * ldw(g, c, fl) + ldw(beta, c, fl);
  }
}

extern "C" void kernel_launch(void* const* d_in, const int* in_sizes, int n_in,
                              void* d_out, int out_size, void* d_ws, size_t ws_size,
                              hipStream_t stream)
{
  const int B_ = 2, L_ = 2048, H_ = 4;
  const long BLE = (long)B_ * L_ * 256;       // 1,048,576
  int* flagp = (int*)d_ws;
  float* base = (float*)d_ws + 64;            // 256B offset for the flag slot
  // workspace layout (units of BLE floats); total 15.19 BLE ~= 63.7 MB
  float* x    = base + 0*BLE;                 // current descriptor fp32
  float* dbuf[2] = { base + 1*BLE, base + 2*BLE };
  float* cat  = base + 3*BLE;                 // 4 BLE; first 3 double as qkv
  float* qb   = base + 7*BLE;                 // also dt buffer after attn
  float* kb   = base + 8*BLE;                 // also y (scan out) after attn
  float* vb   = base + 9*BLE;
  float* ob   = base + 10*BLE;
  float* hbuf = base + 11*BLE;                // 2 BLE; xz then FFN hidden
  float* xcb  = base + 13*BLE;
  float* zcb  = base + 14*BLE;
  float* xdbl = base + 15*BLE;                // B*L*48 = 196,608 floats

  const void* in[35];
  for (int i = 0; i < 35 && i < n_in; ++i) in[i] = d_in[i];

  k_sniff<<<1, 256, 0, stream>>>((const unsigned int*)in[0], 2048, flagp);

  auto gemm = [&](const float* A, int lda, int K, int N, const void* W,
                  const void* bias, float* Cf, u16* Cb, int ldc,
                  const float* resid, int ldr, float oscale, int act, int om){
    dim3 g((N + 63) / 64, 64);   // M = 4096
    k_gemm<<<g, 256, 0, stream>>>(A, lda, K, N, W, bias, Cf, Cb, ldc,
                                  resid, ldr, oscale, act, om, flagp);
  };

  const long sbP = (long)H_ * L_ * 64, shP = (long)L_ * 64, slP = 64;   // (B,H,L,64)
  const long sbF = (long)L_ * 256,     shF = 64,            slF = 256;  // (B,L,256)

  // ---------------- per-descriptor: mamba_attention ----------------
  for (int i = 0; i < 2; ++i){
    float* d = dbuf[i];
    k_cvt<<<(int)(BLE/256), 256, 0, stream>>>(in[i], x, BLE, flagp);
    // qkv into cat[0:3BLE] (B,L,768)
    gemm(x, 256, 256, 768, in[4], in[5], cat, nullptr, 768, nullptr, 0, 1.f, 0, 0);
    k_rope<<<dim3(L_/4, B_*H_), 256, 0, stream>>>(cat, in[2+i], qb, kb, vb, L_, B_, H_, flagp);
    k_attn<<<dim3(L_/4, B_*H_), 256, 0, stream>>>(qb, sbP, shP, slP,
                                                  kb, sbP, shP, slP,
                                                  vb, sbP, shP, slP,
                                                  ob, 0.125f, L_, H_);
    // mamba two-path
    gemm(x, 256, 256, 512, in[14], nullptr, hbuf, nullptr, 512, nullptr, 0, 1.f, 0, 0); // xz
    k_conv<<<B_*L_, 256, 0, stream>>>(hbuf, 0,   in[15], xcb, L_, flagp);
    k_conv<<<B_*L_, 256, 0, stream>>>(hbuf, 256, in[16], zcb, L_, flagp);
    gemm(xcb, 256, 256, 48, in[17], nullptr, xdbl, nullptr, 48, nullptr, 0, 1.f, 0, 0);  // x_dbl
    gemm(xdbl, 48, 16, 256, in[18], in[19], qb, nullptr, 256, nullptr, 0, 1.f, 0, 0);    // dt (+bias once)
    k_scan<<<128, 64, 0, stream>>>(xcb, qb, xdbl, in[20], in[21], in[19], kb, L_, flagp);
    // concat [x | attn_proj | s_x | c_x] into cat (ld 1024)
    gemm(kb, 256, 256, 256, in[22], nullptr, cat + 512, nullptr, 1024, nullptr, 0, 1.f, 0, 0); // s_x
    gemm(zcb, 256, 256, 256, in[22], nullptr, cat + 768, nullptr, 1024, nullptr, 0, 1.f, 0, 0); // c_x
    gemm(ob, 256, 256, 256, in[6], in[7],   cat + 256, nullptr, 1024, nullptr, 0, 1.f, 0, 0);   // o proj
    k_copyc<<<(int)(BLE/256), 256, 0, stream>>>(x, cat, 1024);
    // FFN
    gemm(cat, 1024, 1024, 512, in[8], in[9], hbuf, nullptr, 512, nullptr, 0, 1.f, 0, 0);
    k_ln<<<1024, 256, 0, stream>>>(hbuf, in[10], in[11], flagp);
    gemm(hbuf, 512, 512, 256, in[12], in[13], d, nullptr, 256, x, 256, 1.f, 1, 0); // gelu(A), +resid
  }

  // ---------------- cross attention ----------------
  const float s4 = 0.35355339059327373f;  // 64^-0.25
  gemm(dbuf[0], 256, 256, 256, in[23], in[24], qb, nullptr, 256, nullptr, 0, s4, 0, 0);  // qk0
  gemm(dbuf[1], 256, 256, 256, in[23], in[24], kb, nullptr, 256, nullptr, 0, s4, 0, 0);  // qk1
  gemm(dbuf[0], 256, 256, 256, in[25], in[26], vb, nullptr, 256, nullptr, 0, 1.f, 0, 0); // v0
  gemm(dbuf[1], 256, 256, 256, in[25], in[26], ob, nullptr, 256, nullptr, 0, 1.f, 0, 0); // v1
  // m0 = softmax_j(sim) @ v1 : attn(q=qk0, k=qk1, v=v1)
  k_attn<<<dim3(L_/4, B_*H_), 256, 0, stream>>>(qb, sbF, shF, slF, kb, sbF, shF, slF,
                                                ob, sbF, shF, slF, xcb, 1.f, L_, H_);
  // m1 = softmax_i(sim) through v0 : attn(q=qk1, k=qk0, v=v0)
  k_attn<<<dim3(L_/4, B_*H_), 256, 0, stream>>>(kb, sbF, shF, slF, qb, sbF, shF, slF,
                                                vb, sbF, shF, slF, zcb, 1.f, L_, H_);
  for (int i = 0; i < 2; ++i){
    float* mi = (i == 0) ? xcb : zcb;
    k_copyc<<<(int)(BLE/256), 256, 0, stream>>>(dbuf[i], cat, 512);
    gemm(mi, 256, 256, 256, in[27], in[28], cat + 256, nullptr, 512, nullptr, 0, 1.f, 0, 0);
    gemm(cat, 512, 512, 512, in[29], in[30], hbuf, nullptr, 512, nullptr, 0, 1.f, 0, 0);
    k_ln<<<1024, 256, 0, stream>>>(hbuf, in[31], in[32], flagp);
    // dynamic-dtype output store (fl ? bf16 : fp32), aliased on d_out
    gemm(hbuf, 512, 512, 256, in[33], in[34],
         (float*)d_out + (long)i * BLE, (u16*)d_out + (long)i * BLE, 256,
         dbuf[i], 256, 1.f, 1, 2);
  }
}

// Round 4
// 3698.426 us; speedup vs baseline: 1.6211x; 1.6211x over previous
//
#include <hip/hip_runtime.h>

typedef unsigned short u16;

__device__ __forceinline__ float bf2f(u16 u){
  union { unsigned int i; float f; } v; v.i = ((unsigned int)u) << 16; return v.f;
}
__device__ __forceinline__ u16 f2bf(float f){
  union { float f; unsigned int u; } v; v.f = f;
  unsigned int r = (v.u + 0x7fffu + ((v.u >> 16) & 1u)) >> 16;
  return (u16)r;
}
__device__ __forceinline__ float gelu_f(float x){
  return 0.5f * x * (1.f + erff(x * 0.70710678118654752440f));
}
// flag-aware loads: fl=1 -> src is bf16, fl=0 -> src is fp32
__device__ __forceinline__ float ldw(const void* p, long i, int fl){
  return fl ? bf2f(((const u16*)p)[i]) : ((const float*)p)[i];
}
__device__ __forceinline__ float4 ldw4(const void* p, long i, int fl){
  if (fl){
    ushort4 w = *(const ushort4*)((const u16*)p + i);
    return make_float4(bf2f(w.x), bf2f(w.y), bf2f(w.z), bf2f(w.w));
  }
  return *(const float4*)((const float*)p + i);
}
__device__ __forceinline__ float softplus_f(float x){
  return (x > 20.f) ? x : log1pf(__expf(x));
}

// ---------------- dtype sniffer ----------------
__global__ __launch_bounds__(256) void k_sniff(const unsigned int* __restrict__ w,
                                               int n, int* __restrict__ flag){
  __shared__ int cnt[256];
  int c = 0;
  for (int i = threadIdx.x; i < n; i += 256){
    unsigned e = (w[i] >> 7) & 0xFFu;
    c += (e >= 120u && e <= 127u) ? 1 : 0;
  }
  cnt[threadIdx.x] = c; __syncthreads();
  for (int s = 128; s > 0; s >>= 1){
    if (threadIdx.x < s) cnt[threadIdx.x] += cnt[threadIdx.x + s];
    __syncthreads();
  }
  if (threadIdx.x == 0) *flag = (2 * cnt[0] > n) ? 1 : 0;
}

// ---------------- convert input activations -> f32 ----------------
__global__ __launch_bounds__(256) void k_cvt(const void* __restrict__ src,
                                             float* __restrict__ dst, long n,
                                             const int* __restrict__ flagp){
  int fl = *flagp;
  long i = (long)blockIdx.x * 256 + threadIdx.x;
  if (i < n) dst[i] = ldw(src, i, fl);
}

// ---- copy f32 (M x 256 contiguous) into dst[m*ldc + c] (concat helper) ----
__global__ __launch_bounds__(256) void k_copyc(const float* __restrict__ src,
                                               float* __restrict__ dst, int ldc){
  long i = (long)blockIdx.x * 256 + threadIdx.x;
  long m = i >> 8; int c = (int)(i & 255);
  dst[m * (long)ldc + c] = src[i];
}

// ---------------- generic GEMM: C = act(A) @ W^T (+bias)*oscale (+resid) ----
__global__ __launch_bounds__(256) void k_gemm(
  const float* __restrict__ A, int lda, int K, int N,
  const void* __restrict__ W, const void* __restrict__ bias,
  float* __restrict__ Cf, u16* __restrict__ Cb, int ldc,
  const float* __restrict__ resid, int ldr,
  float oscale, int act_gelu, int outmode, const int* __restrict__ flagp)
{
  const int fl = *flagp;
  __shared__ float As[16][65];
  __shared__ float Bs[16][65];
  int tid = threadIdx.x;
  int m0 = blockIdx.y << 6, n0 = blockIdx.x << 6;
  int tx = tid & 15, ty = tid >> 4;
  int ar = tid >> 2;            // 0..63 (row within tile)
  int ak = (tid & 3) << 2;      // 0,4,8,12 (k within tile)
  float acc[4][4];
  #pragma unroll
  for (int i = 0; i < 4; ++i)
    #pragma unroll
    for (int j = 0; j < 4; ++j) acc[i][j] = 0.f;

  for (int k0 = 0; k0 < K; k0 += 16){
    float4 av = *(const float4*)(A + (long)(m0 + ar) * lda + k0 + ak);
    if (act_gelu){ av.x = gelu_f(av.x); av.y = gelu_f(av.y);
                   av.z = gelu_f(av.z); av.w = gelu_f(av.w); }
    As[ak+0][ar] = av.x; As[ak+1][ar] = av.y;
    As[ak+2][ar] = av.z; As[ak+3][ar] = av.w;
    int gn = n0 + ar;
    float4 bv = make_float4(0.f, 0.f, 0.f, 0.f);
    if (gn < N) bv = ldw4(W, (long)gn * K + k0 + ak, fl);
    Bs[ak+0][ar] = bv.x; Bs[ak+1][ar] = bv.y;
    Bs[ak+2][ar] = bv.z; Bs[ak+3][ar] = bv.w;
    __syncthreads();
    #pragma unroll
    for (int kk = 0; kk < 16; ++kk){
      float a[4], b[4];
      #pragma unroll
      for (int i = 0; i < 4; ++i){ a[i] = As[kk][ty + 16*i]; b[i] = Bs[kk][tx + 16*i]; }
      #pragma unroll
      for (int i = 0; i < 4; ++i)
        #pragma unroll
        for (int j = 0; j < 4; ++j) acc[i][j] += a[i] * b[j];
    }
    __syncthreads();
  }
  #pragma unroll
  for (int i = 0; i < 4; ++i){
    int gm = m0 + ty + 16*i;
    #pragma unroll
    for (int j = 0; j < 4; ++j){
      int gn = n0 + tx + 16*j;
      if (gn < N){
        float v = acc[i][j];
        if (bias) v += ldw(bias, gn, fl);
        v *= oscale;
        if (resid) v += resid[(long)gm * ldr + gn];
        long off = (long)gm * ldc + gn;
        if (outmode == 2){
          if (fl) Cb[off] = f2bf(v); else Cf[off] = v;
        } else {
          Cf[off] = v;
        }
      }
    }
  }
}

// ---------------- QKV extract + rotary ----------------
__global__ __launch_bounds__(256) void k_rope(
  const float* __restrict__ qkv, const void* __restrict__ pe,
  float* __restrict__ q, float* __restrict__ k, float* __restrict__ v,
  int L, int B, int H, const int* __restrict__ flagp)
{
  int fl = *flagp;
  int tid = threadIdx.x;
  int lq = tid >> 6, d = tid & 63;
  int l = blockIdx.x * 4 + lq;
  int bh = blockIdx.y; int b = bh / H; int h = bh % H;
  const float* row = qkv + ((long)b * L + l) * 768 + h * 192;
  float qv = row[d*3+0], kv = row[d*3+1], vv = row[d*3+2];
  int dn = (d & 1) ? (d - 1) : (d + 1);
  float qn = row[dn*3+0], kn = row[dn*3+1];
  float rq = (d & 1) ? qn : -qn;
  float rk = (d & 1) ? kn : -kn;
  long peo = ((long)b * L + l) * 64 + d;
  float p0 = ldw(pe, peo, fl);
  float p1 = ldw(pe, (long)B * L * 64 + peo, fl);
  long o = ((long)bh * L + l) * 64 + d;
  q[o] = qv * p0 + rq * p1;
  k[o] = kv * p0 + rk * p1;
  v[o] = vv;
}

// ---------------- attention (online softmax), DH=64 ----------------
__global__ __launch_bounds__(256) void k_attn(
  const float* __restrict__ Q, long qsb, long qsh, long qsl,
  const float* __restrict__ Kp, long ksb, long ksh, long ksl,
  const float* __restrict__ Vp, long vsb, long vsh, long vsl,
  float* __restrict__ O, float scale, int L, int H)
{
  __shared__ float Kt[64][65];
  __shared__ float Vt[64][65];
  __shared__ float Qs[4][64];
  __shared__ float Ps[4][64];
  int tid = threadIdx.x;
  int qi = tid >> 6, lane = tid & 63;
  int bh = blockIdx.y; int b = bh / H; int h = bh % H;
  int iq = blockIdx.x * 4 + qi;
  Qs[qi][lane] = Q[b*qsb + h*qsh + (long)iq*qsl + lane] * scale;
  const float* Kb = Kp + b*ksb + h*ksh;
  const float* Vb = Vp + b*vsb + h*vsh;
  float m = -1e30f, lsum = 0.f, oacc = 0.f;
  int r = tid >> 2, c4 = (tid & 3) << 4;
  for (int j0 = 0; j0 < L; j0 += 64){
    const float* kr = Kb + (long)(j0 + r)*ksl + c4;
    const float* vr = Vb + (long)(j0 + r)*vsl + c4;
    #pragma unroll
    for (int u = 0; u < 4; ++u){
      float4 kv = *(const float4*)(kr + u*4);
      Kt[r][c4+u*4+0] = kv.x; Kt[r][c4+u*4+1] = kv.y;
      Kt[r][c4+u*4+2] = kv.z; Kt[r][c4+u*4+3] = kv.w;
      float4 vv = *(const float4*)(vr + u*4);
      Vt[r][c4+u*4+0] = vv.x; Vt[r][c4+u*4+1] = vv.y;
      Vt[r][c4+u*4+2] = vv.z; Vt[r][c4+u*4+3] = vv.w;
    }
    __syncthreads();
    float s = 0.f;
    #pragma unroll 16
    for (int dd = 0; dd < 64; ++dd) s += Qs[qi][dd] * Kt[lane][dd];
    float tmax = s;
    #pragma unroll
    for (int off = 32; off > 0; off >>= 1) tmax = fmaxf(tmax, __shfl_xor(tmax, off));
    float newm = fmaxf(m, tmax);
    float p = __expf(s - newm);
    float psum = p;
    #pragma unroll
    for (int off = 32; off > 0; off >>= 1) psum += __shfl_xor(psum, off);
    float f = __expf(m - newm);
    lsum = lsum * f + psum;
    oacc *= f;
    m = newm;
    Ps[qi][lane] = p;
    __syncthreads();
    float add = 0.f;
    #pragma unroll 16
    for (int jj = 0; jj < 64; ++jj) add += Ps[qi][jj] * Vt[jj][lane];
    oacc += add;
    __syncthreads();
  }
  O[((long)b*L + iq)*((long)H*64) + h*64 + lane] = oacc / lsum;
}

// ---------------- depthwise conv K=5 SAME + silu ----------------
__global__ __launch_bounds__(256) void k_conv(
  const float* __restrict__ xz, int choff, const void* __restrict__ w,
  float* __restrict__ out, int L, const int* __restrict__ flagp)
{
  int fl = *flagp;
  int c = threadIdx.x;
  int bl = blockIdx.x; int b = bl / L, l = bl % L;
  const float* base = xz + ((long)b * L) * 512 + choff + c;
  float s = 0.f;
  #pragma unroll
  for (int kk = 0; kk < 5; ++kk){
    int ll = l + kk - 2;
    if (ll >= 0 && ll < L) s += base[(long)ll * 512] * ldw(w, c*5 + kk, fl);
  }
  out[((long)b * L + l) * 256 + c] = s / (1.f + __expf(-s));   // silu
}

// ---------------- chunk-parallel selective scan ----------------
// Recurrence h[l] = e[l]*h[l-1] + u[l] split into NC=32 chunks of CS=64.
// Pass 1: per (b,d,n,chunk): E = prod(e), F = local scan end (h0=0).
// Pass 2: per (b,d,n): serial carry over 32 chunks -> Hin per chunk.
// Pass 3: re-run local scan seeded with Hin, emit y (reduce over n).
// dt already contains +dt_bias from the dt GEMM; reference adds dt_bias
// AGAIN inside the scan — replicated faithfully.
#define SC_CS 64
#define SC_NC 32

__global__ __launch_bounds__(256) void k_scan1(
  const float* __restrict__ xc, const float* __restrict__ dt,
  const float* __restrict__ xdbl,
  const void* __restrict__ Alog, const void* __restrict__ dtb,
  float* __restrict__ E_out, float* __restrict__ F_out,
  int L, const int* __restrict__ flagp)
{
  int fl = *flagp;
  int tid = threadIdx.x;
  int g = tid >> 4, n = tid & 15;
  int gid = blockIdx.x * 16 + g;          // (p, chunk)
  int chunk = gid & (SC_NC - 1);
  int p = gid >> 5;                        // 0..511 = (b,d)
  int b = p >> 8, d = p & 255;
  float A = -__expf(ldw(Alog, d*16 + n, fl));
  float dtbv = ldw(dtb, d, fl);
  const float* xcb = xc + (long)b*L*256 + d;
  const float* dtp = dt + (long)b*L*256 + d;
  const float* xdb = xdbl + (long)b*L*48;
  int l0 = chunk * SC_CS;
  float E = 1.f, F = 0.f;
  for (int i = 0; i < SC_CS; ++i){
    int l = l0 + i;
    float delta = softplus_f(dtp[(long)l*256] + dtbv);
    float e = __expf(delta * A);
    float u = delta * xcb[(long)l*256] * xdb[l*48 + 16 + n];
    E *= e;
    F = e * F + u;
  }
  long idx = (long)(p*16 + n) * SC_NC + chunk;
  E_out[idx] = E; F_out[idx] = F;
}

__global__ __launch_bounds__(256) void k_scan2(
  const float* __restrict__ E, const float* __restrict__ F,
  float* __restrict__ Hin)
{
  int pn = blockIdx.x * 256 + threadIdx.x;   // 0..8191
  const float* Ep = E + (long)pn * SC_NC;
  const float* Fp = F + (long)pn * SC_NC;
  float* Hp = Hin + (long)pn * SC_NC;
  float h = 0.f;
  #pragma unroll
  for (int c = 0; c < SC_NC; ++c){
    Hp[c] = h;
    h = Ep[c] * h + Fp[c];
  }
}

__global__ __launch_bounds__(256) void k_scan3(
  const float* __restrict__ xc, const float* __restrict__ dt,
  const float* __restrict__ xdbl,
  const void* __restrict__ Alog, const void* __restrict__ Dp,
  const void* __restrict__ dtb, const float* __restrict__ Hin,
  float* __restrict__ y, int L, const int* __restrict__ flagp)
{
  int fl = *flagp;
  int tid = threadIdx.x;
  int g = tid >> 4, n = tid & 15;
  int gid = blockIdx.x * 16 + g;
  int chunk = gid & (SC_NC - 1);
  int p = gid >> 5;
  int b = p >> 8, d = p & 255;
  float A = -__expf(ldw(Alog, d*16 + n, fl));
  float Dv = ldw(Dp, d, fl);
  float dtbv = ldw(dtb, d, fl);
  const float* xcb = xc + (long)b*L*256 + d;
  const float* dtp = dt + (long)b*L*256 + d;
  const float* xdb = xdbl + (long)b*L*48;
  float* yb = y + (long)b*L*256 + d;
  long idx = (long)(p*16 + n) * SC_NC + chunk;
  float h = Hin[idx];
  int l0 = chunk * SC_CS;
  for (int i = 0; i < SC_CS; ++i){
    int l = l0 + i;
    float xv = xcb[(long)l*256];
    float delta = softplus_f(dtp[(long)l*256] + dtbv);
    float e = __expf(delta * A);
    h = e * h + delta * xv * xdb[l*48 + 16 + n];
    float part = h * xdb[l*48 + 32 + n];
    part += __shfl_xor(part, 1, 16);
    part += __shfl_xor(part, 2, 16);
    part += __shfl_xor(part, 4, 16);
    part += __shfl_xor(part, 8, 16);
    if (n == 0) yb[(long)l*256] = part + Dv * xv;
  }
}

// ---------------- LayerNorm over rows of 512 (in place) ----------------
__global__ __launch_bounds__(256) void k_ln(float* __restrict__ h,
                                            const void* __restrict__ g,
                                            const void* __restrict__ beta,
                                            const int* __restrict__ flagp)
{
  int fl = *flagp;
  int row = blockIdx.x * 4 + (threadIdx.x >> 6);
  int lane = threadIdx.x & 63;
  float* hr = h + (long)row * 512;
  float v[8]; float s = 0.f, ss = 0.f;
  #pragma unroll
  for (int i = 0; i < 8; ++i){ v[i] = hr[lane + 64*i]; s += v[i]; ss += v[i]*v[i]; }
  #pragma unroll
  for (int off = 1; off < 64; off <<= 1){ s += __shfl_xor(s, off); ss += __shfl_xor(ss, off); }
  float mean = s * (1.f/512.f);
  float var  = ss * (1.f/512.f) - mean * mean;
  float rs = rsqrtf(var + 1e-5f);
  #pragma unroll
  for (int i = 0; i < 8; ++i){
    int c = lane + 64*i;
    hr[c] = (v[i] - mean) * rs * ldw(g, c, fl) + ldw(beta, c, fl);
  }
}

extern "C" void kernel_launch(void* const* d_in, const int* in_sizes, int n_in,
                              void* d_out, int out_size, void* d_ws, size_t ws_size,
                              hipStream_t stream)
{
  const int B_ = 2, L_ = 2048, H_ = 4;
  const long BLE = (long)B_ * L_ * 256;       // 1,048,576
  int* flagp = (int*)d_ws;
  float* base = (float*)d_ws + 64;            // 256B offset for the flag slot
  // workspace layout (units of BLE floats); total 15.19 BLE ~= 63.7 MB
  float* x    = base + 0*BLE;                 // current descriptor fp32
  float* dbuf[2] = { base + 1*BLE, base + 2*BLE };
  float* cat  = base + 3*BLE;                 // 4 BLE; first 3 double as qkv
  float* qb   = base + 7*BLE;                 // also dt buffer after attn
  float* kb   = base + 8*BLE;                 // also y (scan out) after attn
  float* vb   = base + 9*BLE;                 // also scan scratch (E/F/Hin)
  float* ob   = base + 10*BLE;
  float* hbuf = base + 11*BLE;                // 2 BLE; xz then FFN hidden
  float* xcb  = base + 13*BLE;
  float* zcb  = base + 14*BLE;
  float* xdbl = base + 15*BLE;                // B*L*48 = 196,608 floats

  // scan scratch aliases vb (dead between k_attn and cross-attn v0 GEMM):
  const long SCN = (long)2 * 256 * 16 * SC_NC;   // 262,144
  float* scE = vb;
  float* scF = vb + SCN;
  float* scH = vb + 2*SCN;

  const void* in[35];
  for (int i = 0; i < 35 && i < n_in; ++i) in[i] = d_in[i];

  k_sniff<<<1, 256, 0, stream>>>((const unsigned int*)in[0], 2048, flagp);

  auto gemm = [&](const float* A, int lda, int K, int N, const void* W,
                  const void* bias, float* Cf, u16* Cb, int ldc,
                  const float* resid, int ldr, float oscale, int act, int om){
    dim3 g((N + 63) / 64, 64);   // M = 4096
    k_gemm<<<g, 256, 0, stream>>>(A, lda, K, N, W, bias, Cf, Cb, ldc,
                                  resid, ldr, oscale, act, om, flagp);
  };

  const long sbP = (long)H_ * L_ * 64, shP = (long)L_ * 64, slP = 64;   // (B,H,L,64)
  const long sbF = (long)L_ * 256,     shF = 64,            slF = 256;  // (B,L,256)

  // ---------------- per-descriptor: mamba_attention ----------------
  for (int i = 0; i < 2; ++i){
    float* d = dbuf[i];
    k_cvt<<<(int)(BLE/256), 256, 0, stream>>>(in[i], x, BLE, flagp);
    // qkv into cat[0:3BLE] (B,L,768)
    gemm(x, 256, 256, 768, in[4], in[5], cat, nullptr, 768, nullptr, 0, 1.f, 0, 0);
    k_rope<<<dim3(L_/4, B_*H_), 256, 0, stream>>>(cat, in[2+i], qb, kb, vb, L_, B_, H_, flagp);
    k_attn<<<dim3(L_/4, B_*H_), 256, 0, stream>>>(qb, sbP, shP, slP,
                                                  kb, sbP, shP, slP,
                                                  vb, sbP, shP, slP,
                                                  ob, 0.125f, L_, H_);
    // mamba two-path
    gemm(x, 256, 256, 512, in[14], nullptr, hbuf, nullptr, 512, nullptr, 0, 1.f, 0, 0); // xz
    k_conv<<<B_*L_, 256, 0, stream>>>(hbuf, 0,   in[15], xcb, L_, flagp);
    k_conv<<<B_*L_, 256, 0, stream>>>(hbuf, 256, in[16], zcb, L_, flagp);
    gemm(xcb, 256, 256, 48, in[17], nullptr, xdbl, nullptr, 48, nullptr, 0, 1.f, 0, 0);  // x_dbl
    gemm(xdbl, 48, 16, 256, in[18], in[19], qb, nullptr, 256, nullptr, 0, 1.f, 0, 0);    // dt (+bias once)
    // chunk-parallel scan (y -> kb)
    k_scan1<<<1024, 256, 0, stream>>>(xcb, qb, xdbl, in[20], in[19], scE, scF, L_, flagp);
    k_scan2<<<32, 256, 0, stream>>>(scE, scF, scH);
    k_scan3<<<1024, 256, 0, stream>>>(xcb, qb, xdbl, in[20], in[21], in[19], scH, kb, L_, flagp);
    // concat [x | attn_proj | s_x | c_x] into cat (ld 1024)
    gemm(kb, 256, 256, 256, in[22], nullptr, cat + 512, nullptr, 1024, nullptr, 0, 1.f, 0, 0); // s_x
    gemm(zcb, 256, 256, 256, in[22], nullptr, cat + 768, nullptr, 1024, nullptr, 0, 1.f, 0, 0); // c_x
    gemm(ob, 256, 256, 256, in[6], in[7],   cat + 256, nullptr, 1024, nullptr, 0, 1.f, 0, 0);   // o proj
    k_copyc<<<(int)(BLE/256), 256, 0, stream>>>(x, cat, 1024);
    // FFN
    gemm(cat, 1024, 1024, 512, in[8], in[9], hbuf, nullptr, 512, nullptr, 0, 1.f, 0, 0);
    k_ln<<<1024, 256, 0, stream>>>(hbuf, in[10], in[11], flagp);
    gemm(hbuf, 512, 512, 256, in[12], in[13], d, nullptr, 256, x, 256, 1.f, 1, 0); // gelu(A), +resid
  }

  // ---------------- cross attention ----------------
  const float s4 = 0.35355339059327373f;  // 64^-0.25
  gemm(dbuf[0], 256, 256, 256, in[23], in[24], qb, nullptr, 256, nullptr, 0, s4, 0, 0);  // qk0
  gemm(dbuf[1], 256, 256, 256, in[23], in[24], kb, nullptr, 256, nullptr, 0, s4, 0, 0);  // qk1
  gemm(dbuf[0], 256, 256, 256, in[25], in[26], vb, nullptr, 256, nullptr, 0, 1.f, 0, 0); // v0
  gemm(dbuf[1], 256, 256, 256, in[25], in[26], ob, nullptr, 256, nullptr, 0, 1.f, 0, 0); // v1
  // m0 = softmax_j(sim) @ v1 : attn(q=qk0, k=qk1, v=v1)
  k_attn<<<dim3(L_/4, B_*H_), 256, 0, stream>>>(qb, sbF, shF, slF, kb, sbF, shF, slF,
                                                ob, sbF, shF, slF, xcb, 1.f, L_, H_);
  // m1 = softmax_i(sim) through v0 : attn(q=qk1, k=qk0, v=v0)
  k_attn<<<dim3(L_/4, B_*H_), 256, 0, stream>>>(kb, sbF, shF, slF, qb, sbF, shF, slF,
                                                vb, sbF, shF, slF, zcb, 1.f, L_, H_);
  for (int i = 0; i < 2; ++i){
    float* mi = (i == 0) ? xcb : zcb;
    k_copyc<<<(int)(BLE/256), 256, 0, stream>>>(dbuf[i], cat, 512);
    gemm(mi, 256, 256, 256, in[27], in[28], cat + 256, nullptr, 512, nullptr, 0, 1.f, 0, 0);
    gemm(cat, 512, 512, 512, in[29], in[30], hbuf, nullptr, 512, nullptr, 0, 1.f, 0, 0);
    k_ln<<<1024, 256, 0, stream>>>(hbuf, in[31], in[32], flagp);
    // dynamic-dtype output store (fl ? bf16 : fp32), aliased on d_out
    gemm(hbuf, 512, 512, 256, in[33], in[34],
         (float*)d_out + (long)i * BLE, (u16*)d_out + (long)i * BLE, 256,
         dbuf[i], 256, 1.f, 1, 2);
  }
}

// Round 5
// 1866.326 us; speedup vs baseline: 3.2125x; 1.9817x over previous
//
#include <hip/hip_runtime.h>

typedef unsigned short u16;
typedef short s16;
typedef s16 s16x8 __attribute__((ext_vector_type(8)));
typedef float f32x4 __attribute__((ext_vector_type(4)));

__device__ __forceinline__ float bf2f(u16 u){
  union { unsigned int i; float f; } v; v.i = ((unsigned int)u) << 16; return v.f;
}
__device__ __forceinline__ u16 f2bf(float f){
  union { float f; unsigned int u; } v; v.f = f;
  unsigned int r = (v.u + 0x7fffu + ((v.u >> 16) & 1u)) >> 16;
  return (u16)r;
}
__device__ __forceinline__ float gelu_f(float x){
  return 0.5f * x * (1.f + erff(x * 0.70710678118654752440f));
}
// flag-aware loads: fl=1 -> src is bf16, fl=0 -> src is fp32
__device__ __forceinline__ float ldw(const void* p, long i, int fl){
  return fl ? bf2f(((const u16*)p)[i]) : ((const float*)p)[i];
}
__device__ __forceinline__ float4 ldw4(const void* p, long i, int fl){
  if (fl){
    ushort4 w = *(const ushort4*)((const u16*)p + i);
    return make_float4(bf2f(w.x), bf2f(w.y), bf2f(w.z), bf2f(w.w));
  }
  return *(const float4*)((const float*)p + i);
}
__device__ __forceinline__ float softplus_f(float x){
  return (x > 20.f) ? x : log1pf(__expf(x));
}

// ---------------- dtype sniffer ----------------
__global__ __launch_bounds__(256) void k_sniff(const unsigned int* __restrict__ w,
                                               int n, int* __restrict__ flag){
  __shared__ int cnt[256];
  int c = 0;
  for (int i = threadIdx.x; i < n; i += 256){
    unsigned e = (w[i] >> 7) & 0xFFu;
    c += (e >= 120u && e <= 127u) ? 1 : 0;
  }
  cnt[threadIdx.x] = c; __syncthreads();
  for (int s = 128; s > 0; s >>= 1){
    if (threadIdx.x < s) cnt[threadIdx.x] += cnt[threadIdx.x + s];
    __syncthreads();
  }
  if (threadIdx.x == 0) *flag = (2 * cnt[0] > n) ? 1 : 0;
}

// ---------------- convert input activations -> f32 ----------------
__global__ __launch_bounds__(256) void k_cvt(const void* __restrict__ src,
                                             float* __restrict__ dst, long n,
                                             const int* __restrict__ flagp){
  int fl = *flagp;
  long i = (long)blockIdx.x * 256 + threadIdx.x;
  if (i < n) dst[i] = ldw(src, i, fl);
}

// ---- copy f32 (M x 256 contiguous) into dst[m*ldc + c] (concat helper) ----
__global__ __launch_bounds__(256) void k_copyc(const float* __restrict__ src,
                                               float* __restrict__ dst, int ldc){
  long i = (long)blockIdx.x * 256 + threadIdx.x;
  long m = i >> 8; int c = (int)(i & 255);
  dst[m * (long)ldc + c] = src[i];
}

// ---------------- generic GEMM: C = act(A) @ W^T (+bias)*oscale (+resid) ----
__global__ __launch_bounds__(256) void k_gemm(
  const float* __restrict__ A, int lda, int K, int N,
  const void* __restrict__ W, const void* __restrict__ bias,
  float* __restrict__ Cf, u16* __restrict__ Cb, int ldc,
  const float* __restrict__ resid, int ldr,
  float oscale, int act_gelu, int outmode, const int* __restrict__ flagp)
{
  const int fl = *flagp;
  __shared__ float As[16][65];
  __shared__ float Bs[16][65];
  int tid = threadIdx.x;
  int m0 = blockIdx.y << 6, n0 = blockIdx.x << 6;
  int tx = tid & 15, ty = tid >> 4;
  int ar = tid >> 2;            // 0..63 (row within tile)
  int ak = (tid & 3) << 2;      // 0,4,8,12 (k within tile)
  float acc[4][4];
  #pragma unroll
  for (int i = 0; i < 4; ++i)
    #pragma unroll
    for (int j = 0; j < 4; ++j) acc[i][j] = 0.f;

  for (int k0 = 0; k0 < K; k0 += 16){
    float4 av = *(const float4*)(A + (long)(m0 + ar) * lda + k0 + ak);
    if (act_gelu){ av.x = gelu_f(av.x); av.y = gelu_f(av.y);
                   av.z = gelu_f(av.z); av.w = gelu_f(av.w); }
    As[ak+0][ar] = av.x; As[ak+1][ar] = av.y;
    As[ak+2][ar] = av.z; As[ak+3][ar] = av.w;
    int gn = n0 + ar;
    float4 bv = make_float4(0.f, 0.f, 0.f, 0.f);
    if (gn < N) bv = ldw4(W, (long)gn * K + k0 + ak, fl);
    Bs[ak+0][ar] = bv.x; Bs[ak+1][ar] = bv.y;
    Bs[ak+2][ar] = bv.z; Bs[ak+3][ar] = bv.w;
    __syncthreads();
    #pragma unroll
    for (int kk = 0; kk < 16; ++kk){
      float a[4], b[4];
      #pragma unroll
      for (int i = 0; i < 4; ++i){ a[i] = As[kk][ty + 16*i]; b[i] = Bs[kk][tx + 16*i]; }
      #pragma unroll
      for (int i = 0; i < 4; ++i)
        #pragma unroll
        for (int j = 0; j < 4; ++j) acc[i][j] += a[i] * b[j];
    }
    __syncthreads();
  }
  #pragma unroll
  for (int i = 0; i < 4; ++i){
    int gm = m0 + ty + 16*i;
    #pragma unroll
    for (int j = 0; j < 4; ++j){
      int gn = n0 + tx + 16*j;
      if (gn < N){
        float v = acc[i][j];
        if (bias) v += ldw(bias, gn, fl);
        v *= oscale;
        if (resid) v += resid[(long)gm * ldr + gn];
        long off = (long)gm * ldc + gn;
        if (outmode == 2){
          if (fl) Cb[off] = f2bf(v); else Cf[off] = v;
        } else {
          Cf[off] = v;
        }
      }
    }
  }
}

// ---------------- QKV extract + rotary ----------------
__global__ __launch_bounds__(256) void k_rope(
  const float* __restrict__ qkv, const void* __restrict__ pe,
  float* __restrict__ q, float* __restrict__ k, float* __restrict__ v,
  int L, int B, int H, const int* __restrict__ flagp)
{
  int fl = *flagp;
  int tid = threadIdx.x;
  int lq = tid >> 6, d = tid & 63;
  int l = blockIdx.x * 4 + lq;
  int bh = blockIdx.y; int b = bh / H; int h = bh % H;
  const float* row = qkv + ((long)b * L + l) * 768 + h * 192;
  float qv = row[d*3+0], kv = row[d*3+1], vv = row[d*3+2];
  int dn = (d & 1) ? (d - 1) : (d + 1);
  float qn = row[dn*3+0], kn = row[dn*3+1];
  float rq = (d & 1) ? qn : -qn;
  float rk = (d & 1) ? kn : -kn;
  long peo = ((long)b * L + l) * 64 + d;
  float p0 = ldw(pe, peo, fl);
  float p1 = ldw(pe, (long)B * L * 64 + peo, fl);
  long o = ((long)bh * L + l) * 64 + d;
  q[o] = qv * p0 + rq * p1;
  k[o] = kv * p0 + rk * p1;
  v[o] = vv;
}

// ---------------- MFMA flash attention, DH=64 ----------------
// Block: 64 queries (4 waves x 16), iterates K/V in 64-key tiles.
// LDS pitch 72 u16 (16B-aligned rows, conflict-breaking).
// QK^T: A=Q[m=lane&15][k=quad*8+j] (b128), B=K[n=key][k contiguous] (b128).
// S in C-layout (row=quad*4+reg -> query, col=lane&15 -> key); online softmax
// row-reduce via shfl_xor 1/2/4/8 (stays inside quads). P -> LDS bf16 ->
// A-operand of PV; V stored transposed (dim-major) as B-operand.
__global__ __launch_bounds__(256) void k_attn_mfma(
  const float* __restrict__ Q, long qsb, long qsh, long qsl,
  const float* __restrict__ Kp, long ksb, long ksh, long ksl,
  const float* __restrict__ Vp, long vsb, long vsh, long vsl,
  float* __restrict__ O, float scale, int L, int H)
{
  __shared__ u16 Kt[64*72];
  __shared__ u16 Vt[64*72];
  __shared__ u16 Ps[64*72];
  __shared__ u16 Qs[64*72];
  const int tid  = threadIdx.x;
  const int w    = tid >> 6;          // wave 0..3
  const int lane = tid & 63;
  const int quad = lane >> 4;
  const int m    = lane & 15;
  const int bh = blockIdx.y, b = bh / H, h = bh % H;
  const int iq0 = blockIdx.x * 64;

  const float* Qb = Q  + b*qsb + h*qsh;
  const float* Kb = Kp + b*ksb + h*ksh;
  const float* Vb = Vp + b*vsb + h*vsh;

  // stage Q tile (64 x 64) -> Qs bf16
  {
    int row = tid >> 2, c0 = (tid & 3) << 4;
    const float* qr = Qb + (long)(iq0 + row) * qsl + c0;
    #pragma unroll
    for (int g = 0; g < 2; ++g){
      float4 a0 = *(const float4*)(qr + g*8);
      float4 a1 = *(const float4*)(qr + g*8 + 4);
      union { u16 h[8]; uint4 v; } pk;
      pk.h[0]=f2bf(a0.x); pk.h[1]=f2bf(a0.y); pk.h[2]=f2bf(a0.z); pk.h[3]=f2bf(a0.w);
      pk.h[4]=f2bf(a1.x); pk.h[5]=f2bf(a1.y); pk.h[6]=f2bf(a1.z); pk.h[7]=f2bf(a1.w);
      *(uint4*)&Qs[row*72 + c0 + g*8] = pk.v;
    }
  }
  __syncthreads();
  s16x8 aq[2];
  #pragma unroll
  for (int s = 0; s < 2; ++s)
    aq[s] = *(const s16x8*)&Qs[(w*16 + m)*72 + s*32 + quad*8];

  f32x4 o_acc[4];
  #pragma unroll
  for (int nt = 0; nt < 4; ++nt) o_acc[nt] = (f32x4){0.f,0.f,0.f,0.f};
  float mrow[4] = {-1e30f,-1e30f,-1e30f,-1e30f};
  float lrow[4] = {0.f,0.f,0.f,0.f};

  const int srow = tid >> 2, sc0 = (tid & 3) << 4;   // staging coords

  for (int j0 = 0; j0 < L; j0 += 64){
    // ---- stage K (key-major) and V^T (dim-major) ----
    {
      const float* kr = Kb + (long)(j0 + srow) * ksl + sc0;
      #pragma unroll
      for (int g = 0; g < 2; ++g){
        float4 a0 = *(const float4*)(kr + g*8);
        float4 a1 = *(const float4*)(kr + g*8 + 4);
        union { u16 h[8]; uint4 v; } pk;
        pk.h[0]=f2bf(a0.x); pk.h[1]=f2bf(a0.y); pk.h[2]=f2bf(a0.z); pk.h[3]=f2bf(a0.w);
        pk.h[4]=f2bf(a1.x); pk.h[5]=f2bf(a1.y); pk.h[6]=f2bf(a1.z); pk.h[7]=f2bf(a1.w);
        *(uint4*)&Kt[srow*72 + sc0 + g*8] = pk.v;
      }
      const float* vr = Vb + (long)(j0 + srow) * vsl + sc0;
      #pragma unroll
      for (int g = 0; g < 4; ++g){
        float4 a0 = *(const float4*)(vr + g*4);
        Vt[(sc0 + g*4 + 0)*72 + srow] = f2bf(a0.x);
        Vt[(sc0 + g*4 + 1)*72 + srow] = f2bf(a0.y);
        Vt[(sc0 + g*4 + 2)*72 + srow] = f2bf(a0.z);
        Vt[(sc0 + g*4 + 3)*72 + srow] = f2bf(a0.w);
      }
    }
    __syncthreads();

    // ---- S = scale * Q K^T  (wave's 16 queries x 64 keys) ----
    float sv[4][4];
    #pragma unroll
    for (int ct = 0; ct < 4; ++ct){
      f32x4 acc = (f32x4){0.f,0.f,0.f,0.f};
      #pragma unroll
      for (int s = 0; s < 2; ++s){
        s16x8 bk = *(const s16x8*)&Kt[(ct*16 + m)*72 + s*32 + quad*8];
        acc = __builtin_amdgcn_mfma_f32_16x16x32_bf16(aq[s], bk, acc, 0, 0, 0);
      }
      #pragma unroll
      for (int r = 0; r < 4; ++r) sv[ct][r] = acc[r] * scale;
    }

    // ---- online softmax ----
    float mn[4], alpha[4], rsum[4];
    #pragma unroll
    for (int r = 0; r < 4; ++r){
      float v0 = fmaxf(fmaxf(sv[0][r], sv[1][r]), fmaxf(sv[2][r], sv[3][r]));
      v0 = fmaxf(v0, __shfl_xor(v0, 1));
      v0 = fmaxf(v0, __shfl_xor(v0, 2));
      v0 = fmaxf(v0, __shfl_xor(v0, 4));
      v0 = fmaxf(v0, __shfl_xor(v0, 8));
      mn[r] = fmaxf(mrow[r], v0);
      alpha[r] = __expf(mrow[r] - mn[r]);
      mrow[r] = mn[r];
      rsum[r] = 0.f;
    }
    #pragma unroll
    for (int ct = 0; ct < 4; ++ct)
      #pragma unroll
      for (int r = 0; r < 4; ++r){
        float p = __expf(sv[ct][r] - mn[r]);
        sv[ct][r] = p;
        rsum[r] += p;
      }
    #pragma unroll
    for (int r = 0; r < 4; ++r){
      float s = rsum[r];
      s += __shfl_xor(s, 1);
      s += __shfl_xor(s, 2);
      s += __shfl_xor(s, 4);
      s += __shfl_xor(s, 8);
      lrow[r] = lrow[r] * alpha[r] + s;
    }
    #pragma unroll
    for (int nt = 0; nt < 4; ++nt)
      #pragma unroll
      for (int r = 0; r < 4; ++r) o_acc[nt][r] *= alpha[r];

    // P -> LDS (bf16), wave-private rows
    #pragma unroll
    for (int ct = 0; ct < 4; ++ct)
      #pragma unroll
      for (int r = 0; r < 4; ++r)
        Ps[(w*16 + quad*4 + r)*72 + ct*16 + m] = f2bf(sv[ct][r]);
    asm volatile("s_waitcnt lgkmcnt(0)" ::: "memory");   // same-wave RAW on Ps

    // ---- O += P V ----
    s16x8 ap[2];
    #pragma unroll
    for (int s = 0; s < 2; ++s)
      ap[s] = *(const s16x8*)&Ps[(w*16 + m)*72 + s*32 + quad*8];
    #pragma unroll
    for (int nt = 0; nt < 4; ++nt)
      #pragma unroll
      for (int s = 0; s < 2; ++s){
        s16x8 bv = *(const s16x8*)&Vt[(nt*16 + m)*72 + s*32 + quad*8];
        o_acc[nt] = __builtin_amdgcn_mfma_f32_16x16x32_bf16(ap[s], bv, o_acc[nt], 0, 0, 0);
      }
    __syncthreads();
  }

  // ---- epilogue ----
  #pragma unroll
  for (int r = 0; r < 4; ++r){
    int iq = iq0 + w*16 + quad*4 + r;
    float inv = 1.f / lrow[r];
    long baseo = ((long)b*L + iq)*((long)H*64) + h*64;
    #pragma unroll
    for (int nt = 0; nt < 4; ++nt)
      O[baseo + nt*16 + m] = o_acc[nt][r] * inv;
  }
}

// ---------------- depthwise conv K=5 SAME + silu ----------------
__global__ __launch_bounds__(256) void k_conv(
  const float* __restrict__ xz, int choff, const void* __restrict__ w,
  float* __restrict__ out, int L, const int* __restrict__ flagp)
{
  int fl = *flagp;
  int c = threadIdx.x;
  int bl = blockIdx.x; int b = bl / L, l = bl % L;
  const float* base = xz + ((long)b * L) * 512 + choff + c;
  float s = 0.f;
  #pragma unroll
  for (int kk = 0; kk < 5; ++kk){
    int ll = l + kk - 2;
    if (ll >= 0 && ll < L) s += base[(long)ll * 512] * ldw(w, c*5 + kk, fl);
  }
  out[((long)b * L + l) * 256 + c] = s / (1.f + __expf(-s));   // silu
}

// ---------------- chunk-parallel selective scan ----------------
#define SC_CS 64
#define SC_NC 32

__global__ __launch_bounds__(256) void k_scan1(
  const float* __restrict__ xc, const float* __restrict__ dt,
  const float* __restrict__ xdbl,
  const void* __restrict__ Alog, const void* __restrict__ dtb,
  float* __restrict__ E_out, float* __restrict__ F_out,
  int L, const int* __restrict__ flagp)
{
  int fl = *flagp;
  int tid = threadIdx.x;
  int g = tid >> 4, n = tid & 15;
  int gid = blockIdx.x * 16 + g;
  int chunk = gid & (SC_NC - 1);
  int p = gid >> 5;
  int b = p >> 8, d = p & 255;
  float A = -__expf(ldw(Alog, d*16 + n, fl));
  float dtbv = ldw(dtb, d, fl);
  const float* xcb = xc + (long)b*L*256 + d;
  const float* dtp = dt + (long)b*L*256 + d;
  const float* xdb = xdbl + (long)b*L*48;
  int l0 = chunk * SC_CS;
  float E = 1.f, F = 0.f;
  for (int i = 0; i < SC_CS; ++i){
    int l = l0 + i;
    float delta = softplus_f(dtp[(long)l*256] + dtbv);
    float e = __expf(delta * A);
    float u = delta * xcb[(long)l*256] * xdb[l*48 + 16 + n];
    E *= e;
    F = e * F + u;
  }
  long idx = (long)(p*16 + n) * SC_NC + chunk;
  E_out[idx] = E; F_out[idx] = F;
}

__global__ __launch_bounds__(256) void k_scan2(
  const float* __restrict__ E, const float* __restrict__ F,
  float* __restrict__ Hin)
{
  int pn = blockIdx.x * 256 + threadIdx.x;
  const float* Ep = E + (long)pn * SC_NC;
  const float* Fp = F + (long)pn * SC_NC;
  float* Hp = Hin + (long)pn * SC_NC;
  float h = 0.f;
  #pragma unroll
  for (int c = 0; c < SC_NC; ++c){
    Hp[c] = h;
    h = Ep[c] * h + Fp[c];
  }
}

__global__ __launch_bounds__(256) void k_scan3(
  const float* __restrict__ xc, const float* __restrict__ dt,
  const float* __restrict__ xdbl,
  const void* __restrict__ Alog, const void* __restrict__ Dp,
  const void* __restrict__ dtb, const float* __restrict__ Hin,
  float* __restrict__ y, int L, const int* __restrict__ flagp)
{
  int fl = *flagp;
  int tid = threadIdx.x;
  int g = tid >> 4, n = tid & 15;
  int gid = blockIdx.x * 16 + g;
  int chunk = gid & (SC_NC - 1);
  int p = gid >> 5;
  int b = p >> 8, d = p & 255;
  float A = -__expf(ldw(Alog, d*16 + n, fl));
  float Dv = ldw(Dp, d, fl);
  float dtbv = ldw(dtb, d, fl);
  const float* xcb = xc + (long)b*L*256 + d;
  const float* dtp = dt + (long)b*L*256 + d;
  const float* xdb = xdbl + (long)b*L*48;
  float* yb = y + (long)b*L*256 + d;
  long idx = (long)(p*16 + n) * SC_NC + chunk;
  float h = Hin[idx];
  int l0 = chunk * SC_CS;
  for (int i = 0; i < SC_CS; ++i){
    int l = l0 + i;
    float xv = xcb[(long)l*256];
    float delta = softplus_f(dtp[(long)l*256] + dtbv);
    float e = __expf(delta * A);
    h = e * h + delta * xv * xdb[l*48 + 16 + n];
    float part = h * xdb[l*48 + 32 + n];
    part += __shfl_xor(part, 1, 16);
    part += __shfl_xor(part, 2, 16);
    part += __shfl_xor(part, 4, 16);
    part += __shfl_xor(part, 8, 16);
    if (n == 0) yb[(long)l*256] = part + Dv * xv;
  }
}

// ---------------- LayerNorm over rows of 512 (in place) ----------------
__global__ __launch_bounds__(256) void k_ln(float* __restrict__ h,
                                            const void* __restrict__ g,
                                            const void* __restrict__ beta,
                                            const int* __restrict__ flagp)
{
  int fl = *flagp;
  int row = blockIdx.x * 4 + (threadIdx.x >> 6);
  int lane = threadIdx.x & 63;
  float* hr = h + (long)row * 512;
  float v[8]; float s = 0.f, ss = 0.f;
  #pragma unroll
  for (int i = 0; i < 8; ++i){ v[i] = hr[lane + 64*i]; s += v[i]; ss += v[i]*v[i]; }
  #pragma unroll
  for (int off = 1; off < 64; off <<= 1){ s += __shfl_xor(s, off); ss += __shfl_xor(ss, off); }
  float mean = s * (1.f/512.f);
  float var  = ss * (1.f/512.f) - mean * mean;
  float rs = rsqrtf(var + 1e-5f);
  #pragma unroll
  for (int i = 0; i < 8; ++i){
    int c = lane + 64*i;
    hr[c] = (v[i] - mean) * rs * ldw(g, c, fl) + ldw(beta, c, fl);
  }
}

extern "C" void kernel_launch(void* const* d_in, const int* in_sizes, int n_in,
                              void* d_out, int out_size, void* d_ws, size_t ws_size,
                              hipStream_t stream)
{
  const int B_ = 2, L_ = 2048, H_ = 4;
  const long BLE = (long)B_ * L_ * 256;       // 1,048,576
  int* flagp = (int*)d_ws;
  float* base = (float*)d_ws + 64;
  float* x    = base + 0*BLE;
  float* dbuf[2] = { base + 1*BLE, base + 2*BLE };
  float* cat  = base + 3*BLE;                 // 4 BLE; first 3 double as qkv
  float* qb   = base + 7*BLE;
  float* kb   = base + 8*BLE;
  float* vb   = base + 9*BLE;                 // also scan scratch (E/F/Hin)
  float* ob   = base + 10*BLE;
  float* hbuf = base + 11*BLE;
  float* xcb  = base + 13*BLE;
  float* zcb  = base + 14*BLE;
  float* xdbl = base + 15*BLE;

  const long SCN = (long)2 * 256 * 16 * SC_NC;
  float* scE = vb;
  float* scF = vb + SCN;
  float* scH = vb + 2*SCN;

  const void* in[35];
  for (int i = 0; i < 35 && i < n_in; ++i) in[i] = d_in[i];

  k_sniff<<<1, 256, 0, stream>>>((const unsigned int*)in[0], 2048, flagp);

  auto gemm = [&](const float* A, int lda, int K, int N, const void* W,
                  const void* bias, float* Cf, u16* Cb, int ldc,
                  const float* resid, int ldr, float oscale, int act, int om){
    dim3 g((N + 63) / 64, 64);
    k_gemm<<<g, 256, 0, stream>>>(A, lda, K, N, W, bias, Cf, Cb, ldc,
                                  resid, ldr, oscale, act, om, flagp);
  };

  const long sbP = (long)H_ * L_ * 64, shP = (long)L_ * 64, slP = 64;   // (B,H,L,64)
  const long sbF = (long)L_ * 256,     shF = 64,            slF = 256;  // (B,L,256)

  // ---------------- per-descriptor: mamba_attention ----------------
  for (int i = 0; i < 2; ++i){
    float* d = dbuf[i];
    k_cvt<<<(int)(BLE/256), 256, 0, stream>>>(in[i], x, BLE, flagp);
    gemm(x, 256, 256, 768, in[4], in[5], cat, nullptr, 768, nullptr, 0, 1.f, 0, 0);
    k_rope<<<dim3(L_/4, B_*H_), 256, 0, stream>>>(cat, in[2+i], qb, kb, vb, L_, B_, H_, flagp);
    k_attn_mfma<<<dim3(L_/64, B_*H_), 256, 0, stream>>>(qb, sbP, shP, slP,
                                                        kb, sbP, shP, slP,
                                                        vb, sbP, shP, slP,
                                                        ob, 0.125f, L_, H_);
    gemm(x, 256, 256, 512, in[14], nullptr, hbuf, nullptr, 512, nullptr, 0, 1.f, 0, 0); // xz
    k_conv<<<B_*L_, 256, 0, stream>>>(hbuf, 0,   in[15], xcb, L_, flagp);
    k_conv<<<B_*L_, 256, 0, stream>>>(hbuf, 256, in[16], zcb, L_, flagp);
    gemm(xcb, 256, 256, 48, in[17], nullptr, xdbl, nullptr, 48, nullptr, 0, 1.f, 0, 0);
    gemm(xdbl, 48, 16, 256, in[18], in[19], qb, nullptr, 256, nullptr, 0, 1.f, 0, 0);
    k_scan1<<<1024, 256, 0, stream>>>(xcb, qb, xdbl, in[20], in[19], scE, scF, L_, flagp);
    k_scan2<<<32, 256, 0, stream>>>(scE, scF, scH);
    k_scan3<<<1024, 256, 0, stream>>>(xcb, qb, xdbl, in[20], in[21], in[19], scH, kb, L_, flagp);
    gemm(kb, 256, 256, 256, in[22], nullptr, cat + 512, nullptr, 1024, nullptr, 0, 1.f, 0, 0);
    gemm(zcb, 256, 256, 256, in[22], nullptr, cat + 768, nullptr, 1024, nullptr, 0, 1.f, 0, 0);
    gemm(ob, 256, 256, 256, in[6], in[7],   cat + 256, nullptr, 1024, nullptr, 0, 1.f, 0, 0);
    k_copyc<<<(int)(BLE/256), 256, 0, stream>>>(x, cat, 1024);
    gemm(cat, 1024, 1024, 512, in[8], in[9], hbuf, nullptr, 512, nullptr, 0, 1.f, 0, 0);
    k_ln<<<1024, 256, 0, stream>>>(hbuf, in[10], in[11], flagp);
    gemm(hbuf, 512, 512, 256, in[12], in[13], d, nullptr, 256, x, 256, 1.f, 1, 0);
  }

  // ---------------- cross attention ----------------
  const float s4 = 0.35355339059327373f;  // 64^-0.25
  gemm(dbuf[0], 256, 256, 256, in[23], in[24], qb, nullptr, 256, nullptr, 0, s4, 0, 0);
  gemm(dbuf[1], 256, 256, 256, in[23], in[24], kb, nullptr, 256, nullptr, 0, s4, 0, 0);
  gemm(dbuf[0], 256, 256, 256, in[25], in[26], vb, nullptr, 256, nullptr, 0, 1.f, 0, 0);
  gemm(dbuf[1], 256, 256, 256, in[25], in[26], ob, nullptr, 256, nullptr, 0, 1.f, 0, 0);
  k_attn_mfma<<<dim3(L_/64, B_*H_), 256, 0, stream>>>(qb, sbF, shF, slF, kb, sbF, shF, slF,
                                                      ob, sbF, shF, slF, xcb, 1.f, L_, H_);
  k_attn_mfma<<<dim3(L_/64, B_*H_), 256, 0, stream>>>(kb, sbF, shF, slF, qb, sbF, shF, slF,
                                                      vb, sbF, shF, slF, zcb, 1.f, L_, H_);
  for (int i = 0; i < 2; ++i){
    float* mi = (i == 0) ? xcb : zcb;
    k_copyc<<<(int)(BLE/256), 256, 0, stream>>>(dbuf[i], cat, 512);
    gemm(mi, 256, 256, 256, in[27], in[28], cat + 256, nullptr, 512, nullptr, 0, 1.f, 0, 0);
    gemm(cat, 512, 512, 512, in[29], in[30], hbuf, nullptr, 512, nullptr, 0, 1.f, 0, 0);
    k_ln<<<1024, 256, 0, stream>>>(hbuf, in[31], in[32], flagp);
    gemm(hbuf, 512, 512, 256, in[33], in[34],
         (float*)d_out + (long)i * BLE, (u16*)d_out + (long)i * BLE, 256,
         dbuf[i], 256, 1.f, 1, 2);
  }
}

// Round 6
// 1358.836 us; speedup vs baseline: 4.4124x; 1.3735x over previous
//
#include <hip/hip_runtime.h>

typedef unsigned short u16;
typedef short s16;
typedef s16 s16x8 __attribute__((ext_vector_type(8)));
typedef float f32x4 __attribute__((ext_vector_type(4)));

__device__ __forceinline__ float bf2f(u16 u){
  union { unsigned int i; float f; } v; v.i = ((unsigned int)u) << 16; return v.f;
}
__device__ __forceinline__ u16 f2bf(float f){
  union { float f; unsigned int u; } v; v.f = f;
  unsigned int r = (v.u + 0x7fffu + ((v.u >> 16) & 1u)) >> 16;
  return (u16)r;
}
__device__ __forceinline__ float gelu_f(float x){
  return 0.5f * x * (1.f + erff(x * 0.70710678118654752440f));
}
// flag-aware loads: fl=1 -> src is bf16, fl=0 -> src is fp32
__device__ __forceinline__ float ldw(const void* p, long i, int fl){
  return fl ? bf2f(((const u16*)p)[i]) : ((const float*)p)[i];
}
__device__ __forceinline__ float4 ldw4(const void* p, long i, int fl){
  if (fl){
    ushort4 w = *(const ushort4*)((const u16*)p + i);
    return make_float4(bf2f(w.x), bf2f(w.y), bf2f(w.z), bf2f(w.w));
  }
  return *(const float4*)((const float*)p + i);
}
__device__ __forceinline__ float softplus_f(float x){
  return (x > 20.f) ? x : log1pf(__expf(x));
}

// ---------------- dtype sniffer ----------------
__global__ __launch_bounds__(256) void k_sniff(const unsigned int* __restrict__ w,
                                               int n, int* __restrict__ flag){
  __shared__ int cnt[256];
  int c = 0;
  for (int i = threadIdx.x; i < n; i += 256){
    unsigned e = (w[i] >> 7) & 0xFFu;
    c += (e >= 120u && e <= 127u) ? 1 : 0;
  }
  cnt[threadIdx.x] = c; __syncthreads();
  for (int s = 128; s > 0; s >>= 1){
    if (threadIdx.x < s) cnt[threadIdx.x] += cnt[threadIdx.x + s];
    __syncthreads();
  }
  if (threadIdx.x == 0) *flag = (2 * cnt[0] > n) ? 1 : 0;
}

// ---------------- convert input activations -> f32 ----------------
__global__ __launch_bounds__(256) void k_cvt(const void* __restrict__ src,
                                             float* __restrict__ dst, long n,
                                             const int* __restrict__ flagp){
  int fl = *flagp;
  long i = (long)blockIdx.x * 256 + threadIdx.x;
  if (i < n) dst[i] = ldw(src, i, fl);
}

// ---- copy f32 (M x 256 contiguous) into dst[m*ldc + c] (concat helper) ----
__global__ __launch_bounds__(256) void k_copyc(const float* __restrict__ src,
                                               float* __restrict__ dst, int ldc){
  long i = (long)blockIdx.x * 256 + threadIdx.x;
  long m = i >> 8; int c = (int)(i & 255);
  dst[m * (long)ldc + c] = src[i];
}

// ---------------- fallback fp32 GEMM (K or N not mult of 64) ----------------
__global__ __launch_bounds__(256) void k_gemm(
  const float* __restrict__ A, int lda, int K, int N,
  const void* __restrict__ W, const void* __restrict__ bias,
  float* __restrict__ Cf, u16* __restrict__ Cb, int ldc,
  const float* __restrict__ resid, int ldr,
  float oscale, int act_gelu, int outmode, const int* __restrict__ flagp)
{
  const int fl = *flagp;
  __shared__ float As[16][65];
  __shared__ float Bs[16][65];
  int tid = threadIdx.x;
  int m0 = blockIdx.y << 6, n0 = blockIdx.x << 6;
  int tx = tid & 15, ty = tid >> 4;
  int ar = tid >> 2;
  int ak = (tid & 3) << 2;
  float acc[4][4];
  #pragma unroll
  for (int i = 0; i < 4; ++i)
    #pragma unroll
    for (int j = 0; j < 4; ++j) acc[i][j] = 0.f;

  for (int k0 = 0; k0 < K; k0 += 16){
    float4 av = *(const float4*)(A + (long)(m0 + ar) * lda + k0 + ak);
    if (act_gelu){ av.x = gelu_f(av.x); av.y = gelu_f(av.y);
                   av.z = gelu_f(av.z); av.w = gelu_f(av.w); }
    As[ak+0][ar] = av.x; As[ak+1][ar] = av.y;
    As[ak+2][ar] = av.z; As[ak+3][ar] = av.w;
    int gn = n0 + ar;
    float4 bv = make_float4(0.f, 0.f, 0.f, 0.f);
    if (gn < N) bv = ldw4(W, (long)gn * K + k0 + ak, fl);
    Bs[ak+0][ar] = bv.x; Bs[ak+1][ar] = bv.y;
    Bs[ak+2][ar] = bv.z; Bs[ak+3][ar] = bv.w;
    __syncthreads();
    #pragma unroll
    for (int kk = 0; kk < 16; ++kk){
      float a[4], b[4];
      #pragma unroll
      for (int i = 0; i < 4; ++i){ a[i] = As[kk][ty + 16*i]; b[i] = Bs[kk][tx + 16*i]; }
      #pragma unroll
      for (int i = 0; i < 4; ++i)
        #pragma unroll
        for (int j = 0; j < 4; ++j) acc[i][j] += a[i] * b[j];
    }
    __syncthreads();
  }
  #pragma unroll
  for (int i = 0; i < 4; ++i){
    int gm = m0 + ty + 16*i;
    #pragma unroll
    for (int j = 0; j < 4; ++j){
      int gn = n0 + tx + 16*j;
      if (gn < N){
        float v = acc[i][j];
        if (bias) v += ldw(bias, gn, fl);
        v *= oscale;
        if (resid) v += resid[(long)gm * ldr + gn];
        long off = (long)gm * ldc + gn;
        if (outmode == 2){
          if (fl) Cb[off] = f2bf(v); else Cf[off] = v;
        } else {
          Cf[off] = v;
        }
      }
    }
  }
}

// ---------------- MFMA GEMM: C = act(A) @ W^T (+bias)*oscale (+resid) ----
// Requires K%64==0, N%64==0, M%64==0. 64x64 C-tile/block, 4 waves x 16 rows.
// A fp32 (round to bf16 at staging, gelu applied pre-round); W per flag.
// Same operand layout as k_attn_mfma: A[m=lane&15][k=quad*8+j],
// B[n=lane&15][k=quad*8+j], C row=quad*4+reg, col=lane&15. LDS pitch 72 u16.
__global__ __launch_bounds__(256) void k_gemm_mfma(
  const float* __restrict__ A, int lda, int K, int N,
  const void* __restrict__ W, const void* __restrict__ bias,
  float* __restrict__ Cf, u16* __restrict__ Cb, int ldc,
  const float* __restrict__ resid, int ldr,
  float oscale, int act_gelu, int outmode, const int* __restrict__ flagp)
{
  const int fl = *flagp;
  __shared__ u16 As[64*72];
  __shared__ u16 Bs[64*72];
  const int tid = threadIdx.x;
  const int w = tid >> 6, lane = tid & 63, quad = lane >> 4, m = lane & 15;
  const int m0 = blockIdx.y << 6, n0 = blockIdx.x << 6;
  const int srow = tid >> 2, sc0 = (tid & 3) << 4;

  f32x4 acc[4];
  #pragma unroll
  for (int ct = 0; ct < 4; ++ct) acc[ct] = (f32x4){0.f,0.f,0.f,0.f};

  for (int k0 = 0; k0 < K; k0 += 64){
    // stage A (64 rows x 64 k) -> bf16
    {
      const float* ar = A + (long)(m0 + srow) * lda + k0 + sc0;
      #pragma unroll
      for (int g = 0; g < 2; ++g){
        float4 a0 = *(const float4*)(ar + g*8);
        float4 a1 = *(const float4*)(ar + g*8 + 4);
        if (act_gelu){
          a0.x=gelu_f(a0.x); a0.y=gelu_f(a0.y); a0.z=gelu_f(a0.z); a0.w=gelu_f(a0.w);
          a1.x=gelu_f(a1.x); a1.y=gelu_f(a1.y); a1.z=gelu_f(a1.z); a1.w=gelu_f(a1.w);
        }
        union { u16 h[8]; uint4 v; } pk;
        pk.h[0]=f2bf(a0.x); pk.h[1]=f2bf(a0.y); pk.h[2]=f2bf(a0.z); pk.h[3]=f2bf(a0.w);
        pk.h[4]=f2bf(a1.x); pk.h[5]=f2bf(a1.y); pk.h[6]=f2bf(a1.z); pk.h[7]=f2bf(a1.w);
        *(uint4*)&As[srow*72 + sc0 + g*8] = pk.v;
      }
    }
    // stage W (64 n-rows x 64 k) -> bf16
    {
      long wb = (long)(n0 + srow) * K + k0 + sc0;
      #pragma unroll
      for (int g = 0; g < 2; ++g){
        float4 b0 = ldw4(W, wb + g*8, fl);
        float4 b1 = ldw4(W, wb + g*8 + 4, fl);
        union { u16 h[8]; uint4 v; } pk;
        pk.h[0]=f2bf(b0.x); pk.h[1]=f2bf(b0.y); pk.h[2]=f2bf(b0.z); pk.h[3]=f2bf(b0.w);
        pk.h[4]=f2bf(b1.x); pk.h[5]=f2bf(b1.y); pk.h[6]=f2bf(b1.z); pk.h[7]=f2bf(b1.w);
        *(uint4*)&Bs[srow*72 + sc0 + g*8] = pk.v;
      }
    }
    __syncthreads();

    s16x8 av[2];
    #pragma unroll
    for (int s = 0; s < 2; ++s)
      av[s] = *(const s16x8*)&As[(w*16 + m)*72 + s*32 + quad*8];
    #pragma unroll
    for (int ct = 0; ct < 4; ++ct)
      #pragma unroll
      for (int s = 0; s < 2; ++s){
        s16x8 bv = *(const s16x8*)&Bs[(ct*16 + m)*72 + s*32 + quad*8];
        acc[ct] = __builtin_amdgcn_mfma_f32_16x16x32_bf16(av[s], bv, acc[ct], 0, 0, 0);
      }
    __syncthreads();
  }

  // epilogue
  #pragma unroll
  for (int r = 0; r < 4; ++r){
    int gm = m0 + w*16 + quad*4 + r;
    #pragma unroll
    for (int ct = 0; ct < 4; ++ct){
      int gn = n0 + ct*16 + m;
      float v = acc[ct][r];
      if (bias) v += ldw(bias, gn, fl);
      v *= oscale;
      if (resid) v += resid[(long)gm * ldr + gn];
      long off = (long)gm * ldc + gn;
      if (outmode == 2){
        if (fl) Cb[off] = f2bf(v); else Cf[off] = v;
      } else {
        Cf[off] = v;
      }
    }
  }
}

// ---------------- QKV extract + rotary ----------------
__global__ __launch_bounds__(256) void k_rope(
  const float* __restrict__ qkv, const void* __restrict__ pe,
  float* __restrict__ q, float* __restrict__ k, float* __restrict__ v,
  int L, int B, int H, const int* __restrict__ flagp)
{
  int fl = *flagp;
  int tid = threadIdx.x;
  int lq = tid >> 6, d = tid & 63;
  int l = blockIdx.x * 4 + lq;
  int bh = blockIdx.y; int b = bh / H; int h = bh % H;
  const float* row = qkv + ((long)b * L + l) * 768 + h * 192;
  float qv = row[d*3+0], kv = row[d*3+1], vv = row[d*3+2];
  int dn = (d & 1) ? (d - 1) : (d + 1);
  float qn = row[dn*3+0], kn = row[dn*3+1];
  float rq = (d & 1) ? qn : -qn;
  float rk = (d & 1) ? kn : -kn;
  long peo = ((long)b * L + l) * 64 + d;
  float p0 = ldw(pe, peo, fl);
  float p1 = ldw(pe, (long)B * L * 64 + peo, fl);
  long o = ((long)bh * L + l) * 64 + d;
  q[o] = qv * p0 + rq * p1;
  k[o] = kv * p0 + rk * p1;
  v[o] = vv;
}

// ---------------- MFMA flash attention, DH=64 ----------------
__global__ __launch_bounds__(256) void k_attn_mfma(
  const float* __restrict__ Q, long qsb, long qsh, long qsl,
  const float* __restrict__ Kp, long ksb, long ksh, long ksl,
  const float* __restrict__ Vp, long vsb, long vsh, long vsl,
  float* __restrict__ O, float scale, int L, int H)
{
  __shared__ u16 Kt[64*72];
  __shared__ u16 Vt[64*72];
  __shared__ u16 Ps[64*72];
  __shared__ u16 Qs[64*72];
  const int tid  = threadIdx.x;
  const int w    = tid >> 6;
  const int lane = tid & 63;
  const int quad = lane >> 4;
  const int m    = lane & 15;
  const int bh = blockIdx.y, b = bh / H, h = bh % H;
  const int iq0 = blockIdx.x * 64;

  const float* Qb = Q  + b*qsb + h*qsh;
  const float* Kb = Kp + b*ksb + h*ksh;
  const float* Vb = Vp + b*vsb + h*vsh;

  {
    int row = tid >> 2, c0 = (tid & 3) << 4;
    const float* qr = Qb + (long)(iq0 + row) * qsl + c0;
    #pragma unroll
    for (int g = 0; g < 2; ++g){
      float4 a0 = *(const float4*)(qr + g*8);
      float4 a1 = *(const float4*)(qr + g*8 + 4);
      union { u16 h[8]; uint4 v; } pk;
      pk.h[0]=f2bf(a0.x); pk.h[1]=f2bf(a0.y); pk.h[2]=f2bf(a0.z); pk.h[3]=f2bf(a0.w);
      pk.h[4]=f2bf(a1.x); pk.h[5]=f2bf(a1.y); pk.h[6]=f2bf(a1.z); pk.h[7]=f2bf(a1.w);
      *(uint4*)&Qs[row*72 + c0 + g*8] = pk.v;
    }
  }
  __syncthreads();
  s16x8 aq[2];
  #pragma unroll
  for (int s = 0; s < 2; ++s)
    aq[s] = *(const s16x8*)&Qs[(w*16 + m)*72 + s*32 + quad*8];

  f32x4 o_acc[4];
  #pragma unroll
  for (int nt = 0; nt < 4; ++nt) o_acc[nt] = (f32x4){0.f,0.f,0.f,0.f};
  float mrow[4] = {-1e30f,-1e30f,-1e30f,-1e30f};
  float lrow[4] = {0.f,0.f,0.f,0.f};

  const int srow = tid >> 2, sc0 = (tid & 3) << 4;

  for (int j0 = 0; j0 < L; j0 += 64){
    {
      const float* kr = Kb + (long)(j0 + srow) * ksl + sc0;
      #pragma unroll
      for (int g = 0; g < 2; ++g){
        float4 a0 = *(const float4*)(kr + g*8);
        float4 a1 = *(const float4*)(kr + g*8 + 4);
        union { u16 h[8]; uint4 v; } pk;
        pk.h[0]=f2bf(a0.x); pk.h[1]=f2bf(a0.y); pk.h[2]=f2bf(a0.z); pk.h[3]=f2bf(a0.w);
        pk.h[4]=f2bf(a1.x); pk.h[5]=f2bf(a1.y); pk.h[6]=f2bf(a1.z); pk.h[7]=f2bf(a1.w);
        *(uint4*)&Kt[srow*72 + sc0 + g*8] = pk.v;
      }
      const float* vr = Vb + (long)(j0 + srow) * vsl + sc0;
      #pragma unroll
      for (int g = 0; g < 4; ++g){
        float4 a0 = *(const float4*)(vr + g*4);
        Vt[(sc0 + g*4 + 0)*72 + srow] = f2bf(a0.x);
        Vt[(sc0 + g*4 + 1)*72 + srow] = f2bf(a0.y);
        Vt[(sc0 + g*4 + 2)*72 + srow] = f2bf(a0.z);
        Vt[(sc0 + g*4 + 3)*72 + srow] = f2bf(a0.w);
      }
    }
    __syncthreads();

    float sv[4][4];
    #pragma unroll
    for (int ct = 0; ct < 4; ++ct){
      f32x4 acc = (f32x4){0.f,0.f,0.f,0.f};
      #pragma unroll
      for (int s = 0; s < 2; ++s){
        s16x8 bk = *(const s16x8*)&Kt[(ct*16 + m)*72 + s*32 + quad*8];
        acc = __builtin_amdgcn_mfma_f32_16x16x32_bf16(aq[s], bk, acc, 0, 0, 0);
      }
      #pragma unroll
      for (int r = 0; r < 4; ++r) sv[ct][r] = acc[r] * scale;
    }

    float mn[4], alpha[4], rsum[4];
    #pragma unroll
    for (int r = 0; r < 4; ++r){
      float v0 = fmaxf(fmaxf(sv[0][r], sv[1][r]), fmaxf(sv[2][r], sv[3][r]));
      v0 = fmaxf(v0, __shfl_xor(v0, 1));
      v0 = fmaxf(v0, __shfl_xor(v0, 2));
      v0 = fmaxf(v0, __shfl_xor(v0, 4));
      v0 = fmaxf(v0, __shfl_xor(v0, 8));
      mn[r] = fmaxf(mrow[r], v0);
      alpha[r] = __expf(mrow[r] - mn[r]);
      mrow[r] = mn[r];
      rsum[r] = 0.f;
    }
    #pragma unroll
    for (int ct = 0; ct < 4; ++ct)
      #pragma unroll
      for (int r = 0; r < 4; ++r){
        float p = __expf(sv[ct][r] - mn[r]);
        sv[ct][r] = p;
        rsum[r] += p;
      }
    #pragma unroll
    for (int r = 0; r < 4; ++r){
      float s = rsum[r];
      s += __shfl_xor(s, 1);
      s += __shfl_xor(s, 2);
      s += __shfl_xor(s, 4);
      s += __shfl_xor(s, 8);
      lrow[r] = lrow[r] * alpha[r] + s;
    }
    #pragma unroll
    for (int nt = 0; nt < 4; ++nt)
      #pragma unroll
      for (int r = 0; r < 4; ++r) o_acc[nt][r] *= alpha[r];

    #pragma unroll
    for (int ct = 0; ct < 4; ++ct)
      #pragma unroll
      for (int r = 0; r < 4; ++r)
        Ps[(w*16 + quad*4 + r)*72 + ct*16 + m] = f2bf(sv[ct][r]);
    asm volatile("s_waitcnt lgkmcnt(0)" ::: "memory");

    s16x8 ap[2];
    #pragma unroll
    for (int s = 0; s < 2; ++s)
      ap[s] = *(const s16x8*)&Ps[(w*16 + m)*72 + s*32 + quad*8];
    #pragma unroll
    for (int nt = 0; nt < 4; ++nt)
      #pragma unroll
      for (int s = 0; s < 2; ++s){
        s16x8 bv = *(const s16x8*)&Vt[(nt*16 + m)*72 + s*32 + quad*8];
        o_acc[nt] = __builtin_amdgcn_mfma_f32_16x16x32_bf16(ap[s], bv, o_acc[nt], 0, 0, 0);
      }
    __syncthreads();
  }

  #pragma unroll
  for (int r = 0; r < 4; ++r){
    int iq = iq0 + w*16 + quad*4 + r;
    float inv = 1.f / lrow[r];
    long baseo = ((long)b*L + iq)*((long)H*64) + h*64;
    #pragma unroll
    for (int nt = 0; nt < 4; ++nt)
      O[baseo + nt*16 + m] = o_acc[nt][r] * inv;
  }
}

// ---------------- depthwise conv K=5 SAME + silu ----------------
__global__ __launch_bounds__(256) void k_conv(
  const float* __restrict__ xz, int choff, const void* __restrict__ w,
  float* __restrict__ out, int L, const int* __restrict__ flagp)
{
  int fl = *flagp;
  int c = threadIdx.x;
  int bl = blockIdx.x; int b = bl / L, l = bl % L;
  const float* base = xz + ((long)b * L) * 512 + choff + c;
  float s = 0.f;
  #pragma unroll
  for (int kk = 0; kk < 5; ++kk){
    int ll = l + kk - 2;
    if (ll >= 0 && ll < L) s += base[(long)ll * 512] * ldw(w, c*5 + kk, fl);
  }
  out[((long)b * L + l) * 256 + c] = s / (1.f + __expf(-s));   // silu
}

// ---------------- chunk-parallel selective scan ----------------
#define SC_CS 64
#define SC_NC 32

__global__ __launch_bounds__(256) void k_scan1(
  const float* __restrict__ xc, const float* __restrict__ dt,
  const float* __restrict__ xdbl,
  const void* __restrict__ Alog, const void* __restrict__ dtb,
  float* __restrict__ E_out, float* __restrict__ F_out,
  int L, const int* __restrict__ flagp)
{
  int fl = *flagp;
  int tid = threadIdx.x;
  int g = tid >> 4, n = tid & 15;
  int gid = blockIdx.x * 16 + g;
  int chunk = gid & (SC_NC - 1);
  int p = gid >> 5;
  int b = p >> 8, d = p & 255;
  float A = -__expf(ldw(Alog, d*16 + n, fl));
  float dtbv = ldw(dtb, d, fl);
  const float* xcb = xc + (long)b*L*256 + d;
  const float* dtp = dt + (long)b*L*256 + d;
  const float* xdb = xdbl + (long)b*L*48;
  int l0 = chunk * SC_CS;
  float E = 1.f, F = 0.f;
  for (int i = 0; i < SC_CS; ++i){
    int l = l0 + i;
    float delta = softplus_f(dtp[(long)l*256] + dtbv);
    float e = __expf(delta * A);
    float u = delta * xcb[(long)l*256] * xdb[l*48 + 16 + n];
    E *= e;
    F = e * F + u;
  }
  long idx = (long)(p*16 + n) * SC_NC + chunk;
  E_out[idx] = E; F_out[idx] = F;
}

__global__ __launch_bounds__(256) void k_scan2(
  const float* __restrict__ E, const float* __restrict__ F,
  float* __restrict__ Hin)
{
  int pn = blockIdx.x * 256 + threadIdx.x;
  const float* Ep = E + (long)pn * SC_NC;
  const float* Fp = F + (long)pn * SC_NC;
  float* Hp = Hin + (long)pn * SC_NC;
  float h = 0.f;
  #pragma unroll
  for (int c = 0; c < SC_NC; ++c){
    Hp[c] = h;
    h = Ep[c] * h + Fp[c];
  }
}

__global__ __launch_bounds__(256) void k_scan3(
  const float* __restrict__ xc, const float* __restrict__ dt,
  const float* __restrict__ xdbl,
  const void* __restrict__ Alog, const void* __restrict__ Dp,
  const void* __restrict__ dtb, const float* __restrict__ Hin,
  float* __restrict__ y, int L, const int* __restrict__ flagp)
{
  int fl = *flagp;
  int tid = threadIdx.x;
  int g = tid >> 4, n = tid & 15;
  int gid = blockIdx.x * 16 + g;
  int chunk = gid & (SC_NC - 1);
  int p = gid >> 5;
  int b = p >> 8, d = p & 255;
  float A = -__expf(ldw(Alog, d*16 + n, fl));
  float Dv = ldw(Dp, d, fl);
  float dtbv = ldw(dtb, d, fl);
  const float* xcb = xc + (long)b*L*256 + d;
  const float* dtp = dt + (long)b*L*256 + d;
  const float* xdb = xdbl + (long)b*L*48;
  float* yb = y + (long)b*L*256 + d;
  long idx = (long)(p*16 + n) * SC_NC + chunk;
  float h = Hin[idx];
  int l0 = chunk * SC_CS;
  for (int i = 0; i < SC_CS; ++i){
    int l = l0 + i;
    float xv = xcb[(long)l*256];
    float delta = softplus_f(dtp[(long)l*256] + dtbv);
    float e = __expf(delta * A);
    h = e * h + delta * xv * xdb[l*48 + 16 + n];
    float part = h * xdb[l*48 + 32 + n];
    part += __shfl_xor(part, 1, 16);
    part += __shfl_xor(part, 2, 16);
    part += __shfl_xor(part, 4, 16);
    part += __shfl_xor(part, 8, 16);
    if (n == 0) yb[(long)l*256] = part + Dv * xv;
  }
}

// ---------------- LayerNorm over rows of 512 (in place) ----------------
__global__ __launch_bounds__(256) void k_ln(float* __restrict__ h,
                                            const void* __restrict__ g,
                                            const void* __restrict__ beta,
                                            const int* __restrict__ flagp)
{
  int fl = *flagp;
  int row = blockIdx.x * 4 + (threadIdx.x >> 6);
  int lane = threadIdx.x & 63;
  float* hr = h + (long)row * 512;
  float v[8]; float s = 0.f, ss = 0.f;
  #pragma unroll
  for (int i = 0; i < 8; ++i){ v[i] = hr[lane + 64*i]; s += v[i]; ss += v[i]*v[i]; }
  #pragma unroll
  for (int off = 1; off < 64; off <<= 1){ s += __shfl_xor(s, off); ss += __shfl_xor(ss, off); }
  float mean = s * (1.f/512.f);
  float var  = ss * (1.f/512.f) - mean * mean;
  float rs = rsqrtf(var + 1e-5f);
  #pragma unroll
  for (int i = 0; i < 8; ++i){
    int c = lane + 64*i;
    hr[c] = (v[i] - mean) * rs * ldw(g, c, fl) + ldw(beta, c, fl);
  }
}

extern "C" void kernel_launch(void* const* d_in, const int* in_sizes, int n_in,
                              void* d_out, int out_size, void* d_ws, size_t ws_size,
                              hipStream_t stream)
{
  const int B_ = 2, L_ = 2048, H_ = 4;
  const long BLE = (long)B_ * L_ * 256;       // 1,048,576
  int* flagp = (int*)d_ws;
  float* base = (float*)d_ws + 64;
  float* x    = base + 0*BLE;
  float* dbuf[2] = { base + 1*BLE, base + 2*BLE };
  float* cat  = base + 3*BLE;                 // 4 BLE; first 3 double as qkv
  float* qb   = base + 7*BLE;
  float* kb   = base + 8*BLE;
  float* vb   = base + 9*BLE;                 // also scan scratch (E/F/Hin)
  float* ob   = base + 10*BLE;
  float* hbuf = base + 11*BLE;
  float* xcb  = base + 13*BLE;
  float* zcb  = base + 14*BLE;
  float* xdbl = base + 15*BLE;

  const long SCN = (long)2 * 256 * 16 * SC_NC;
  float* scE = vb;
  float* scF = vb + SCN;
  float* scH = vb + 2*SCN;

  const void* in[35];
  for (int i = 0; i < 35 && i < n_in; ++i) in[i] = d_in[i];

  k_sniff<<<1, 256, 0, stream>>>((const unsigned int*)in[0], 2048, flagp);

  auto gemm = [&](const float* A, int lda, int K, int N, const void* W,
                  const void* bias, float* Cf, u16* Cb, int ldc,
                  const float* resid, int ldr, float oscale, int act, int om){
    if ((K & 63) == 0 && (N & 63) == 0){
      dim3 g(N >> 6, 64);
      k_gemm_mfma<<<g, 256, 0, stream>>>(A, lda, K, N, W, bias, Cf, Cb, ldc,
                                         resid, ldr, oscale, act, om, flagp);
    } else {
      dim3 g((N + 63) / 64, 64);
      k_gemm<<<g, 256, 0, stream>>>(A, lda, K, N, W, bias, Cf, Cb, ldc,
                                    resid, ldr, oscale, act, om, flagp);
    }
  };

  const long sbP = (long)H_ * L_ * 64, shP = (long)L_ * 64, slP = 64;   // (B,H,L,64)
  const long sbF = (long)L_ * 256,     shF = 64,            slF = 256;  // (B,L,256)

  // ---------------- per-descriptor: mamba_attention ----------------
  for (int i = 0; i < 2; ++i){
    float* d = dbuf[i];
    k_cvt<<<(int)(BLE/256), 256, 0, stream>>>(in[i], x, BLE, flagp);
    gemm(x, 256, 256, 768, in[4], in[5], cat, nullptr, 768, nullptr, 0, 1.f, 0, 0);
    k_rope<<<dim3(L_/4, B_*H_), 256, 0, stream>>>(cat, in[2+i], qb, kb, vb, L_, B_, H_, flagp);
    k_attn_mfma<<<dim3(L_/64, B_*H_), 256, 0, stream>>>(qb, sbP, shP, slP,
                                                        kb, sbP, shP, slP,
                                                        vb, sbP, shP, slP,
                                                        ob, 0.125f, L_, H_);
    gemm(x, 256, 256, 512, in[14], nullptr, hbuf, nullptr, 512, nullptr, 0, 1.f, 0, 0); // xz
    k_conv<<<B_*L_, 256, 0, stream>>>(hbuf, 0,   in[15], xcb, L_, flagp);
    k_conv<<<B_*L_, 256, 0, stream>>>(hbuf, 256, in[16], zcb, L_, flagp);
    gemm(xcb, 256, 256, 48, in[17], nullptr, xdbl, nullptr, 48, nullptr, 0, 1.f, 0, 0);
    gemm(xdbl, 48, 16, 256, in[18], in[19], qb, nullptr, 256, nullptr, 0, 1.f, 0, 0);
    k_scan1<<<1024, 256, 0, stream>>>(xcb, qb, xdbl, in[20], in[19], scE, scF, L_, flagp);
    k_scan2<<<32, 256, 0, stream>>>(scE, scF, scH);
    k_scan3<<<1024, 256, 0, stream>>>(xcb, qb, xdbl, in[20], in[21], in[19], scH, kb, L_, flagp);
    gemm(kb, 256, 256, 256, in[22], nullptr, cat + 512, nullptr, 1024, nullptr, 0, 1.f, 0, 0);
    gemm(zcb, 256, 256, 256, in[22], nullptr, cat + 768, nullptr, 1024, nullptr, 0, 1.f, 0, 0);
    gemm(ob, 256, 256, 256, in[6], in[7],   cat + 256, nullptr, 1024, nullptr, 0, 1.f, 0, 0);
    k_copyc<<<(int)(BLE/256), 256, 0, stream>>>(x, cat, 1024);
    gemm(cat, 1024, 1024, 512, in[8], in[9], hbuf, nullptr, 512, nullptr, 0, 1.f, 0, 0);
    k_ln<<<1024, 256, 0, stream>>>(hbuf, in[10], in[11], flagp);
    gemm(hbuf, 512, 512, 256, in[12], in[13], d, nullptr, 256, x, 256, 1.f, 1, 0);
  }

  // ---------------- cross attention ----------------
  const float s4 = 0.35355339059327373f;  // 64^-0.25
  gemm(dbuf[0], 256, 256, 256, in[23], in[24], qb, nullptr, 256, nullptr, 0, s4, 0, 0);
  gemm(dbuf[1], 256, 256, 256, in[23], in[24], kb, nullptr, 256, nullptr, 0, s4, 0, 0);
  gemm(dbuf[0], 256, 256, 256, in[25], in[26], vb, nullptr, 256, nullptr, 0, 1.f, 0, 0);
  gemm(dbuf[1], 256, 256, 256, in[25], in[26], ob, nullptr, 256, nullptr, 0, 1.f, 0, 0);
  k_attn_mfma<<<dim3(L_/64, B_*H_), 256, 0, stream>>>(qb, sbF, shF, slF, kb, sbF, shF, slF,
                                                      ob, sbF, shF, slF, xcb, 1.f, L_, H_);
  k_attn_mfma<<<dim3(L_/64, B_*H_), 256, 0, stream>>>(kb, sbF, shF, slF, qb, sbF, shF, slF,
                                                      vb, sbF, shF, slF, zcb, 1.f, L_, H_);
  for (int i = 0; i < 2; ++i){
    float* mi = (i == 0) ? xcb : zcb;
    k_copyc<<<(int)(BLE/256), 256, 0, stream>>>(dbuf[i], cat, 512);
    gemm(mi, 256, 256, 256, in[27], in[28], cat + 256, nullptr, 512, nullptr, 0, 1.f, 0, 0);
    gemm(cat, 512, 512, 512, in[29], in[30], hbuf, nullptr, 512, nullptr, 0, 1.f, 0, 0);
    k_ln<<<1024, 256, 0, stream>>>(hbuf, in[31], in[32], flagp);
    gemm(hbuf, 512, 512, 256, in[33], in[34],
         (float*)d_out + (long)i * BLE, (u16*)d_out + (long)i * BLE, 256,
         dbuf[i], 256, 1.f, 1, 2);
  }
}

// Round 7
// 1185.482 us; speedup vs baseline: 5.0576x; 1.1462x over previous
//
#include <hip/hip_runtime.h>

typedef unsigned short u16;
typedef short s16;
typedef s16 s16x8 __attribute__((ext_vector_type(8)));
typedef float f32x4 __attribute__((ext_vector_type(4)));

__device__ __forceinline__ float bf2f(u16 u){
  union { unsigned int i; float f; } v; v.i = ((unsigned int)u) << 16; return v.f;
}
__device__ __forceinline__ u16 f2bf(float f){
  union { float f; unsigned int u; } v; v.f = f;
  unsigned int r = (v.u + 0x7fffu + ((v.u >> 16) & 1u)) >> 16;
  return (u16)r;
}
__device__ __forceinline__ float gelu_f(float x){
  return 0.5f * x * (1.f + erff(x * 0.70710678118654752440f));
}
// flag-aware loads: fl=1 -> src is bf16, fl=0 -> src is fp32
__device__ __forceinline__ float ldw(const void* p, long i, int fl){
  return fl ? bf2f(((const u16*)p)[i]) : ((const float*)p)[i];
}
__device__ __forceinline__ float4 ldw4(const void* p, long i, int fl){
  if (fl){
    ushort4 w = *(const ushort4*)((const u16*)p + i);
    return make_float4(bf2f(w.x), bf2f(w.y), bf2f(w.z), bf2f(w.w));
  }
  return *(const float4*)((const float*)p + i);
}
__device__ __forceinline__ float softplus_f(float x){
  return (x > 20.f) ? x : log1pf(__expf(x));
}

// ---------------- dtype sniffer ----------------
__global__ __launch_bounds__(256) void k_sniff(const unsigned int* __restrict__ w,
                                               int n, int* __restrict__ flag){
  __shared__ int cnt[256];
  int c = 0;
  for (int i = threadIdx.x; i < n; i += 256){
    unsigned e = (w[i] >> 7) & 0xFFu;
    c += (e >= 120u && e <= 127u) ? 1 : 0;
  }
  cnt[threadIdx.x] = c; __syncthreads();
  for (int s = 128; s > 0; s >>= 1){
    if (threadIdx.x < s) cnt[threadIdx.x] += cnt[threadIdx.x + s];
    __syncthreads();
  }
  if (threadIdx.x == 0) *flag = (2 * cnt[0] > n) ? 1 : 0;
}

// ---------------- convert input activations -> f32 ----------------
__global__ __launch_bounds__(256) void k_cvt(const void* __restrict__ src,
                                             float* __restrict__ dst, long n,
                                             const int* __restrict__ flagp){
  int fl = *flagp;
  long i = (long)blockIdx.x * 256 + threadIdx.x;
  if (i < n) dst[i] = ldw(src, i, fl);
}

// ---- copy f32 (M x 256 contiguous) into dst[m*ldc + c] (concat helper) ----
__global__ __launch_bounds__(256) void k_copyc(const float* __restrict__ src,
                                               float* __restrict__ dst, int ldc){
  long i = (long)blockIdx.x * 256 + threadIdx.x;
  long m = i >> 8; int c = (int)(i & 255);
  dst[m * (long)ldc + c] = src[i];
}

// ---------------- fallback fp32 GEMM (K or N not mult of 64) ----------------
__global__ __launch_bounds__(256) void k_gemm(
  const float* __restrict__ A, int lda, int K, int N,
  const void* __restrict__ W, const void* __restrict__ bias,
  float* __restrict__ Cf, u16* __restrict__ Cb, int ldc,
  const float* __restrict__ resid, int ldr,
  float oscale, int act_gelu, int outmode, const int* __restrict__ flagp)
{
  const int fl = *flagp;
  __shared__ float As[16][65];
  __shared__ float Bs[16][65];
  int tid = threadIdx.x;
  int m0 = blockIdx.y << 6, n0 = blockIdx.x << 6;
  int tx = tid & 15, ty = tid >> 4;
  int ar = tid >> 2;
  int ak = (tid & 3) << 2;
  float acc[4][4];
  #pragma unroll
  for (int i = 0; i < 4; ++i)
    #pragma unroll
    for (int j = 0; j < 4; ++j) acc[i][j] = 0.f;

  for (int k0 = 0; k0 < K; k0 += 16){
    float4 av = *(const float4*)(A + (long)(m0 + ar) * lda + k0 + ak);
    if (act_gelu){ av.x = gelu_f(av.x); av.y = gelu_f(av.y);
                   av.z = gelu_f(av.z); av.w = gelu_f(av.w); }
    As[ak+0][ar] = av.x; As[ak+1][ar] = av.y;
    As[ak+2][ar] = av.z; As[ak+3][ar] = av.w;
    int gn = n0 + ar;
    float4 bv = make_float4(0.f, 0.f, 0.f, 0.f);
    if (gn < N) bv = ldw4(W, (long)gn * K + k0 + ak, fl);
    Bs[ak+0][ar] = bv.x; Bs[ak+1][ar] = bv.y;
    Bs[ak+2][ar] = bv.z; Bs[ak+3][ar] = bv.w;
    __syncthreads();
    #pragma unroll
    for (int kk = 0; kk < 16; ++kk){
      float a[4], b[4];
      #pragma unroll
      for (int i = 0; i < 4; ++i){ a[i] = As[kk][ty + 16*i]; b[i] = Bs[kk][tx + 16*i]; }
      #pragma unroll
      for (int i = 0; i < 4; ++i)
        #pragma unroll
        for (int j = 0; j < 4; ++j) acc[i][j] += a[i] * b[j];
    }
    __syncthreads();
  }
  #pragma unroll
  for (int i = 0; i < 4; ++i){
    int gm = m0 + ty + 16*i;
    #pragma unroll
    for (int j = 0; j < 4; ++j){
      int gn = n0 + tx + 16*j;
      if (gn < N){
        float v = acc[i][j];
        if (bias) v += ldw(bias, gn, fl);
        v *= oscale;
        if (resid) v += resid[(long)gm * ldr + gn];
        long off = (long)gm * ldc + gn;
        if (outmode == 2){
          if (fl) Cb[off] = f2bf(v); else Cf[off] = v;
        } else {
          Cf[off] = v;
        }
      }
    }
  }
}

// ---------------- MFMA GEMM: C = act(A) @ W^T (+bias)*oscale (+resid) ----
__global__ __launch_bounds__(256) void k_gemm_mfma(
  const float* __restrict__ A, int lda, int K, int N,
  const void* __restrict__ W, const void* __restrict__ bias,
  float* __restrict__ Cf, u16* __restrict__ Cb, int ldc,
  const float* __restrict__ resid, int ldr,
  float oscale, int act_gelu, int outmode, const int* __restrict__ flagp)
{
  const int fl = *flagp;
  __shared__ u16 As[64*72];
  __shared__ u16 Bs[64*72];
  const int tid = threadIdx.x;
  const int w = tid >> 6, lane = tid & 63, quad = lane >> 4, m = lane & 15;
  const int m0 = blockIdx.y << 6, n0 = blockIdx.x << 6;
  const int srow = tid >> 2, sc0 = (tid & 3) << 4;

  f32x4 acc[4];
  #pragma unroll
  for (int ct = 0; ct < 4; ++ct) acc[ct] = (f32x4){0.f,0.f,0.f,0.f};

  for (int k0 = 0; k0 < K; k0 += 64){
    {
      const float* ar = A + (long)(m0 + srow) * lda + k0 + sc0;
      #pragma unroll
      for (int g = 0; g < 2; ++g){
        float4 a0 = *(const float4*)(ar + g*8);
        float4 a1 = *(const float4*)(ar + g*8 + 4);
        if (act_gelu){
          a0.x=gelu_f(a0.x); a0.y=gelu_f(a0.y); a0.z=gelu_f(a0.z); a0.w=gelu_f(a0.w);
          a1.x=gelu_f(a1.x); a1.y=gelu_f(a1.y); a1.z=gelu_f(a1.z); a1.w=gelu_f(a1.w);
        }
        union { u16 h[8]; uint4 v; } pk;
        pk.h[0]=f2bf(a0.x); pk.h[1]=f2bf(a0.y); pk.h[2]=f2bf(a0.z); pk.h[3]=f2bf(a0.w);
        pk.h[4]=f2bf(a1.x); pk.h[5]=f2bf(a1.y); pk.h[6]=f2bf(a1.z); pk.h[7]=f2bf(a1.w);
        *(uint4*)&As[srow*72 + sc0 + g*8] = pk.v;
      }
    }
    {
      long wb = (long)(n0 + srow) * K + k0 + sc0;
      #pragma unroll
      for (int g = 0; g < 2; ++g){
        float4 b0 = ldw4(W, wb + g*8, fl);
        float4 b1 = ldw4(W, wb + g*8 + 4, fl);
        union { u16 h[8]; uint4 v; } pk;
        pk.h[0]=f2bf(b0.x); pk.h[1]=f2bf(b0.y); pk.h[2]=f2bf(b0.z); pk.h[3]=f2bf(b0.w);
        pk.h[4]=f2bf(b1.x); pk.h[5]=f2bf(b1.y); pk.h[6]=f2bf(b1.z); pk.h[7]=f2bf(b1.w);
        *(uint4*)&Bs[srow*72 + sc0 + g*8] = pk.v;
      }
    }
    __syncthreads();

    s16x8 av[2];
    #pragma unroll
    for (int s = 0; s < 2; ++s)
      av[s] = *(const s16x8*)&As[(w*16 + m)*72 + s*32 + quad*8];
    #pragma unroll
    for (int ct = 0; ct < 4; ++ct)
      #pragma unroll
      for (int s = 0; s < 2; ++s){
        s16x8 bv = *(const s16x8*)&Bs[(ct*16 + m)*72 + s*32 + quad*8];
        acc[ct] = __builtin_amdgcn_mfma_f32_16x16x32_bf16(av[s], bv, acc[ct], 0, 0, 0);
      }
    __syncthreads();
  }

  #pragma unroll
  for (int r = 0; r < 4; ++r){
    int gm = m0 + w*16 + quad*4 + r;
    #pragma unroll
    for (int ct = 0; ct < 4; ++ct){
      int gn = n0 + ct*16 + m;
      float v = acc[ct][r];
      if (bias) v += ldw(bias, gn, fl);
      v *= oscale;
      if (resid) v += resid[(long)gm * ldr + gn];
      long off = (long)gm * ldc + gn;
      if (outmode == 2){
        if (fl) Cb[off] = f2bf(v); else Cf[off] = v;
      } else {
        Cf[off] = v;
      }
    }
  }
}

// ---------------- QKV extract + rotary ----------------
__global__ __launch_bounds__(256) void k_rope(
  const float* __restrict__ qkv, const void* __restrict__ pe,
  float* __restrict__ q, float* __restrict__ k, float* __restrict__ v,
  int L, int B, int H, const int* __restrict__ flagp)
{
  int fl = *flagp;
  int tid = threadIdx.x;
  int lq = tid >> 6, d = tid & 63;
  int l = blockIdx.x * 4 + lq;
  int bh = blockIdx.y; int b = bh / H; int h = bh % H;
  const float* row = qkv + ((long)b * L + l) * 768 + h * 192;
  float qv = row[d*3+0], kv = row[d*3+1], vv = row[d*3+2];
  int dn = (d & 1) ? (d - 1) : (d + 1);
  float qn = row[dn*3+0], kn = row[dn*3+1];
  float rq = (d & 1) ? qn : -qn;
  float rk = (d & 1) ? kn : -kn;
  long peo = ((long)b * L + l) * 64 + d;
  float p0 = ldw(pe, peo, fl);
  float p1 = ldw(pe, (long)B * L * 64 + peo, fl);
  long o = ((long)bh * L + l) * 64 + d;
  q[o] = qv * p0 + rq * p1;
  k[o] = kv * p0 + rk * p1;
  v[o] = vv;
}

// ---------------- MFMA flash attention with K-split, DH=64 ----------------
// grid (L/64, B*H, NZ); block z processes keys [z*kchunk, (z+1)*kchunk).
// Emits UNNORMALIZED O-partials + per-row (m,l); k_attn_comb merges.
__global__ __launch_bounds__(256) void k_attn_mfma(
  const float* __restrict__ Q, long qsb, long qsh, long qsl,
  const float* __restrict__ Kp, long ksb, long ksh, long ksl,
  const float* __restrict__ Vp, long vsb, long vsh, long vsl,
  float* __restrict__ Opart, float* __restrict__ mpart, float* __restrict__ lpart,
  float scale, int L, int H, int kchunk)
{
  __shared__ u16 Kt[64*72];
  __shared__ u16 Vt[64*72];
  __shared__ u16 Ps[64*72];
  __shared__ u16 Qs[64*72];
  const int tid  = threadIdx.x;
  const int w    = tid >> 6;
  const int lane = tid & 63;
  const int quad = lane >> 4;
  const int m    = lane & 15;
  const int bh = blockIdx.y, b = bh / H, h = bh % H;
  const int iq0 = blockIdx.x * 64;
  const int z = blockIdx.z;
  const long BHL = (long)gridDim.y * L;

  const float* Qb = Q  + b*qsb + h*qsh;
  const float* Kb = Kp + b*ksb + h*ksh;
  const float* Vb = Vp + b*vsb + h*vsh;

  {
    int row = tid >> 2, c0 = (tid & 3) << 4;
    const float* qr = Qb + (long)(iq0 + row) * qsl + c0;
    #pragma unroll
    for (int g = 0; g < 2; ++g){
      float4 a0 = *(const float4*)(qr + g*8);
      float4 a1 = *(const float4*)(qr + g*8 + 4);
      union { u16 h[8]; uint4 v; } pk;
      pk.h[0]=f2bf(a0.x); pk.h[1]=f2bf(a0.y); pk.h[2]=f2bf(a0.z); pk.h[3]=f2bf(a0.w);
      pk.h[4]=f2bf(a1.x); pk.h[5]=f2bf(a1.y); pk.h[6]=f2bf(a1.z); pk.h[7]=f2bf(a1.w);
      *(uint4*)&Qs[row*72 + c0 + g*8] = pk.v;
    }
  }
  __syncthreads();
  s16x8 aq[2];
  #pragma unroll
  for (int s = 0; s < 2; ++s)
    aq[s] = *(const s16x8*)&Qs[(w*16 + m)*72 + s*32 + quad*8];

  f32x4 o_acc[4];
  #pragma unroll
  for (int nt = 0; nt < 4; ++nt) o_acc[nt] = (f32x4){0.f,0.f,0.f,0.f};
  float mrow[4] = {-1e30f,-1e30f,-1e30f,-1e30f};
  float lrow[4] = {0.f,0.f,0.f,0.f};

  const int srow = tid >> 2, sc0 = (tid & 3) << 4;
  const int jend = (z + 1) * kchunk;

  for (int j0 = z * kchunk; j0 < jend; j0 += 64){
    {
      const float* kr = Kb + (long)(j0 + srow) * ksl + sc0;
      #pragma unroll
      for (int g = 0; g < 2; ++g){
        float4 a0 = *(const float4*)(kr + g*8);
        float4 a1 = *(const float4*)(kr + g*8 + 4);
        union { u16 h[8]; uint4 v; } pk;
        pk.h[0]=f2bf(a0.x); pk.h[1]=f2bf(a0.y); pk.h[2]=f2bf(a0.z); pk.h[3]=f2bf(a0.w);
        pk.h[4]=f2bf(a1.x); pk.h[5]=f2bf(a1.y); pk.h[6]=f2bf(a1.z); pk.h[7]=f2bf(a1.w);
        *(uint4*)&Kt[srow*72 + sc0 + g*8] = pk.v;
      }
      const float* vr = Vb + (long)(j0 + srow) * vsl + sc0;
      #pragma unroll
      for (int g = 0; g < 4; ++g){
        float4 a0 = *(const float4*)(vr + g*4);
        Vt[(sc0 + g*4 + 0)*72 + srow] = f2bf(a0.x);
        Vt[(sc0 + g*4 + 1)*72 + srow] = f2bf(a0.y);
        Vt[(sc0 + g*4 + 2)*72 + srow] = f2bf(a0.z);
        Vt[(sc0 + g*4 + 3)*72 + srow] = f2bf(a0.w);
      }
    }
    __syncthreads();

    float sv[4][4];
    #pragma unroll
    for (int ct = 0; ct < 4; ++ct){
      f32x4 acc = (f32x4){0.f,0.f,0.f,0.f};
      #pragma unroll
      for (int s = 0; s < 2; ++s){
        s16x8 bk = *(const s16x8*)&Kt[(ct*16 + m)*72 + s*32 + quad*8];
        acc = __builtin_amdgcn_mfma_f32_16x16x32_bf16(aq[s], bk, acc, 0, 0, 0);
      }
      #pragma unroll
      for (int r = 0; r < 4; ++r) sv[ct][r] = acc[r] * scale;
    }

    float mn[4], alpha[4], rsum[4];
    #pragma unroll
    for (int r = 0; r < 4; ++r){
      float v0 = fmaxf(fmaxf(sv[0][r], sv[1][r]), fmaxf(sv[2][r], sv[3][r]));
      v0 = fmaxf(v0, __shfl_xor(v0, 1));
      v0 = fmaxf(v0, __shfl_xor(v0, 2));
      v0 = fmaxf(v0, __shfl_xor(v0, 4));
      v0 = fmaxf(v0, __shfl_xor(v0, 8));
      mn[r] = fmaxf(mrow[r], v0);
      alpha[r] = __expf(mrow[r] - mn[r]);
      mrow[r] = mn[r];
      rsum[r] = 0.f;
    }
    #pragma unroll
    for (int ct = 0; ct < 4; ++ct)
      #pragma unroll
      for (int r = 0; r < 4; ++r){
        float p = __expf(sv[ct][r] - mn[r]);
        sv[ct][r] = p;
        rsum[r] += p;
      }
    #pragma unroll
    for (int r = 0; r < 4; ++r){
      float s = rsum[r];
      s += __shfl_xor(s, 1);
      s += __shfl_xor(s, 2);
      s += __shfl_xor(s, 4);
      s += __shfl_xor(s, 8);
      lrow[r] = lrow[r] * alpha[r] + s;
    }
    #pragma unroll
    for (int nt = 0; nt < 4; ++nt)
      #pragma unroll
      for (int r = 0; r < 4; ++r) o_acc[nt][r] *= alpha[r];

    #pragma unroll
    for (int ct = 0; ct < 4; ++ct)
      #pragma unroll
      for (int r = 0; r < 4; ++r)
        Ps[(w*16 + quad*4 + r)*72 + ct*16 + m] = f2bf(sv[ct][r]);
    asm volatile("s_waitcnt lgkmcnt(0)" ::: "memory");

    s16x8 ap[2];
    #pragma unroll
    for (int s = 0; s < 2; ++s)
      ap[s] = *(const s16x8*)&Ps[(w*16 + m)*72 + s*32 + quad*8];
    #pragma unroll
    for (int nt = 0; nt < 4; ++nt)
      #pragma unroll
      for (int s = 0; s < 2; ++s){
        s16x8 bv = *(const s16x8*)&Vt[(nt*16 + m)*72 + s*32 + quad*8];
        o_acc[nt] = __builtin_amdgcn_mfma_f32_16x16x32_bf16(ap[s], bv, o_acc[nt], 0, 0, 0);
      }
    __syncthreads();
  }

  // epilogue: unnormalized partials + (m,l)
  const long zOoff = (long)z * BHL * 64;
  #pragma unroll
  for (int r = 0; r < 4; ++r){
    int iq = iq0 + w*16 + quad*4 + r;
    long rowid = ((long)b*L + iq) * H + h;
    #pragma unroll
    for (int nt = 0; nt < 4; ++nt)
      Opart[zOoff + rowid*64 + nt*16 + m] = o_acc[nt][r];
    if (m == 0){
      mpart[(long)z*BHL + rowid] = mrow[r];
      lpart[(long)z*BHL + rowid] = lrow[r];
    }
  }
}

// ---------------- attention split combine ----------------
// O[i] = sum_z Opart[z][i]*exp(m_z-M) / sum_z l_z*exp(m_z-M), 4 splits.
__global__ __launch_bounds__(256) void k_attn_comb(
  const float* __restrict__ Opart, const float* __restrict__ mpart,
  const float* __restrict__ lpart, float* __restrict__ O, long BHL)
{
  long i = (long)blockIdx.x * 256 + threadIdx.x;
  long row = i >> 6;
  float m0 = mpart[row],         m1 = mpart[BHL + row];
  float m2 = mpart[2*BHL + row], m3 = mpart[3*BHL + row];
  float M = fmaxf(fmaxf(m0, m1), fmaxf(m2, m3));
  float w0 = __expf(m0 - M), w1 = __expf(m1 - M);
  float w2 = __expf(m2 - M), w3 = __expf(m3 - M);
  float T = lpart[row]*w0 + lpart[BHL+row]*w1 + lpart[2*BHL+row]*w2 + lpart[3*BHL+row]*w3;
  long N64 = BHL * 64;
  float acc = Opart[i]*w0 + Opart[N64 + i]*w1 + Opart[2*N64 + i]*w2 + Opart[3*N64 + i]*w3;
  O[i] = acc / T;
}

// ---------------- depthwise conv K=5 SAME + silu ----------------
__global__ __launch_bounds__(256) void k_conv(
  const float* __restrict__ xz, int choff, const void* __restrict__ w,
  float* __restrict__ out, int L, const int* __restrict__ flagp)
{
  int fl = *flagp;
  int c = threadIdx.x;
  int bl = blockIdx.x; int b = bl / L, l = bl % L;
  const float* base = xz + ((long)b * L) * 512 + choff + c;
  float s = 0.f;
  #pragma unroll
  for (int kk = 0; kk < 5; ++kk){
    int ll = l + kk - 2;
    if (ll >= 0 && ll < L) s += base[(long)ll * 512] * ldw(w, c*5 + kk, fl);
  }
  out[((long)b * L + l) * 256 + c] = s / (1.f + __expf(-s));   // silu
}

// ---------------- chunk-parallel selective scan ----------------
#define SC_CS 64
#define SC_NC 32

__global__ __launch_bounds__(256) void k_scan1(
  const float* __restrict__ xc, const float* __restrict__ dt,
  const float* __restrict__ xdbl,
  const void* __restrict__ Alog, const void* __restrict__ dtb,
  float* __restrict__ E_out, float* __restrict__ F_out,
  int L, const int* __restrict__ flagp)
{
  int fl = *flagp;
  int tid = threadIdx.x;
  int g = tid >> 4, n = tid & 15;
  int gid = blockIdx.x * 16 + g;
  int chunk = gid & (SC_NC - 1);
  int p = gid >> 5;
  int b = p >> 8, d = p & 255;
  float A = -__expf(ldw(Alog, d*16 + n, fl));
  float dtbv = ldw(dtb, d, fl);
  const float* xcb = xc + (long)b*L*256 + d;
  const float* dtp = dt + (long)b*L*256 + d;
  const float* xdb = xdbl + (long)b*L*48;
  int l0 = chunk * SC_CS;
  float E = 1.f, F = 0.f;
  for (int i = 0; i < SC_CS; ++i){
    int l = l0 + i;
    float delta = softplus_f(dtp[(long)l*256] + dtbv);
    float e = __expf(delta * A);
    float u = delta * xcb[(long)l*256] * xdb[l*48 + 16 + n];
    E *= e;
    F = e * F + u;
  }
  long idx = (long)(p*16 + n) * SC_NC + chunk;
  E_out[idx] = E; F_out[idx] = F;
}

__global__ __launch_bounds__(256) void k_scan2(
  const float* __restrict__ E, const float* __restrict__ F,
  float* __restrict__ Hin)
{
  int pn = blockIdx.x * 256 + threadIdx.x;
  const float* Ep = E + (long)pn * SC_NC;
  const float* Fp = F + (long)pn * SC_NC;
  float* Hp = Hin + (long)pn * SC_NC;
  float h = 0.f;
  #pragma unroll
  for (int c = 0; c < SC_NC; ++c){
    Hp[c] = h;
    h = Ep[c] * h + Fp[c];
  }
}

__global__ __launch_bounds__(256) void k_scan3(
  const float* __restrict__ xc, const float* __restrict__ dt,
  const float* __restrict__ xdbl,
  const void* __restrict__ Alog, const void* __restrict__ Dp,
  const void* __restrict__ dtb, const float* __restrict__ Hin,
  float* __restrict__ y, int L, const int* __restrict__ flagp)
{
  int fl = *flagp;
  int tid = threadIdx.x;
  int g = tid >> 4, n = tid & 15;
  int gid = blockIdx.x * 16 + g;
  int chunk = gid & (SC_NC - 1);
  int p = gid >> 5;
  int b = p >> 8, d = p & 255;
  float A = -__expf(ldw(Alog, d*16 + n, fl));
  float Dv = ldw(Dp, d, fl);
  float dtbv = ldw(dtb, d, fl);
  const float* xcb = xc + (long)b*L*256 + d;
  const float* dtp = dt + (long)b*L*256 + d;
  const float* xdb = xdbl + (long)b*L*48;
  float* yb = y + (long)b*L*256 + d;
  long idx = (long)(p*16 + n) * SC_NC + chunk;
  float h = Hin[idx];
  int l0 = chunk * SC_CS;
  for (int i = 0; i < SC_CS; ++i){
    int l = l0 + i;
    float xv = xcb[(long)l*256];
    float delta = softplus_f(dtp[(long)l*256] + dtbv);
    float e = __expf(delta * A);
    h = e * h + delta * xv * xdb[l*48 + 16 + n];
    float part = h * xdb[l*48 + 32 + n];
    part += __shfl_xor(part, 1, 16);
    part += __shfl_xor(part, 2, 16);
    part += __shfl_xor(part, 4, 16);
    part += __shfl_xor(part, 8, 16);
    if (n == 0) yb[(long)l*256] = part + Dv * xv;
  }
}

// ---------------- LayerNorm over rows of 512 (in place) ----------------
__global__ __launch_bounds__(256) void k_ln(float* __restrict__ h,
                                            const void* __restrict__ g,
                                            const void* __restrict__ beta,
                                            const int* __restrict__ flagp)
{
  int fl = *flagp;
  int row = blockIdx.x * 4 + (threadIdx.x >> 6);
  int lane = threadIdx.x & 63;
  float* hr = h + (long)row * 512;
  float v[8]; float s = 0.f, ss = 0.f;
  #pragma unroll
  for (int i = 0; i < 8; ++i){ v[i] = hr[lane + 64*i]; s += v[i]; ss += v[i]*v[i]; }
  #pragma unroll
  for (int off = 1; off < 64; off <<= 1){ s += __shfl_xor(s, off); ss += __shfl_xor(ss, off); }
  float mean = s * (1.f/512.f);
  float var  = ss * (1.f/512.f) - mean * mean;
  float rs = rsqrtf(var + 1e-5f);
  #pragma unroll
  for (int i = 0; i < 8; ++i){
    int c = lane + 64*i;
    hr[c] = (v[i] - mean) * rs * ldw(g, c, fl) + ldw(beta, c, fl);
  }
}

extern "C" void kernel_launch(void* const* d_in, const int* in_sizes, int n_in,
                              void* d_out, int out_size, void* d_ws, size_t ws_size,
                              hipStream_t stream)
{
  const int B_ = 2, L_ = 2048, H_ = 4;
  const long BLE = (long)B_ * L_ * 256;       // 1,048,576
  const long BHL = (long)B_ * H_ * L_;        // 16,384
  int* flagp = (int*)d_ws;
  float* base = (float*)d_ws + 64;
  float* x    = base + 0*BLE;
  float* dbuf[2] = { base + 1*BLE, base + 2*BLE };
  float* cat  = base + 3*BLE;                 // 4 BLE; qkv staging + attn O-partials
  float* qb   = base + 7*BLE;
  float* kb   = base + 8*BLE;
  float* vb   = base + 9*BLE;                 // also scan scratch (E/F/Hin)
  float* ob   = base + 10*BLE;
  float* hbuf = base + 11*BLE;                // 2 BLE; attn (m,l) scratch + xz/FFN hidden
  float* xcb  = base + 13*BLE;
  float* zcb  = base + 14*BLE;
  float* xdbl = base + 15*BLE;

  const long SCN = (long)2 * 256 * 16 * SC_NC;
  float* scE = vb;
  float* scF = vb + SCN;
  float* scH = vb + 2*SCN;
  float* mml = hbuf;                 // 4*BHL floats
  float* mll = hbuf + 4*BHL;         // 4*BHL floats

  const void* in[35];
  for (int i = 0; i < 35 && i < n_in; ++i) in[i] = d_in[i];

  k_sniff<<<1, 256, 0, stream>>>((const unsigned int*)in[0], 2048, flagp);

  auto gemm = [&](const float* A, int lda, int K, int N, const void* W,
                  const void* bias, float* Cf, u16* Cb, int ldc,
                  const float* resid, int ldr, float oscale, int act, int om){
    if ((K & 63) == 0 && (N & 63) == 0){
      dim3 g(N >> 6, 64);
      k_gemm_mfma<<<g, 256, 0, stream>>>(A, lda, K, N, W, bias, Cf, Cb, ldc,
                                         resid, ldr, oscale, act, om, flagp);
    } else {
      dim3 g((N + 63) / 64, 64);
      k_gemm<<<g, 256, 0, stream>>>(A, lda, K, N, W, bias, Cf, Cb, ldc,
                                    resid, ldr, oscale, act, om, flagp);
    }
  };

  const long sbP = (long)H_ * L_ * 64, shP = (long)L_ * 64, slP = 64;   // (B,H,L,64)
  const long sbF = (long)L_ * 256,     shF = 64,            slF = 256;  // (B,L,256)
  const dim3 gAttn(L_/64, B_*H_, 4);
  const int kchunk = L_ / 4;

  // ---------------- per-descriptor: mamba_attention ----------------
  for (int i = 0; i < 2; ++i){
    float* d = dbuf[i];
    k_cvt<<<(int)(BLE/256), 256, 0, stream>>>(in[i], x, BLE, flagp);
    gemm(x, 256, 256, 768, in[4], in[5], cat, nullptr, 768, nullptr, 0, 1.f, 0, 0);
    k_rope<<<dim3(L_/4, B_*H_), 256, 0, stream>>>(cat, in[2+i], qb, kb, vb, L_, B_, H_, flagp);
    k_attn_mfma<<<gAttn, 256, 0, stream>>>(qb, sbP, shP, slP,
                                           kb, sbP, shP, slP,
                                           vb, sbP, shP, slP,
                                           cat, mml, mll, 0.125f, L_, H_, kchunk);
    k_attn_comb<<<(int)(BLE/256), 256, 0, stream>>>(cat, mml, mll, ob, BHL);
    gemm(x, 256, 256, 512, in[14], nullptr, hbuf, nullptr, 512, nullptr, 0, 1.f, 0, 0); // xz
    k_conv<<<B_*L_, 256, 0, stream>>>(hbuf, 0,   in[15], xcb, L_, flagp);
    k_conv<<<B_*L_, 256, 0, stream>>>(hbuf, 256, in[16], zcb, L_, flagp);
    gemm(xcb, 256, 256, 48, in[17], nullptr, xdbl, nullptr, 48, nullptr, 0, 1.f, 0, 0);
    gemm(xdbl, 48, 16, 256, in[18], in[19], qb, nullptr, 256, nullptr, 0, 1.f, 0, 0);
    k_scan1<<<1024, 256, 0, stream>>>(xcb, qb, xdbl, in[20], in[19], scE, scF, L_, flagp);
    k_scan2<<<32, 256, 0, stream>>>(scE, scF, scH);
    k_scan3<<<1024, 256, 0, stream>>>(xcb, qb, xdbl, in[20], in[21], in[19], scH, kb, L_, flagp);
    gemm(kb, 256, 256, 256, in[22], nullptr, cat + 512, nullptr, 1024, nullptr, 0, 1.f, 0, 0);
    gemm(zcb, 256, 256, 256, in[22], nullptr, cat + 768, nullptr, 1024, nullptr, 0, 1.f, 0, 0);
    gemm(ob, 256, 256, 256, in[6], in[7],   cat + 256, nullptr, 1024, nullptr, 0, 1.f, 0, 0);
    k_copyc<<<(int)(BLE/256), 256, 0, stream>>>(x, cat, 1024);
    gemm(cat, 1024, 1024, 512, in[8], in[9], hbuf, nullptr, 512, nullptr, 0, 1.f, 0, 0);
    k_ln<<<1024, 256, 0, stream>>>(hbuf, in[10], in[11], flagp);
    gemm(hbuf, 512, 512, 256, in[12], in[13], d, nullptr, 256, x, 256, 1.f, 1, 0);
  }

  // ---------------- cross attention ----------------
  const float s4 = 0.35355339059327373f;  // 64^-0.25
  gemm(dbuf[0], 256, 256, 256, in[23], in[24], qb, nullptr, 256, nullptr, 0, s4, 0, 0);
  gemm(dbuf[1], 256, 256, 256, in[23], in[24], kb, nullptr, 256, nullptr, 0, s4, 0, 0);
  gemm(dbuf[0], 256, 256, 256, in[25], in[26], vb, nullptr, 256, nullptr, 0, 1.f, 0, 0);
  gemm(dbuf[1], 256, 256, 256, in[25], in[26], ob, nullptr, 256, nullptr, 0, 1.f, 0, 0);
  // m0 = attn(q=qk0, k=qk1, v=v1)
  k_attn_mfma<<<gAttn, 256, 0, stream>>>(qb, sbF, shF, slF, kb, sbF, shF, slF,
                                         ob, sbF, shF, slF, cat, mml, mll, 1.f, L_, H_, kchunk);
  k_attn_comb<<<(int)(BLE/256), 256, 0, stream>>>(cat, mml, mll, xcb, BHL);
  // m1 = attn(q=qk1, k=qk0, v=v0)
  k_attn_mfma<<<gAttn, 256, 0, stream>>>(kb, sbF, shF, slF, qb, sbF, shF, slF,
                                         vb, sbF, shF, slF, cat, mml, mll, 1.f, L_, H_, kchunk);
  k_attn_comb<<<(int)(BLE/256), 256, 0, stream>>>(cat, mml, mll, zcb, BHL);
  for (int i = 0; i < 2; ++i){
    float* mi = (i == 0) ? xcb : zcb;
    k_copyc<<<(int)(BLE/256), 256, 0, stream>>>(dbuf[i], cat, 512);
    gemm(mi, 256, 256, 256, in[27], in[28], cat + 256, nullptr, 512, nullptr, 0, 1.f, 0, 0);
    gemm(cat, 512, 512, 512, in[29], in[30], hbuf, nullptr, 512, nullptr, 0, 1.f, 0, 0);
    k_ln<<<1024, 256, 0, stream>>>(hbuf, in[31], in[32], flagp);
    gemm(hbuf, 512, 512, 256, in[33], in[34],
         (float*)d_out + (long)i * BLE, (u16*)d_out + (long)i * BLE, 256,
         dbuf[i], 256, 1.f, 1, 2);
  }
}

// Round 8
// 1045.808 us; speedup vs baseline: 5.7330x; 1.1336x over previous
//
#include <hip/hip_runtime.h>

typedef unsigned short u16;
typedef short s16;
typedef s16 s16x8 __attribute__((ext_vector_type(8)));
typedef float f32x4 __attribute__((ext_vector_type(4)));

__device__ __forceinline__ float bf2f(u16 u){
  union { unsigned int i; float f; } v; v.i = ((unsigned int)u) << 16; return v.f;
}
__device__ __forceinline__ u16 f2bf(float f){
  union { float f; unsigned int u; } v; v.f = f;
  unsigned int r = (v.u + 0x7fffu + ((v.u >> 16) & 1u)) >> 16;
  return (u16)r;
}
__device__ __forceinline__ float gelu_f(float x){
  return 0.5f * x * (1.f + erff(x * 0.70710678118654752440f));
}
// flag-aware loads: fl=1 -> src is bf16, fl=0 -> src is fp32
__device__ __forceinline__ float ldw(const void* p, long i, int fl){
  return fl ? bf2f(((const u16*)p)[i]) : ((const float*)p)[i];
}
__device__ __forceinline__ float4 ldw4(const void* p, long i, int fl){
  if (fl){
    ushort4 w = *(const ushort4*)((const u16*)p + i);
    return make_float4(bf2f(w.x), bf2f(w.y), bf2f(w.z), bf2f(w.w));
  }
  return *(const float4*)((const float*)p + i);
}

// ---------------- dtype sniffer ----------------
__global__ __launch_bounds__(256) void k_sniff(const unsigned int* __restrict__ w,
                                               int n, int* __restrict__ flag){
  __shared__ int cnt[256];
  int c = 0;
  for (int i = threadIdx.x; i < n; i += 256){
    unsigned e = (w[i] >> 7) & 0xFFu;
    c += (e >= 120u && e <= 127u) ? 1 : 0;
  }
  cnt[threadIdx.x] = c; __syncthreads();
  for (int s = 128; s > 0; s >>= 1){
    if (threadIdx.x < s) cnt[threadIdx.x] += cnt[threadIdx.x + s];
    __syncthreads();
  }
  if (threadIdx.x == 0) *flag = (2 * cnt[0] > n) ? 1 : 0;
}

// ---------------- convert input activations -> f32 ----------------
__global__ __launch_bounds__(256) void k_cvt(const void* __restrict__ src,
                                             float* __restrict__ dst, long n,
                                             const int* __restrict__ flagp){
  int fl = *flagp;
  long i = (long)blockIdx.x * 256 + threadIdx.x;
  if (i < n) dst[i] = ldw(src, i, fl);
}

// ---- copy f32 (M x 256 contiguous) into dst[m*ldc + c] (concat helper) ----
__global__ __launch_bounds__(256) void k_copyc(const float* __restrict__ src,
                                               float* __restrict__ dst, int ldc){
  long i = (long)blockIdx.x * 256 + threadIdx.x;
  long m = i >> 8; int c = (int)(i & 255);
  dst[m * (long)ldc + c] = src[i];
}

// ---------------- fallback fp32 GEMM (K or N not mult of 64) ----------------
__global__ __launch_bounds__(256) void k_gemm(
  const float* __restrict__ A, int lda, int K, int N,
  const void* __restrict__ W, const void* __restrict__ bias,
  float* __restrict__ Cf, u16* __restrict__ Cb, int ldc,
  const float* __restrict__ resid, int ldr,
  float oscale, int act_gelu, int outmode, const int* __restrict__ flagp)
{
  const int fl = *flagp;
  __shared__ float As[16][65];
  __shared__ float Bs[16][65];
  int tid = threadIdx.x;
  int m0 = blockIdx.y << 6, n0 = blockIdx.x << 6;
  int tx = tid & 15, ty = tid >> 4;
  int ar = tid >> 2;
  int ak = (tid & 3) << 2;
  float acc[4][4];
  #pragma unroll
  for (int i = 0; i < 4; ++i)
    #pragma unroll
    for (int j = 0; j < 4; ++j) acc[i][j] = 0.f;

  for (int k0 = 0; k0 < K; k0 += 16){
    float4 av = *(const float4*)(A + (long)(m0 + ar) * lda + k0 + ak);
    if (act_gelu){ av.x = gelu_f(av.x); av.y = gelu_f(av.y);
                   av.z = gelu_f(av.z); av.w = gelu_f(av.w); }
    As[ak+0][ar] = av.x; As[ak+1][ar] = av.y;
    As[ak+2][ar] = av.z; As[ak+3][ar] = av.w;
    int gn = n0 + ar;
    float4 bv = make_float4(0.f, 0.f, 0.f, 0.f);
    if (gn < N) bv = ldw4(W, (long)gn * K + k0 + ak, fl);
    Bs[ak+0][ar] = bv.x; Bs[ak+1][ar] = bv.y;
    Bs[ak+2][ar] = bv.z; Bs[ak+3][ar] = bv.w;
    __syncthreads();
    #pragma unroll
    for (int kk = 0; kk < 16; ++kk){
      float a[4], b[4];
      #pragma unroll
      for (int i = 0; i < 4; ++i){ a[i] = As[kk][ty + 16*i]; b[i] = Bs[kk][tx + 16*i]; }
      #pragma unroll
      for (int i = 0; i < 4; ++i)
        #pragma unroll
        for (int j = 0; j < 4; ++j) acc[i][j] += a[i] * b[j];
    }
    __syncthreads();
  }
  #pragma unroll
  for (int i = 0; i < 4; ++i){
    int gm = m0 + ty + 16*i;
    #pragma unroll
    for (int j = 0; j < 4; ++j){
      int gn = n0 + tx + 16*j;
      if (gn < N){
        float v = acc[i][j];
        if (bias) v += ldw(bias, gn, fl);
        v *= oscale;
        if (resid) v += resid[(long)gm * ldr + gn];
        long off = (long)gm * ldc + gn;
        if (outmode == 2){
          if (fl) Cb[off] = f2bf(v); else Cf[off] = v;
        } else {
          Cf[off] = v;
        }
      }
    }
  }
}

// ---------------- MFMA GEMM: C = act(A) @ W^T (+bias)*oscale (+resid) ----
__global__ __launch_bounds__(256) void k_gemm_mfma(
  const float* __restrict__ A, int lda, int K, int N,
  const void* __restrict__ W, const void* __restrict__ bias,
  float* __restrict__ Cf, u16* __restrict__ Cb, int ldc,
  const float* __restrict__ resid, int ldr,
  float oscale, int act_gelu, int outmode, const int* __restrict__ flagp)
{
  const int fl = *flagp;
  __shared__ u16 As[64*72];
  __shared__ u16 Bs[64*72];
  const int tid = threadIdx.x;
  const int w = tid >> 6, lane = tid & 63, quad = lane >> 4, m = lane & 15;
  const int m0 = blockIdx.y << 6, n0 = blockIdx.x << 6;
  const int srow = tid >> 2, sc0 = (tid & 3) << 4;

  f32x4 acc[4];
  #pragma unroll
  for (int ct = 0; ct < 4; ++ct) acc[ct] = (f32x4){0.f,0.f,0.f,0.f};

  for (int k0 = 0; k0 < K; k0 += 64){
    {
      const float* ar = A + (long)(m0 + srow) * lda + k0 + sc0;
      #pragma unroll
      for (int g = 0; g < 2; ++g){
        float4 a0 = *(const float4*)(ar + g*8);
        float4 a1 = *(const float4*)(ar + g*8 + 4);
        if (act_gelu){
          a0.x=gelu_f(a0.x); a0.y=gelu_f(a0.y); a0.z=gelu_f(a0.z); a0.w=gelu_f(a0.w);
          a1.x=gelu_f(a1.x); a1.y=gelu_f(a1.y); a1.z=gelu_f(a1.z); a1.w=gelu_f(a1.w);
        }
        union { u16 h[8]; uint4 v; } pk;
        pk.h[0]=f2bf(a0.x); pk.h[1]=f2bf(a0.y); pk.h[2]=f2bf(a0.z); pk.h[3]=f2bf(a0.w);
        pk.h[4]=f2bf(a1.x); pk.h[5]=f2bf(a1.y); pk.h[6]=f2bf(a1.z); pk.h[7]=f2bf(a1.w);
        *(uint4*)&As[srow*72 + sc0 + g*8] = pk.v;
      }
    }
    {
      long wb = (long)(n0 + srow) * K + k0 + sc0;
      #pragma unroll
      for (int g = 0; g < 2; ++g){
        float4 b0 = ldw4(W, wb + g*8, fl);
        float4 b1 = ldw4(W, wb + g*8 + 4, fl);
        union { u16 h[8]; uint4 v; } pk;
        pk.h[0]=f2bf(b0.x); pk.h[1]=f2bf(b0.y); pk.h[2]=f2bf(b0.z); pk.h[3]=f2bf(b0.w);
        pk.h[4]=f2bf(b1.x); pk.h[5]=f2bf(b1.y); pk.h[6]=f2bf(b1.z); pk.h[7]=f2bf(b1.w);
        *(uint4*)&Bs[srow*72 + sc0 + g*8] = pk.v;
      }
    }
    __syncthreads();

    s16x8 av[2];
    #pragma unroll
    for (int s = 0; s < 2; ++s)
      av[s] = *(const s16x8*)&As[(w*16 + m)*72 + s*32 + quad*8];
    #pragma unroll
    for (int ct = 0; ct < 4; ++ct)
      #pragma unroll
      for (int s = 0; s < 2; ++s){
        s16x8 bv = *(const s16x8*)&Bs[(ct*16 + m)*72 + s*32 + quad*8];
        acc[ct] = __builtin_amdgcn_mfma_f32_16x16x32_bf16(av[s], bv, acc[ct], 0, 0, 0);
      }
    __syncthreads();
  }

  #pragma unroll
  for (int r = 0; r < 4; ++r){
    int gm = m0 + w*16 + quad*4 + r;
    #pragma unroll
    for (int ct = 0; ct < 4; ++ct){
      int gn = n0 + ct*16 + m;
      float v = acc[ct][r];
      if (bias) v += ldw(bias, gn, fl);
      v *= oscale;
      if (resid) v += resid[(long)gm * ldr + gn];
      long off = (long)gm * ldc + gn;
      if (outmode == 2){
        if (fl) Cb[off] = f2bf(v); else Cf[off] = v;
      } else {
        Cf[off] = v;
      }
    }
  }
}

// ---------------- QKV extract + rotary ----------------
__global__ __launch_bounds__(256) void k_rope(
  const float* __restrict__ qkv, const void* __restrict__ pe,
  float* __restrict__ q, float* __restrict__ k, float* __restrict__ v,
  int L, int B, int H, const int* __restrict__ flagp)
{
  int fl = *flagp;
  int tid = threadIdx.x;
  int lq = tid >> 6, d = tid & 63;
  int l = blockIdx.x * 4 + lq;
  int bh = blockIdx.y; int b = bh / H; int h = bh % H;
  const float* row = qkv + ((long)b * L + l) * 768 + h * 192;
  float qv = row[d*3+0], kv = row[d*3+1], vv = row[d*3+2];
  int dn = (d & 1) ? (d - 1) : (d + 1);
  float qn = row[dn*3+0], kn = row[dn*3+1];
  float rq = (d & 1) ? qn : -qn;
  float rk = (d & 1) ? kn : -kn;
  long peo = ((long)b * L + l) * 64 + d;
  float p0 = ldw(pe, peo, fl);
  float p1 = ldw(pe, (long)B * L * 64 + peo, fl);
  long o = ((long)bh * L + l) * 64 + d;
  q[o] = qv * p0 + rq * p1;
  k[o] = kv * p0 + rk * p1;
  v[o] = vv;
}

// ---------------- MFMA flash attention with K-split, DH=64 ----------------
__global__ __launch_bounds__(256) void k_attn_mfma(
  const float* __restrict__ Q, long qsb, long qsh, long qsl,
  const float* __restrict__ Kp, long ksb, long ksh, long ksl,
  const float* __restrict__ Vp, long vsb, long vsh, long vsl,
  float* __restrict__ Opart, float* __restrict__ mpart, float* __restrict__ lpart,
  float scale, int L, int H, int kchunk)
{
  __shared__ u16 Kt[64*72];
  __shared__ u16 Vt[64*72];
  __shared__ u16 Ps[64*72];
  __shared__ u16 Qs[64*72];
  const int tid  = threadIdx.x;
  const int w    = tid >> 6;
  const int lane = tid & 63;
  const int quad = lane >> 4;
  const int m    = lane & 15;
  const int bh = blockIdx.y, b = bh / H, h = bh % H;
  const int iq0 = blockIdx.x * 64;
  const int z = blockIdx.z;
  const long BHL = (long)gridDim.y * L;

  const float* Qb = Q  + b*qsb + h*qsh;
  const float* Kb = Kp + b*ksb + h*ksh;
  const float* Vb = Vp + b*vsb + h*vsh;

  {
    int row = tid >> 2, c0 = (tid & 3) << 4;
    const float* qr = Qb + (long)(iq0 + row) * qsl + c0;
    #pragma unroll
    for (int g = 0; g < 2; ++g){
      float4 a0 = *(const float4*)(qr + g*8);
      float4 a1 = *(const float4*)(qr + g*8 + 4);
      union { u16 h[8]; uint4 v; } pk;
      pk.h[0]=f2bf(a0.x); pk.h[1]=f2bf(a0.y); pk.h[2]=f2bf(a0.z); pk.h[3]=f2bf(a0.w);
      pk.h[4]=f2bf(a1.x); pk.h[5]=f2bf(a1.y); pk.h[6]=f2bf(a1.z); pk.h[7]=f2bf(a1.w);
      *(uint4*)&Qs[row*72 + c0 + g*8] = pk.v;
    }
  }
  __syncthreads();
  s16x8 aq[2];
  #pragma unroll
  for (int s = 0; s < 2; ++s)
    aq[s] = *(const s16x8*)&Qs[(w*16 + m)*72 + s*32 + quad*8];

  f32x4 o_acc[4];
  #pragma unroll
  for (int nt = 0; nt < 4; ++nt) o_acc[nt] = (f32x4){0.f,0.f,0.f,0.f};
  float mrow[4] = {-1e30f,-1e30f,-1e30f,-1e30f};
  float lrow[4] = {0.f,0.f,0.f,0.f};

  const int srow = tid >> 2, sc0 = (tid & 3) << 4;
  const int jend = (z + 1) * kchunk;

  for (int j0 = z * kchunk; j0 < jend; j0 += 64){
    {
      const float* kr = Kb + (long)(j0 + srow) * ksl + sc0;
      #pragma unroll
      for (int g = 0; g < 2; ++g){
        float4 a0 = *(const float4*)(kr + g*8);
        float4 a1 = *(const float4*)(kr + g*8 + 4);
        union { u16 h[8]; uint4 v; } pk;
        pk.h[0]=f2bf(a0.x); pk.h[1]=f2bf(a0.y); pk.h[2]=f2bf(a0.z); pk.h[3]=f2bf(a0.w);
        pk.h[4]=f2bf(a1.x); pk.h[5]=f2bf(a1.y); pk.h[6]=f2bf(a1.z); pk.h[7]=f2bf(a1.w);
        *(uint4*)&Kt[srow*72 + sc0 + g*8] = pk.v;
      }
      const float* vr = Vb + (long)(j0 + srow) * vsl + sc0;
      #pragma unroll
      for (int g = 0; g < 4; ++g){
        float4 a0 = *(const float4*)(vr + g*4);
        Vt[(sc0 + g*4 + 0)*72 + srow] = f2bf(a0.x);
        Vt[(sc0 + g*4 + 1)*72 + srow] = f2bf(a0.y);
        Vt[(sc0 + g*4 + 2)*72 + srow] = f2bf(a0.z);
        Vt[(sc0 + g*4 + 3)*72 + srow] = f2bf(a0.w);
      }
    }
    __syncthreads();

    float sv[4][4];
    #pragma unroll
    for (int ct = 0; ct < 4; ++ct){
      f32x4 acc = (f32x4){0.f,0.f,0.f,0.f};
      #pragma unroll
      for (int s = 0; s < 2; ++s){
        s16x8 bk = *(const s16x8*)&Kt[(ct*16 + m)*72 + s*32 + quad*8];
        acc = __builtin_amdgcn_mfma_f32_16x16x32_bf16(aq[s], bk, acc, 0, 0, 0);
      }
      #pragma unroll
      for (int r = 0; r < 4; ++r) sv[ct][r] = acc[r] * scale;
    }

    float mn[4], alpha[4], rsum[4];
    #pragma unroll
    for (int r = 0; r < 4; ++r){
      float v0 = fmaxf(fmaxf(sv[0][r], sv[1][r]), fmaxf(sv[2][r], sv[3][r]));
      v0 = fmaxf(v0, __shfl_xor(v0, 1));
      v0 = fmaxf(v0, __shfl_xor(v0, 2));
      v0 = fmaxf(v0, __shfl_xor(v0, 4));
      v0 = fmaxf(v0, __shfl_xor(v0, 8));
      mn[r] = fmaxf(mrow[r], v0);
      alpha[r] = __expf(mrow[r] - mn[r]);
      mrow[r] = mn[r];
      rsum[r] = 0.f;
    }
    #pragma unroll
    for (int ct = 0; ct < 4; ++ct)
      #pragma unroll
      for (int r = 0; r < 4; ++r){
        float p = __expf(sv[ct][r] - mn[r]);
        sv[ct][r] = p;
        rsum[r] += p;
      }
    #pragma unroll
    for (int r = 0; r < 4; ++r){
      float s = rsum[r];
      s += __shfl_xor(s, 1);
      s += __shfl_xor(s, 2);
      s += __shfl_xor(s, 4);
      s += __shfl_xor(s, 8);
      lrow[r] = lrow[r] * alpha[r] + s;
    }
    #pragma unroll
    for (int nt = 0; nt < 4; ++nt)
      #pragma unroll
      for (int r = 0; r < 4; ++r) o_acc[nt][r] *= alpha[r];

    #pragma unroll
    for (int ct = 0; ct < 4; ++ct)
      #pragma unroll
      for (int r = 0; r < 4; ++r)
        Ps[(w*16 + quad*4 + r)*72 + ct*16 + m] = f2bf(sv[ct][r]);
    asm volatile("s_waitcnt lgkmcnt(0)" ::: "memory");

    s16x8 ap[2];
    #pragma unroll
    for (int s = 0; s < 2; ++s)
      ap[s] = *(const s16x8*)&Ps[(w*16 + m)*72 + s*32 + quad*8];
    #pragma unroll
    for (int nt = 0; nt < 4; ++nt)
      #pragma unroll
      for (int s = 0; s < 2; ++s){
        s16x8 bv = *(const s16x8*)&Vt[(nt*16 + m)*72 + s*32 + quad*8];
        o_acc[nt] = __builtin_amdgcn_mfma_f32_16x16x32_bf16(ap[s], bv, o_acc[nt], 0, 0, 0);
      }
    __syncthreads();
  }

  const long zOoff = (long)z * BHL * 64;
  #pragma unroll
  for (int r = 0; r < 4; ++r){
    int iq = iq0 + w*16 + quad*4 + r;
    long rowid = ((long)b*L + iq) * H + h;
    #pragma unroll
    for (int nt = 0; nt < 4; ++nt)
      Opart[zOoff + rowid*64 + nt*16 + m] = o_acc[nt][r];
    if (m == 0){
      mpart[(long)z*BHL + rowid] = mrow[r];
      lpart[(long)z*BHL + rowid] = lrow[r];
    }
  }
}

// ---------------- attention split combine ----------------
__global__ __launch_bounds__(256) void k_attn_comb(
  const float* __restrict__ Opart, const float* __restrict__ mpart,
  const float* __restrict__ lpart, float* __restrict__ O, long BHL)
{
  long i = (long)blockIdx.x * 256 + threadIdx.x;
  long row = i >> 6;
  float m0 = mpart[row],         m1 = mpart[BHL + row];
  float m2 = mpart[2*BHL + row], m3 = mpart[3*BHL + row];
  float M = fmaxf(fmaxf(m0, m1), fmaxf(m2, m3));
  float w0 = __expf(m0 - M), w1 = __expf(m1 - M);
  float w2 = __expf(m2 - M), w3 = __expf(m3 - M);
  float T = lpart[row]*w0 + lpart[BHL+row]*w1 + lpart[2*BHL+row]*w2 + lpart[3*BHL+row]*w3;
  long N64 = BHL * 64;
  float acc = Opart[i]*w0 + Opart[N64 + i]*w1 + Opart[2*N64 + i]*w2 + Opart[3*N64 + i]*w3;
  O[i] = acc / T;
}

// ---------------- depthwise conv K=5 SAME + silu ----------------
__global__ __launch_bounds__(256) void k_conv(
  const float* __restrict__ xz, int choff, const void* __restrict__ w,
  float* __restrict__ out, int L, const int* __restrict__ flagp)
{
  int fl = *flagp;
  int c = threadIdx.x;
  int bl = blockIdx.x; int b = bl / L, l = bl % L;
  const float* base = xz + ((long)b * L) * 512 + choff + c;
  float s = 0.f;
  #pragma unroll
  for (int kk = 0; kk < 5; ++kk){
    int ll = l + kk - 2;
    if (ll >= 0 && ll < L) s += base[(long)ll * 512] * ldw(w, c*5 + kk, fl);
  }
  out[((long)b * L + l) * 256 + c] = s / (1.f + __expf(-s));   // silu
}

// ---------------- softplus precompute ----------------
// dt <- softplus(dt + dtb[d])  (fast __logf form), dxc <- delta * xc.
// Removes log1pf from the scans and the 16x per-n redundancy.
// dt carries +dt_bias from the dt GEMM; reference adds dt_bias AGAIN here
// (softplus(dt + bias)) — replicated faithfully.
__global__ __launch_bounds__(256) void k_sp(
  float* __restrict__ dt, const float* __restrict__ xc,
  float* __restrict__ dxc, const void* __restrict__ dtb,
  const int* __restrict__ flagp)
{
  int fl = *flagp;
  long i = (long)blockIdx.x * 256 + threadIdx.x;
  int d = (int)(i & 255);
  float dl = dt[i] + ldw(dtb, d, fl);
  float delta = (dl > 20.f) ? dl : __logf(1.f + __expf(dl));
  dt[i] = delta;
  dxc[i] = delta * xc[i];
}

// ---------------- chunk-parallel selective scan ----------------
// h[l] = e[l]*h[l-1] + u[l], e = exp(delta*A[n]), u = (delta*x)[l]*Bm[l,n].
// delta/dxc precomputed by k_sp. NC=32 chunks of CS=64 per (b,d) chain.
#define SC_CS 64
#define SC_NC 32

__global__ __launch_bounds__(256) void k_scan1(
  const float* __restrict__ delta, const float* __restrict__ dxc,
  const float* __restrict__ xdbl, const void* __restrict__ Alog,
  float* __restrict__ E_out, float* __restrict__ F_out,
  int L, const int* __restrict__ flagp)
{
  int fl = *flagp;
  int tid = threadIdx.x;
  int g = tid >> 4, n = tid & 15;
  int gid = blockIdx.x * 16 + g;
  int chunk = gid & (SC_NC - 1);
  int p = gid >> 5;
  int b = p >> 8, d = p & 255;
  float A = -__expf(ldw(Alog, d*16 + n, fl));
  const float* dtp = delta + (long)b*L*256 + d;
  const float* dxp = dxc   + (long)b*L*256 + d;
  const float* xdb = xdbl + (long)b*L*48;
  int l0 = chunk * SC_CS;
  float E = 1.f, F = 0.f;
  for (int i = 0; i < SC_CS; ++i){
    int l = l0 + i;
    float e = __expf(dtp[(long)l*256] * A);
    float u = dxp[(long)l*256] * xdb[l*48 + 16 + n];
    E *= e;
    F = e * F + u;
  }
  long idx = (long)(p*16 + n) * SC_NC + chunk;
  E_out[idx] = E; F_out[idx] = F;
}

__global__ __launch_bounds__(256) void k_scan2(
  const float* __restrict__ E, const float* __restrict__ F,
  float* __restrict__ Hin)
{
  int pn = blockIdx.x * 256 + threadIdx.x;
  const float* Ep = E + (long)pn * SC_NC;
  const float* Fp = F + (long)pn * SC_NC;
  float* Hp = Hin + (long)pn * SC_NC;
  float h = 0.f;
  #pragma unroll
  for (int c = 0; c < SC_NC; ++c){
    Hp[c] = h;
    h = Ep[c] * h + Fp[c];
  }
}

__global__ __launch_bounds__(256) void k_scan3(
  const float* __restrict__ delta, const float* __restrict__ dxc,
  const float* __restrict__ xc, const float* __restrict__ xdbl,
  const void* __restrict__ Alog, const void* __restrict__ Dp,
  const float* __restrict__ Hin, float* __restrict__ y,
  int L, const int* __restrict__ flagp)
{
  int fl = *flagp;
  int tid = threadIdx.x;
  int g = tid >> 4, n = tid & 15;
  int gid = blockIdx.x * 16 + g;
  int chunk = gid & (SC_NC - 1);
  int p = gid >> 5;
  int b = p >> 8, d = p & 255;
  float A = -__expf(ldw(Alog, d*16 + n, fl));
  float Dv = ldw(Dp, d, fl);
  const float* dtp = delta + (long)b*L*256 + d;
  const float* dxp = dxc   + (long)b*L*256 + d;
  const float* xcb = xc    + (long)b*L*256 + d;
  const float* xdb = xdbl + (long)b*L*48;
  float* yb = y + (long)b*L*256 + d;
  long idx = (long)(p*16 + n) * SC_NC + chunk;
  float h = Hin[idx];
  int l0 = chunk * SC_CS;
  for (int i = 0; i < SC_CS; ++i){
    int l = l0 + i;
    float e = __expf(dtp[(long)l*256] * A);
    h = e * h + dxp[(long)l*256] * xdb[l*48 + 16 + n];
    float part = h * xdb[l*48 + 32 + n];
    part += __shfl_xor(part, 1, 16);
    part += __shfl_xor(part, 2, 16);
    part += __shfl_xor(part, 4, 16);
    part += __shfl_xor(part, 8, 16);
    if (n == 0) yb[(long)l*256] = part + Dv * xcb[(long)l*256];
  }
}

// ---------------- LayerNorm over rows of 512 (in place) ----------------
__global__ __launch_bounds__(256) void k_ln(float* __restrict__ h,
                                            const void* __restrict__ g,
                                            const void* __restrict__ beta,
                                            const int* __restrict__ flagp)
{
  int fl = *flagp;
  int row = blockIdx.x * 4 + (threadIdx.x >> 6);
  int lane = threadIdx.x & 63;
  float* hr = h + (long)row * 512;
  float v[8]; float s = 0.f, ss = 0.f;
  #pragma unroll
  for (int i = 0; i < 8; ++i){ v[i] = hr[lane + 64*i]; s += v[i]; ss += v[i]*v[i]; }
  #pragma unroll
  for (int off = 1; off < 64; off <<= 1){ s += __shfl_xor(s, off); ss += __shfl_xor(ss, off); }
  float mean = s * (1.f/512.f);
  float var  = ss * (1.f/512.f) - mean * mean;
  float rs = rsqrtf(var + 1e-5f);
  #pragma unroll
  for (int i = 0; i < 8; ++i){
    int c = lane + 64*i;
    hr[c] = (v[i] - mean) * rs * ldw(g, c, fl) + ldw(beta, c, fl);
  }
}

extern "C" void kernel_launch(void* const* d_in, const int* in_sizes, int n_in,
                              void* d_out, int out_size, void* d_ws, size_t ws_size,
                              hipStream_t stream)
{
  const int B_ = 2, L_ = 2048, H_ = 4;
  const long BLE = (long)B_ * L_ * 256;       // 1,048,576
  const long BHL = (long)B_ * H_ * L_;        // 16,384
  int* flagp = (int*)d_ws;
  float* base = (float*)d_ws + 64;
  float* x    = base + 0*BLE;
  float* dbuf[2] = { base + 1*BLE, base + 2*BLE };
  float* cat  = base + 3*BLE;                 // 4 BLE; qkv staging + attn O-partials
  float* qb   = base + 7*BLE;                 // also dt/delta buffer
  float* kb   = base + 8*BLE;                 // also scan y output
  float* vb   = base + 9*BLE;                 // also scan scratch (E/F/Hin)
  float* ob   = base + 10*BLE;
  float* hbuf = base + 11*BLE;                // 2 BLE; attn (m,l) + xz + dxc + FFN hidden
  float* xcb  = base + 13*BLE;
  float* zcb  = base + 14*BLE;
  float* xdbl = base + 15*BLE;

  const long SCN = (long)2 * 256 * 16 * SC_NC;
  float* scE = vb;
  float* scF = vb + SCN;
  float* scH = vb + 2*SCN;
  float* mml = hbuf;                 // attention (m,l) scratch: 8*BHL floats
  float* mll = hbuf + 4*BHL;
  float* dxc = hbuf;                 // scan dxc (hbuf free between conv and FFN)

  const void* in[35];
  for (int i = 0; i < 35 && i < n_in; ++i) in[i] = d_in[i];

  k_sniff<<<1, 256, 0, stream>>>((const unsigned int*)in[0], 2048, flagp);

  auto gemm = [&](const float* A, int lda, int K, int N, const void* W,
                  const void* bias, float* Cf, u16* Cb, int ldc,
                  const float* resid, int ldr, float oscale, int act, int om){
    if ((K & 63) == 0 && (N & 63) == 0){
      dim3 g(N >> 6, 64);
      k_gemm_mfma<<<g, 256, 0, stream>>>(A, lda, K, N, W, bias, Cf, Cb, ldc,
                                         resid, ldr, oscale, act, om, flagp);
    } else {
      dim3 g((N + 63) / 64, 64);
      k_gemm<<<g, 256, 0, stream>>>(A, lda, K, N, W, bias, Cf, Cb, ldc,
                                    resid, ldr, oscale, act, om, flagp);
    }
  };

  const long sbP = (long)H_ * L_ * 64, shP = (long)L_ * 64, slP = 64;   // (B,H,L,64)
  const long sbF = (long)L_ * 256,     shF = 64,            slF = 256;  // (B,L,256)
  const dim3 gAttn(L_/64, B_*H_, 4);
  const int kchunk = L_ / 4;

  // ---------------- per-descriptor: mamba_attention ----------------
  for (int i = 0; i < 2; ++i){
    float* d = dbuf[i];
    k_cvt<<<(int)(BLE/256), 256, 0, stream>>>(in[i], x, BLE, flagp);
    gemm(x, 256, 256, 768, in[4], in[5], cat, nullptr, 768, nullptr, 0, 1.f, 0, 0);
    k_rope<<<dim3(L_/4, B_*H_), 256, 0, stream>>>(cat, in[2+i], qb, kb, vb, L_, B_, H_, flagp);
    k_attn_mfma<<<gAttn, 256, 0, stream>>>(qb, sbP, shP, slP,
                                           kb, sbP, shP, slP,
                                           vb, sbP, shP, slP,
                                           cat, mml, mll, 0.125f, L_, H_, kchunk);
    k_attn_comb<<<(int)(BLE/256), 256, 0, stream>>>(cat, mml, mll, ob, BHL);
    gemm(x, 256, 256, 512, in[14], nullptr, hbuf, nullptr, 512, nullptr, 0, 1.f, 0, 0); // xz
    k_conv<<<B_*L_, 256, 0, stream>>>(hbuf, 0,   in[15], xcb, L_, flagp);
    k_conv<<<B_*L_, 256, 0, stream>>>(hbuf, 256, in[16], zcb, L_, flagp);
    gemm(xcb, 256, 256, 48, in[17], nullptr, xdbl, nullptr, 48, nullptr, 0, 1.f, 0, 0);
    gemm(xdbl, 48, 16, 256, in[18], in[19], qb, nullptr, 256, nullptr, 0, 1.f, 0, 0);    // dt
    k_sp<<<(int)(BLE/256), 256, 0, stream>>>(qb, xcb, dxc, in[19], flagp);               // delta, dxc
    k_scan1<<<1024, 256, 0, stream>>>(qb, dxc, xdbl, in[20], scE, scF, L_, flagp);
    k_scan2<<<32, 256, 0, stream>>>(scE, scF, scH);
    k_scan3<<<1024, 256, 0, stream>>>(qb, dxc, xcb, xdbl, in[20], in[21], scH, kb, L_, flagp);
    gemm(kb, 256, 256, 256, in[22], nullptr, cat + 512, nullptr, 1024, nullptr, 0, 1.f, 0, 0);
    gemm(zcb, 256, 256, 256, in[22], nullptr, cat + 768, nullptr, 1024, nullptr, 0, 1.f, 0, 0);
    gemm(ob, 256, 256, 256, in[6], in[7],   cat + 256, nullptr, 1024, nullptr, 0, 1.f, 0, 0);
    k_copyc<<<(int)(BLE/256), 256, 0, stream>>>(x, cat, 1024);
    gemm(cat, 1024, 1024, 512, in[8], in[9], hbuf, nullptr, 512, nullptr, 0, 1.f, 0, 0);
    k_ln<<<1024, 256, 0, stream>>>(hbuf, in[10], in[11], flagp);
    gemm(hbuf, 512, 512, 256, in[12], in[13], d, nullptr, 256, x, 256, 1.f, 1, 0);
  }

  // ---------------- cross attention ----------------
  const float s4 = 0.35355339059327373f;  // 64^-0.25
  gemm(dbuf[0], 256, 256, 256, in[23], in[24], qb, nullptr, 256, nullptr, 0, s4, 0, 0);
  gemm(dbuf[1], 256, 256, 256, in[23], in[24], kb, nullptr, 256, nullptr, 0, s4, 0, 0);
  gemm(dbuf[0], 256, 256, 256, in[25], in[26], vb, nullptr, 256, nullptr, 0, 1.f, 0, 0);
  gemm(dbuf[1], 256, 256, 256, in[25], in[26], ob, nullptr, 256, nullptr, 0, 1.f, 0, 0);
  k_attn_mfma<<<gAttn, 256, 0, stream>>>(qb, sbF, shF, slF, kb, sbF, shF, slF,
                                         ob, sbF, shF, slF, cat, mml, mll, 1.f, L_, H_, kchunk);
  k_attn_comb<<<(int)(BLE/256), 256, 0, stream>>>(cat, mml, mll, xcb, BHL);
  k_attn_mfma<<<gAttn, 256, 0, stream>>>(kb, sbF, shF, slF, qb, sbF, shF, slF,
                                         vb, sbF, shF, slF, cat, mml, mll, 1.f, L_, H_, kchunk);
  k_attn_comb<<<(int)(BLE/256), 256, 0, stream>>>(cat, mml, mll, zcb, BHL);
  for (int i = 0; i < 2; ++i){
    float* mi = (i == 0) ? xcb : zcb;
    k_copyc<<<(int)(BLE/256), 256, 0, stream>>>(dbuf[i], cat, 512);
    gemm(mi, 256, 256, 256, in[27], in[28], cat + 256, nullptr, 512, nullptr, 0, 1.f, 0, 0);
    gemm(cat, 512, 512, 512, in[29], in[30], hbuf, nullptr, 512, nullptr, 0, 1.f, 0, 0);
    k_ln<<<1024, 256, 0, stream>>>(hbuf, in[31], in[32], flagp);
    gemm(hbuf, 512, 512, 256, in[33], in[34],
         (float*)d_out + (long)i * BLE, (u16*)d_out + (long)i * BLE, 256,
         dbuf[i], 256, 1.f, 1, 2);
  }
}

// Round 9
// 1037.616 us; speedup vs baseline: 5.7783x; 1.0079x over previous
//
#include <hip/hip_runtime.h>

typedef unsigned short u16;
typedef short s16;
typedef s16 s16x8 __attribute__((ext_vector_type(8)));
typedef float f32x4 __attribute__((ext_vector_type(4)));

__device__ __forceinline__ float bf2f(u16 u){
  union { unsigned int i; float f; } v; v.i = ((unsigned int)u) << 16; return v.f;
}
__device__ __forceinline__ u16 f2bf(float f){
  union { float f; unsigned int u; } v; v.f = f;
  unsigned int r = (v.u + 0x7fffu + ((v.u >> 16) & 1u)) >> 16;
  return (u16)r;
}
__device__ __forceinline__ float gelu_f(float x){
  return 0.5f * x * (1.f + erff(x * 0.70710678118654752440f));
}
// flag-aware loads: fl=1 -> src is bf16, fl=0 -> src is fp32
__device__ __forceinline__ float ldw(const void* p, long i, int fl){
  return fl ? bf2f(((const u16*)p)[i]) : ((const float*)p)[i];
}
__device__ __forceinline__ float4 ldw4(const void* p, long i, int fl){
  if (fl){
    ushort4 w = *(const ushort4*)((const u16*)p + i);
    return make_float4(bf2f(w.x), bf2f(w.y), bf2f(w.z), bf2f(w.w));
  }
  return *(const float4*)((const float*)p + i);
}

// ---------------- dtype sniffer ----------------
__global__ __launch_bounds__(256) void k_sniff(const unsigned int* __restrict__ w,
                                               int n, int* __restrict__ flag){
  __shared__ int cnt[256];
  int c = 0;
  for (int i = threadIdx.x; i < n; i += 256){
    unsigned e = (w[i] >> 7) & 0xFFu;
    c += (e >= 120u && e <= 127u) ? 1 : 0;
  }
  cnt[threadIdx.x] = c; __syncthreads();
  for (int s = 128; s > 0; s >>= 1){
    if (threadIdx.x < s) cnt[threadIdx.x] += cnt[threadIdx.x + s];
    __syncthreads();
  }
  if (threadIdx.x == 0) *flag = (2 * cnt[0] > n) ? 1 : 0;
}

// ---------------- convert input activations -> f32 ----------------
__global__ __launch_bounds__(256) void k_cvt(const void* __restrict__ src,
                                             float* __restrict__ dst, long n,
                                             const int* __restrict__ flagp){
  int fl = *flagp;
  long i = (long)blockIdx.x * 256 + threadIdx.x;
  if (i < n) dst[i] = ldw(src, i, fl);
}

// ---- copy f32 (M x 256 contiguous) into dst[m*ldc + c] (concat helper) ----
__global__ __launch_bounds__(256) void k_copyc(const float* __restrict__ src,
                                               float* __restrict__ dst, int ldc){
  long i = (long)blockIdx.x * 256 + threadIdx.x;
  long m = i >> 8; int c = (int)(i & 255);
  dst[m * (long)ldc + c] = src[i];
}

// ---------------- fallback fp32 GEMM (K or N not mult of 64) ----------------
__global__ __launch_bounds__(256) void k_gemm(
  const float* __restrict__ A, int lda, int K, int N,
  const void* __restrict__ W, const void* __restrict__ bias,
  float* __restrict__ Cf, u16* __restrict__ Cb, int ldc,
  const float* __restrict__ resid, int ldr,
  float oscale, int act_gelu, int outmode, const int* __restrict__ flagp)
{
  const int fl = *flagp;
  __shared__ float As[16][65];
  __shared__ float Bs[16][65];
  int tid = threadIdx.x;
  int m0 = blockIdx.y << 6, n0 = blockIdx.x << 6;
  int tx = tid & 15, ty = tid >> 4;
  int ar = tid >> 2;
  int ak = (tid & 3) << 2;
  float acc[4][4];
  #pragma unroll
  for (int i = 0; i < 4; ++i)
    #pragma unroll
    for (int j = 0; j < 4; ++j) acc[i][j] = 0.f;

  for (int k0 = 0; k0 < K; k0 += 16){
    float4 av = *(const float4*)(A + (long)(m0 + ar) * lda + k0 + ak);
    if (act_gelu){ av.x = gelu_f(av.x); av.y = gelu_f(av.y);
                   av.z = gelu_f(av.z); av.w = gelu_f(av.w); }
    As[ak+0][ar] = av.x; As[ak+1][ar] = av.y;
    As[ak+2][ar] = av.z; As[ak+3][ar] = av.w;
    int gn = n0 + ar;
    float4 bv = make_float4(0.f, 0.f, 0.f, 0.f);
    if (gn < N) bv = ldw4(W, (long)gn * K + k0 + ak, fl);
    Bs[ak+0][ar] = bv.x; Bs[ak+1][ar] = bv.y;
    Bs[ak+2][ar] = bv.z; Bs[ak+3][ar] = bv.w;
    __syncthreads();
    #pragma unroll
    for (int kk = 0; kk < 16; ++kk){
      float a[4], b[4];
      #pragma unroll
      for (int i = 0; i < 4; ++i){ a[i] = As[kk][ty + 16*i]; b[i] = Bs[kk][tx + 16*i]; }
      #pragma unroll
      for (int i = 0; i < 4; ++i)
        #pragma unroll
        for (int j = 0; j < 4; ++j) acc[i][j] += a[i] * b[j];
    }
    __syncthreads();
  }
  #pragma unroll
  for (int i = 0; i < 4; ++i){
    int gm = m0 + ty + 16*i;
    #pragma unroll
    for (int j = 0; j < 4; ++j){
      int gn = n0 + tx + 16*j;
      if (gn < N){
        float v = acc[i][j];
        if (bias) v += ldw(bias, gn, fl);
        v *= oscale;
        if (resid) v += resid[(long)gm * ldr + gn];
        long off = (long)gm * ldc + gn;
        if (outmode == 2){
          if (fl) Cb[off] = f2bf(v); else Cf[off] = v;
        } else {
          Cf[off] = v;
        }
      }
    }
  }
}

// ---------------- MFMA GEMM: C = act(A) @ W^T (+bias)*oscale (+resid) ----
__global__ __launch_bounds__(256) void k_gemm_mfma(
  const float* __restrict__ A, int lda, int K, int N,
  const void* __restrict__ W, const void* __restrict__ bias,
  float* __restrict__ Cf, u16* __restrict__ Cb, int ldc,
  const float* __restrict__ resid, int ldr,
  float oscale, int act_gelu, int outmode, const int* __restrict__ flagp)
{
  const int fl = *flagp;
  __shared__ u16 As[64*72];
  __shared__ u16 Bs[64*72];
  const int tid = threadIdx.x;
  const int w = tid >> 6, lane = tid & 63, quad = lane >> 4, m = lane & 15;
  const int m0 = blockIdx.y << 6, n0 = blockIdx.x << 6;
  const int srow = tid >> 2, sc0 = (tid & 3) << 4;

  f32x4 acc[4];
  #pragma unroll
  for (int ct = 0; ct < 4; ++ct) acc[ct] = (f32x4){0.f,0.f,0.f,0.f};

  for (int k0 = 0; k0 < K; k0 += 64){
    {
      const float* ar = A + (long)(m0 + srow) * lda + k0 + sc0;
      #pragma unroll
      for (int g = 0; g < 2; ++g){
        float4 a0 = *(const float4*)(ar + g*8);
        float4 a1 = *(const float4*)(ar + g*8 + 4);
        if (act_gelu){
          a0.x=gelu_f(a0.x); a0.y=gelu_f(a0.y); a0.z=gelu_f(a0.z); a0.w=gelu_f(a0.w);
          a1.x=gelu_f(a1.x); a1.y=gelu_f(a1.y); a1.z=gelu_f(a1.z); a1.w=gelu_f(a1.w);
        }
        union { u16 h[8]; uint4 v; } pk;
        pk.h[0]=f2bf(a0.x); pk.h[1]=f2bf(a0.y); pk.h[2]=f2bf(a0.z); pk.h[3]=f2bf(a0.w);
        pk.h[4]=f2bf(a1.x); pk.h[5]=f2bf(a1.y); pk.h[6]=f2bf(a1.z); pk.h[7]=f2bf(a1.w);
        *(uint4*)&As[srow*72 + sc0 + g*8] = pk.v;
      }
    }
    {
      long wb = (long)(n0 + srow) * K + k0 + sc0;
      #pragma unroll
      for (int g = 0; g < 2; ++g){
        float4 b0 = ldw4(W, wb + g*8, fl);
        float4 b1 = ldw4(W, wb + g*8 + 4, fl);
        union { u16 h[8]; uint4 v; } pk;
        pk.h[0]=f2bf(b0.x); pk.h[1]=f2bf(b0.y); pk.h[2]=f2bf(b0.z); pk.h[3]=f2bf(b0.w);
        pk.h[4]=f2bf(b1.x); pk.h[5]=f2bf(b1.y); pk.h[6]=f2bf(b1.z); pk.h[7]=f2bf(b1.w);
        *(uint4*)&Bs[srow*72 + sc0 + g*8] = pk.v;
      }
    }
    __syncthreads();

    s16x8 av[2];
    #pragma unroll
    for (int s = 0; s < 2; ++s)
      av[s] = *(const s16x8*)&As[(w*16 + m)*72 + s*32 + quad*8];
    #pragma unroll
    for (int ct = 0; ct < 4; ++ct)
      #pragma unroll
      for (int s = 0; s < 2; ++s){
        s16x8 bv = *(const s16x8*)&Bs[(ct*16 + m)*72 + s*32 + quad*8];
        acc[ct] = __builtin_amdgcn_mfma_f32_16x16x32_bf16(av[s], bv, acc[ct], 0, 0, 0);
      }
    __syncthreads();
  }

  #pragma unroll
  for (int r = 0; r < 4; ++r){
    int gm = m0 + w*16 + quad*4 + r;
    #pragma unroll
    for (int ct = 0; ct < 4; ++ct){
      int gn = n0 + ct*16 + m;
      float v = acc[ct][r];
      if (bias) v += ldw(bias, gn, fl);
      v *= oscale;
      if (resid) v += resid[(long)gm * ldr + gn];
      long off = (long)gm * ldc + gn;
      if (outmode == 2){
        if (fl) Cb[off] = f2bf(v); else Cf[off] = v;
      } else {
        Cf[off] = v;
      }
    }
  }
}

// ---------------- QKV extract + rotary ----------------
__global__ __launch_bounds__(256) void k_rope(
  const float* __restrict__ qkv, const void* __restrict__ pe,
  float* __restrict__ q, float* __restrict__ k, float* __restrict__ v,
  int L, int B, int H, const int* __restrict__ flagp)
{
  int fl = *flagp;
  int tid = threadIdx.x;
  int lq = tid >> 6, d = tid & 63;
  int l = blockIdx.x * 4 + lq;
  int bh = blockIdx.y; int b = bh / H; int h = bh % H;
  const float* row = qkv + ((long)b * L + l) * 768 + h * 192;
  float qv = row[d*3+0], kv = row[d*3+1], vv = row[d*3+2];
  int dn = (d & 1) ? (d - 1) : (d + 1);
  float qn = row[dn*3+0], kn = row[dn*3+1];
  float rq = (d & 1) ? qn : -qn;
  float rk = (d & 1) ? kn : -kn;
  long peo = ((long)b * L + l) * 64 + d;
  float p0 = ldw(pe, peo, fl);
  float p1 = ldw(pe, (long)B * L * 64 + peo, fl);
  long o = ((long)bh * L + l) * 64 + d;
  q[o] = qv * p0 + rq * p1;
  k[o] = kv * p0 + rk * p1;
  v[o] = vv;
}

// ---------------- MFMA flash attention with K-split, DH=64 ----------------
// v2: no Qs tile (direct per-lane global Q fragment load, pre-scaled — exact
// for pow2 scales), Ps aliases Kt (extra barrier after QK). LDS 18.4 KB ->
// 8 blocks/CU.
__global__ __launch_bounds__(256) void k_attn_mfma(
  const float* __restrict__ Q, long qsb, long qsh, long qsl,
  const float* __restrict__ Kp, long ksb, long ksh, long ksl,
  const float* __restrict__ Vp, long vsb, long vsh, long vsl,
  float* __restrict__ Opart, float* __restrict__ mpart, float* __restrict__ lpart,
  float scale, int L, int H, int kchunk)
{
  __shared__ u16 Kt[64*72];     // K tile; re-used as P tile after QK phase
  __shared__ u16 Vt[64*72];
  u16* Ps = Kt;
  const int tid  = threadIdx.x;
  const int w    = tid >> 6;
  const int lane = tid & 63;
  const int quad = lane >> 4;
  const int m    = lane & 15;
  const int bh = blockIdx.y, b = bh / H, h = bh % H;
  const int iq0 = blockIdx.x * 64;
  const int z = blockIdx.z;
  const long BHL = (long)gridDim.y * L;

  const float* Qb = Q  + b*qsb + h*qsh;
  const float* Kb = Kp + b*ksb + h*ksh;
  const float* Vb = Vp + b*vsb + h*vsh;

  // direct Q fragment: rows iq0 + w*16 + m, cols s*32 + quad*8 + 0..7
  s16x8 aq[2];
  {
    const float* qr = Qb + (long)(iq0 + w*16 + m) * qsl + quad*8;
    #pragma unroll
    for (int s = 0; s < 2; ++s){
      float4 a0 = *(const float4*)(qr + s*32);
      float4 a1 = *(const float4*)(qr + s*32 + 4);
      s16x8 t;
      t[0]=(s16)f2bf(a0.x*scale); t[1]=(s16)f2bf(a0.y*scale);
      t[2]=(s16)f2bf(a0.z*scale); t[3]=(s16)f2bf(a0.w*scale);
      t[4]=(s16)f2bf(a1.x*scale); t[5]=(s16)f2bf(a1.y*scale);
      t[6]=(s16)f2bf(a1.z*scale); t[7]=(s16)f2bf(a1.w*scale);
      aq[s] = t;
    }
  }

  f32x4 o_acc[4];
  #pragma unroll
  for (int nt = 0; nt < 4; ++nt) o_acc[nt] = (f32x4){0.f,0.f,0.f,0.f};
  float mrow[4] = {-1e30f,-1e30f,-1e30f,-1e30f};
  float lrow[4] = {0.f,0.f,0.f,0.f};

  const int srow = tid >> 2, sc0 = (tid & 3) << 4;
  const int jend = (z + 1) * kchunk;

  for (int j0 = z * kchunk; j0 < jend; j0 += 64){
    {
      const float* kr = Kb + (long)(j0 + srow) * ksl + sc0;
      #pragma unroll
      for (int g = 0; g < 2; ++g){
        float4 a0 = *(const float4*)(kr + g*8);
        float4 a1 = *(const float4*)(kr + g*8 + 4);
        union { u16 h[8]; uint4 v; } pk;
        pk.h[0]=f2bf(a0.x); pk.h[1]=f2bf(a0.y); pk.h[2]=f2bf(a0.z); pk.h[3]=f2bf(a0.w);
        pk.h[4]=f2bf(a1.x); pk.h[5]=f2bf(a1.y); pk.h[6]=f2bf(a1.z); pk.h[7]=f2bf(a1.w);
        *(uint4*)&Kt[srow*72 + sc0 + g*8] = pk.v;
      }
      const float* vr = Vb + (long)(j0 + srow) * vsl + sc0;
      #pragma unroll
      for (int g = 0; g < 4; ++g){
        float4 a0 = *(const float4*)(vr + g*4);
        Vt[(sc0 + g*4 + 0)*72 + srow] = f2bf(a0.x);
        Vt[(sc0 + g*4 + 1)*72 + srow] = f2bf(a0.y);
        Vt[(sc0 + g*4 + 2)*72 + srow] = f2bf(a0.z);
        Vt[(sc0 + g*4 + 3)*72 + srow] = f2bf(a0.w);
      }
    }
    __syncthreads();

    float sv[4][4];
    #pragma unroll
    for (int ct = 0; ct < 4; ++ct){
      f32x4 acc = (f32x4){0.f,0.f,0.f,0.f};
      #pragma unroll
      for (int s = 0; s < 2; ++s){
        s16x8 bk = *(const s16x8*)&Kt[(ct*16 + m)*72 + s*32 + quad*8];
        acc = __builtin_amdgcn_mfma_f32_16x16x32_bf16(aq[s], bk, acc, 0, 0, 0);
      }
      #pragma unroll
      for (int r = 0; r < 4; ++r) sv[ct][r] = acc[r];
    }

    float mn[4], alpha[4], rsum[4];
    #pragma unroll
    for (int r = 0; r < 4; ++r){
      float v0 = fmaxf(fmaxf(sv[0][r], sv[1][r]), fmaxf(sv[2][r], sv[3][r]));
      v0 = fmaxf(v0, __shfl_xor(v0, 1));
      v0 = fmaxf(v0, __shfl_xor(v0, 2));
      v0 = fmaxf(v0, __shfl_xor(v0, 4));
      v0 = fmaxf(v0, __shfl_xor(v0, 8));
      mn[r] = fmaxf(mrow[r], v0);
      alpha[r] = __expf(mrow[r] - mn[r]);
      mrow[r] = mn[r];
      rsum[r] = 0.f;
    }
    #pragma unroll
    for (int ct = 0; ct < 4; ++ct)
      #pragma unroll
      for (int r = 0; r < 4; ++r){
        float p = __expf(sv[ct][r] - mn[r]);
        sv[ct][r] = p;
        rsum[r] += p;
      }
    #pragma unroll
    for (int r = 0; r < 4; ++r){
      float s = rsum[r];
      s += __shfl_xor(s, 1);
      s += __shfl_xor(s, 2);
      s += __shfl_xor(s, 4);
      s += __shfl_xor(s, 8);
      lrow[r] = lrow[r] * alpha[r] + s;
    }
    #pragma unroll
    for (int nt = 0; nt < 4; ++nt)
      #pragma unroll
      for (int r = 0; r < 4; ++r) o_acc[nt][r] *= alpha[r];

    __syncthreads();   // all waves done reading Kt before P overwrites it

    #pragma unroll
    for (int ct = 0; ct < 4; ++ct)
      #pragma unroll
      for (int r = 0; r < 4; ++r)
        Ps[(w*16 + quad*4 + r)*72 + ct*16 + m] = f2bf(sv[ct][r]);
    asm volatile("s_waitcnt lgkmcnt(0)" ::: "memory");  // own-wave rows RAW

    s16x8 ap[2];
    #pragma unroll
    for (int s = 0; s < 2; ++s)
      ap[s] = *(const s16x8*)&Ps[(w*16 + m)*72 + s*32 + quad*8];
    #pragma unroll
    for (int nt = 0; nt < 4; ++nt)
      #pragma unroll
      for (int s = 0; s < 2; ++s){
        s16x8 bv = *(const s16x8*)&Vt[(nt*16 + m)*72 + s*32 + quad*8];
        o_acc[nt] = __builtin_amdgcn_mfma_f32_16x16x32_bf16(ap[s], bv, o_acc[nt], 0, 0, 0);
      }
    __syncthreads();
  }

  const long zOoff = (long)z * BHL * 64;
  #pragma unroll
  for (int r = 0; r < 4; ++r){
    int iq = iq0 + w*16 + quad*4 + r;
    long rowid = ((long)b*L + iq) * H + h;
    #pragma unroll
    for (int nt = 0; nt < 4; ++nt)
      Opart[zOoff + rowid*64 + nt*16 + m] = o_acc[nt][r];
    if (m == 0){
      mpart[(long)z*BHL + rowid] = mrow[r];
      lpart[(long)z*BHL + rowid] = lrow[r];
    }
  }
}

// ---------------- attention split combine ----------------
__global__ __launch_bounds__(256) void k_attn_comb(
  const float* __restrict__ Opart, const float* __restrict__ mpart,
  const float* __restrict__ lpart, float* __restrict__ O, long BHL)
{
  long i = (long)blockIdx.x * 256 + threadIdx.x;
  long row = i >> 6;
  float m0 = mpart[row],         m1 = mpart[BHL + row];
  float m2 = mpart[2*BHL + row], m3 = mpart[3*BHL + row];
  float M = fmaxf(fmaxf(m0, m1), fmaxf(m2, m3));
  float w0 = __expf(m0 - M), w1 = __expf(m1 - M);
  float w2 = __expf(m2 - M), w3 = __expf(m3 - M);
  float T = lpart[row]*w0 + lpart[BHL+row]*w1 + lpart[2*BHL+row]*w2 + lpart[3*BHL+row]*w3;
  long N64 = BHL * 64;
  float acc = Opart[i]*w0 + Opart[N64 + i]*w1 + Opart[2*N64 + i]*w2 + Opart[3*N64 + i]*w3;
  O[i] = acc / T;
}

// ---------------- depthwise conv K=5 SAME + silu ----------------
__global__ __launch_bounds__(256) void k_conv(
  const float* __restrict__ xz, int choff, const void* __restrict__ w,
  float* __restrict__ out, int L, const int* __restrict__ flagp)
{
  int fl = *flagp;
  int c = threadIdx.x;
  int bl = blockIdx.x; int b = bl / L, l = bl % L;
  const float* base = xz + ((long)b * L) * 512 + choff + c;
  float s = 0.f;
  #pragma unroll
  for (int kk = 0; kk < 5; ++kk){
    int ll = l + kk - 2;
    if (ll >= 0 && ll < L) s += base[(long)ll * 512] * ldw(w, c*5 + kk, fl);
  }
  out[((long)b * L + l) * 256 + c] = s / (1.f + __expf(-s));   // silu
}

// ---------------- softplus precompute ----------------
__global__ __launch_bounds__(256) void k_sp(
  float* __restrict__ dt, const float* __restrict__ xc,
  float* __restrict__ dxc, const void* __restrict__ dtb,
  const int* __restrict__ flagp)
{
  int fl = *flagp;
  long i = (long)blockIdx.x * 256 + threadIdx.x;
  int d = (int)(i & 255);
  float dl = dt[i] + ldw(dtb, d, fl);
  float delta = (dl > 20.f) ? dl : __logf(1.f + __expf(dl));
  dt[i] = delta;
  dxc[i] = delta * xc[i];
}

// ---------------- chunk-parallel selective scan ----------------
#define SC_CS 64
#define SC_NC 32

__global__ __launch_bounds__(256) void k_scan1(
  const float* __restrict__ delta, const float* __restrict__ dxc,
  const float* __restrict__ xdbl, const void* __restrict__ Alog,
  float* __restrict__ E_out, float* __restrict__ F_out,
  int L, const int* __restrict__ flagp)
{
  int fl = *flagp;
  int tid = threadIdx.x;
  int g = tid >> 4, n = tid & 15;
  int gid = blockIdx.x * 16 + g;
  int chunk = gid & (SC_NC - 1);
  int p = gid >> 5;
  int b = p >> 8, d = p & 255;
  float A = -__expf(ldw(Alog, d*16 + n, fl));
  const float* dtp = delta + (long)b*L*256 + d;
  const float* dxp = dxc   + (long)b*L*256 + d;
  const float* xdb = xdbl + (long)b*L*48;
  int l0 = chunk * SC_CS;
  float E = 1.f, F = 0.f;
  for (int i = 0; i < SC_CS; ++i){
    int l = l0 + i;
    float e = __expf(dtp[(long)l*256] * A);
    float u = dxp[(long)l*256] * xdb[l*48 + 16 + n];
    E *= e;
    F = e * F + u;
  }
  long idx = (long)(p*16 + n) * SC_NC + chunk;
  E_out[idx] = E; F_out[idx] = F;
}

__global__ __launch_bounds__(256) void k_scan2(
  const float* __restrict__ E, const float* __restrict__ F,
  float* __restrict__ Hin)
{
  int pn = blockIdx.x * 256 + threadIdx.x;
  const float* Ep = E + (long)pn * SC_NC;
  const float* Fp = F + (long)pn * SC_NC;
  float* Hp = Hin + (long)pn * SC_NC;
  float h = 0.f;
  #pragma unroll
  for (int c = 0; c < SC_NC; ++c){
    Hp[c] = h;
    h = Ep[c] * h + Fp[c];
  }
}

__global__ __launch_bounds__(256) void k_scan3(
  const float* __restrict__ delta, const float* __restrict__ dxc,
  const float* __restrict__ xc, const float* __restrict__ xdbl,
  const void* __restrict__ Alog, const void* __restrict__ Dp,
  const float* __restrict__ Hin, float* __restrict__ y,
  int L, const int* __restrict__ flagp)
{
  int fl = *flagp;
  int tid = threadIdx.x;
  int g = tid >> 4, n = tid & 15;
  int gid = blockIdx.x * 16 + g;
  int chunk = gid & (SC_NC - 1);
  int p = gid >> 5;
  int b = p >> 8, d = p & 255;
  float A = -__expf(ldw(Alog, d*16 + n, fl));
  float Dv = ldw(Dp, d, fl);
  const float* dtp = delta + (long)b*L*256 + d;
  const float* dxp = dxc   + (long)b*L*256 + d;
  const float* xcb = xc    + (long)b*L*256 + d;
  const float* xdb = xdbl + (long)b*L*48;
  float* yb = y + (long)b*L*256 + d;
  long idx = (long)(p*16 + n) * SC_NC + chunk;
  float h = Hin[idx];
  int l0 = chunk * SC_CS;
  for (int i = 0; i < SC_CS; ++i){
    int l = l0 + i;
    float e = __expf(dtp[(long)l*256] * A);
    h = e * h + dxp[(long)l*256] * xdb[l*48 + 16 + n];
    float part = h * xdb[l*48 + 32 + n];
    part += __shfl_xor(part, 1, 16);
    part += __shfl_xor(part, 2, 16);
    part += __shfl_xor(part, 4, 16);
    part += __shfl_xor(part, 8, 16);
    if (n == 0) yb[(long)l*256] = part + Dv * xcb[(long)l*256];
  }
}

// ---------------- LayerNorm over rows of 512 (in place) ----------------
__global__ __launch_bounds__(256) void k_ln(float* __restrict__ h,
                                            const void* __restrict__ g,
                                            const void* __restrict__ beta,
                                            const int* __restrict__ flagp)
{
  int fl = *flagp;
  int row = blockIdx.x * 4 + (threadIdx.x >> 6);
  int lane = threadIdx.x & 63;
  float* hr = h + (long)row * 512;
  float v[8]; float s = 0.f, ss = 0.f;
  #pragma unroll
  for (int i = 0; i < 8; ++i){ v[i] = hr[lane + 64*i]; s += v[i]; ss += v[i]*v[i]; }
  #pragma unroll
  for (int off = 1; off < 64; off <<= 1){ s += __shfl_xor(s, off); ss += __shfl_xor(ss, off); }
  float mean = s * (1.f/512.f);
  float var  = ss * (1.f/512.f) - mean * mean;
  float rs = rsqrtf(var + 1e-5f);
  #pragma unroll
  for (int i = 0; i < 8; ++i){
    int c = lane + 64*i;
    hr[c] = (v[i] - mean) * rs * ldw(g, c, fl) + ldw(beta, c, fl);
  }
}

extern "C" void kernel_launch(void* const* d_in, const int* in_sizes, int n_in,
                              void* d_out, int out_size, void* d_ws, size_t ws_size,
                              hipStream_t stream)
{
  const int B_ = 2, L_ = 2048, H_ = 4;
  const long BLE = (long)B_ * L_ * 256;       // 1,048,576
  const long BHL = (long)B_ * H_ * L_;        // 16,384
  int* flagp = (int*)d_ws;
  float* base = (float*)d_ws + 64;
  float* x    = base + 0*BLE;
  float* dbuf[2] = { base + 1*BLE, base + 2*BLE };
  float* cat  = base + 3*BLE;                 // 4 BLE; qkv staging + attn O-partials
  float* qb   = base + 7*BLE;                 // also dt/delta buffer
  float* kb   = base + 8*BLE;                 // also scan y output
  float* vb   = base + 9*BLE;                 // also scan scratch (E/F/Hin)
  float* ob   = base + 10*BLE;
  float* hbuf = base + 11*BLE;                // 2 BLE; attn (m,l) + xz + dxc + FFN hidden
  float* xcb  = base + 13*BLE;
  float* zcb  = base + 14*BLE;
  float* xdbl = base + 15*BLE;

  const long SCN = (long)2 * 256 * 16 * SC_NC;
  float* scE = vb;
  float* scF = vb + SCN;
  float* scH = vb + 2*SCN;
  float* mml = hbuf;                 // attention (m,l) scratch: 8*BHL floats
  float* mll = hbuf + 4*BHL;
  float* dxc = hbuf;                 // scan dxc (hbuf free between conv and FFN)

  const void* in[35];
  for (int i = 0; i < 35 && i < n_in; ++i) in[i] = d_in[i];

  k_sniff<<<1, 256, 0, stream>>>((const unsigned int*)in[0], 2048, flagp);

  auto gemm = [&](const float* A, int lda, int K, int N, const void* W,
                  const void* bias, float* Cf, u16* Cb, int ldc,
                  const float* resid, int ldr, float oscale, int act, int om){
    if ((K & 63) == 0 && (N & 63) == 0){
      dim3 g(N >> 6, 64);
      k_gemm_mfma<<<g, 256, 0, stream>>>(A, lda, K, N, W, bias, Cf, Cb, ldc,
                                         resid, ldr, oscale, act, om, flagp);
    } else {
      dim3 g((N + 63) / 64, 64);
      k_gemm<<<g, 256, 0, stream>>>(A, lda, K, N, W, bias, Cf, Cb, ldc,
                                    resid, ldr, oscale, act, om, flagp);
    }
  };

  const long sbP = (long)H_ * L_ * 64, shP = (long)L_ * 64, slP = 64;   // (B,H,L,64)
  const long sbF = (long)L_ * 256,     shF = 64,            slF = 256;  // (B,L,256)
  const dim3 gAttn(L_/64, B_*H_, 4);
  const int kchunk = L_ / 4;

  // ---------------- per-descriptor: mamba_attention ----------------
  for (int i = 0; i < 2; ++i){
    float* d = dbuf[i];
    k_cvt<<<(int)(BLE/256), 256, 0, stream>>>(in[i], x, BLE, flagp);
    gemm(x, 256, 256, 768, in[4], in[5], cat, nullptr, 768, nullptr, 0, 1.f, 0, 0);
    k_rope<<<dim3(L_/4, B_*H_), 256, 0, stream>>>(cat, in[2+i], qb, kb, vb, L_, B_, H_, flagp);
    k_attn_mfma<<<gAttn, 256, 0, stream>>>(qb, sbP, shP, slP,
                                           kb, sbP, shP, slP,
                                           vb, sbP, shP, slP,
                                           cat, mml, mll, 0.125f, L_, H_, kchunk);
    k_attn_comb<<<(int)(BLE/256), 256, 0, stream>>>(cat, mml, mll, ob, BHL);
    gemm(x, 256, 256, 512, in[14], nullptr, hbuf, nullptr, 512, nullptr, 0, 1.f, 0, 0); // xz
    k_conv<<<B_*L_, 256, 0, stream>>>(hbuf, 0,   in[15], xcb, L_, flagp);
    k_conv<<<B_*L_, 256, 0, stream>>>(hbuf, 256, in[16], zcb, L_, flagp);
    gemm(xcb, 256, 256, 48, in[17], nullptr, xdbl, nullptr, 48, nullptr, 0, 1.f, 0, 0);
    gemm(xdbl, 48, 16, 256, in[18], in[19], qb, nullptr, 256, nullptr, 0, 1.f, 0, 0);    // dt
    k_sp<<<(int)(BLE/256), 256, 0, stream>>>(qb, xcb, dxc, in[19], flagp);               // delta, dxc
    k_scan1<<<1024, 256, 0, stream>>>(qb, dxc, xdbl, in[20], scE, scF, L_, flagp);
    k_scan2<<<32, 256, 0, stream>>>(scE, scF, scH);
    k_scan3<<<1024, 256, 0, stream>>>(qb, dxc, xcb, xdbl, in[20], in[21], scH, kb, L_, flagp);
    gemm(kb, 256, 256, 256, in[22], nullptr, cat + 512, nullptr, 1024, nullptr, 0, 1.f, 0, 0);
    gemm(zcb, 256, 256, 256, in[22], nullptr, cat + 768, nullptr, 1024, nullptr, 0, 1.f, 0, 0);
    gemm(ob, 256, 256, 256, in[6], in[7],   cat + 256, nullptr, 1024, nullptr, 0, 1.f, 0, 0);
    k_copyc<<<(int)(BLE/256), 256, 0, stream>>>(x, cat, 1024);
    gemm(cat, 1024, 1024, 512, in[8], in[9], hbuf, nullptr, 512, nullptr, 0, 1.f, 0, 0);
    k_ln<<<1024, 256, 0, stream>>>(hbuf, in[10], in[11], flagp);
    gemm(hbuf, 512, 512, 256, in[12], in[13], d, nullptr, 256, x, 256, 1.f, 1, 0);
  }

  // ---------------- cross attention ----------------
  const float s4 = 0.35355339059327373f;  // 64^-0.25
  gemm(dbuf[0], 256, 256, 256, in[23], in[24], qb, nullptr, 256, nullptr, 0, s4, 0, 0);
  gemm(dbuf[1], 256, 256, 256, in[23], in[24], kb, nullptr, 256, nullptr, 0, s4, 0, 0);
  gemm(dbuf[0], 256, 256, 256, in[25], in[26], vb, nullptr, 256, nullptr, 0, 1.f, 0, 0);
  gemm(dbuf[1], 256, 256, 256, in[25], in[26], ob, nullptr, 256, nullptr, 0, 1.f, 0, 0);
  k_attn_mfma<<<gAttn, 256, 0, stream>>>(qb, sbF, shF, slF, kb, sbF, shF, slF,
                                         ob, sbF, shF, slF, cat, mml, mll, 1.f, L_, H_, kchunk);
  k_attn_comb<<<(int)(BLE/256), 256, 0, stream>>>(cat, mml, mll, xcb, BHL);
  k_attn_mfma<<<gAttn, 256, 0, stream>>>(kb, sbF, shF, slF, qb, sbF, shF, slF,
                                         vb, sbF, shF, slF, cat, mml, mll, 1.f, L_, H_, kchunk);
  k_attn_comb<<<(int)(BLE/256), 256, 0, stream>>>(cat, mml, mll, zcb, BHL);
  for (int i = 0; i < 2; ++i){
    float* mi = (i == 0) ? xcb : zcb;
    k_copyc<<<(int)(BLE/256), 256, 0, stream>>>(dbuf[i], cat, 512);
    gemm(mi, 256, 256, 256, in[27], in[28], cat + 256, nullptr, 512, nullptr, 0, 1.f, 0, 0);
    gemm(cat, 512, 512, 512, in[29], in[30], hbuf, nullptr, 512, nullptr, 0, 1.f, 0, 0);
    k_ln<<<1024, 256, 0, stream>>>(hbuf, in[31], in[32], flagp);
    gemm(hbuf, 512, 512, 256, in[33], in[34],
         (float*)d_out + (long)i * BLE, (u16*)d_out + (long)i * BLE, 256,
         dbuf[i], 256, 1.f, 1, 2);
  }
}

// Round 10
// 908.671 us; speedup vs baseline: 6.5983x; 1.1419x over previous
//
#include <hip/hip_runtime.h>

typedef unsigned short u16;
typedef short s16;
typedef s16 s16x8 __attribute__((ext_vector_type(8)));
typedef float f32x4 __attribute__((ext_vector_type(4)));

__device__ __forceinline__ float bf2f(u16 u){
  union { unsigned int i; float f; } v; v.i = ((unsigned int)u) << 16; return v.f;
}
__device__ __forceinline__ u16 f2bf(float f){
  union { float f; unsigned int u; } v; v.f = f;
  unsigned int r = (v.u + 0x7fffu + ((v.u >> 16) & 1u)) >> 16;
  return (u16)r;
}
__device__ __forceinline__ float gelu_f(float x){
  return 0.5f * x * (1.f + erff(x * 0.70710678118654752440f));
}
__device__ __forceinline__ float ldw(const void* p, long i, int fl){
  return fl ? bf2f(((const u16*)p)[i]) : ((const float*)p)[i];
}
__device__ __forceinline__ float4 ldw4(const void* p, long i, int fl){
  if (fl){
    ushort4 w = *(const ushort4*)((const u16*)p + i);
    return make_float4(bf2f(w.x), bf2f(w.y), bf2f(w.z), bf2f(w.w));
  }
  return *(const float4*)((const float*)p + i);
}

// ---------------- dtype sniffer ----------------
__global__ __launch_bounds__(256) void k_sniff(const unsigned int* __restrict__ w,
                                               int n, int* __restrict__ flag){
  __shared__ int cnt[256];
  int c = 0;
  for (int i = threadIdx.x; i < n; i += 256){
    unsigned e = (w[i] >> 7) & 0xFFu;
    c += (e >= 120u && e <= 127u) ? 1 : 0;
  }
  cnt[threadIdx.x] = c; __syncthreads();
  for (int s = 128; s > 0; s >>= 1){
    if (threadIdx.x < s) cnt[threadIdx.x] += cnt[threadIdx.x + s];
    __syncthreads();
  }
  if (threadIdx.x == 0) *flag = (2 * cnt[0] > n) ? 1 : 0;
}

// ---------------- convert input activations -> f32 ----------------
__global__ __launch_bounds__(256) void k_cvt(const void* __restrict__ src,
                                             float* __restrict__ dst, long n,
                                             const int* __restrict__ flagp){
  int fl = *flagp;
  long i = (long)blockIdx.x * 256 + threadIdx.x;
  if (i < n) dst[i] = ldw(src, i, fl);
}

// ---------------- fallback fp32 GEMM (K or N not mult of 64) ----------------
__global__ __launch_bounds__(256) void k_gemm(
  const float* __restrict__ A, int lda, int K, int N,
  const void* __restrict__ W, const void* __restrict__ bias,
  float* __restrict__ Cf, int ldc, const int* __restrict__ flagp)
{
  const int fl = *flagp;
  __shared__ float As[16][65];
  __shared__ float Bs[16][65];
  int tid = threadIdx.x;
  int m0 = blockIdx.y << 6, n0 = blockIdx.x << 6;
  int tx = tid & 15, ty = tid >> 4;
  int ar = tid >> 2;
  int ak = (tid & 3) << 2;
  float acc[4][4];
  #pragma unroll
  for (int i = 0; i < 4; ++i)
    #pragma unroll
    for (int j = 0; j < 4; ++j) acc[i][j] = 0.f;

  for (int k0 = 0; k0 < K; k0 += 16){
    float4 av = *(const float4*)(A + (long)(m0 + ar) * lda + k0 + ak);
    As[ak+0][ar] = av.x; As[ak+1][ar] = av.y;
    As[ak+2][ar] = av.z; As[ak+3][ar] = av.w;
    int gn = n0 + ar;
    float4 bv = make_float4(0.f, 0.f, 0.f, 0.f);
    if (gn < N) bv = ldw4(W, (long)gn * K + k0 + ak, fl);
    Bs[ak+0][ar] = bv.x; Bs[ak+1][ar] = bv.y;
    Bs[ak+2][ar] = bv.z; Bs[ak+3][ar] = bv.w;
    __syncthreads();
    #pragma unroll
    for (int kk = 0; kk < 16; ++kk){
      float a[4], b[4];
      #pragma unroll
      for (int i = 0; i < 4; ++i){ a[i] = As[kk][ty + 16*i]; b[i] = Bs[kk][tx + 16*i]; }
      #pragma unroll
      for (int i = 0; i < 4; ++i)
        #pragma unroll
        for (int j = 0; j < 4; ++j) acc[i][j] += a[i] * b[j];
    }
    __syncthreads();
  }
  #pragma unroll
  for (int i = 0; i < 4; ++i){
    int gm = m0 + ty + 16*i;
    #pragma unroll
    for (int j = 0; j < 4; ++j){
      int gn = n0 + tx + 16*j;
      if (gn < N){
        float v = acc[i][j];
        if (bias) v += ldw(bias, gn, fl);
        Cf[(long)gm * ldc + gn] = v;
      }
    }
  }
}

// ---------------- MFMA GEMM (+split output, +concat-copy fusion) ----------------
// C = act(A) @ W^T (+bias)*oscale (+resid); cols >= nsplit go to C2 (raw, W2).
__global__ __launch_bounds__(256) void k_gemm_mfma(
  const float* __restrict__ A, int lda, int K, int N,
  const void* __restrict__ W, const void* __restrict__ W2, int nsplit,
  const void* __restrict__ bias,
  float* __restrict__ Cf, u16* __restrict__ Cb, int ldc,
  float* __restrict__ C2, int ldc2,
  const float* __restrict__ resid, int ldr,
  const float* __restrict__ csrc, float* __restrict__ cdst,
  float oscale, int act_gelu, int outmode, const int* __restrict__ flagp)
{
  const int fl = *flagp;
  __shared__ u16 As[64*72];
  __shared__ u16 Bs[64*72];
  const int tid = threadIdx.x;
  const int w = tid >> 6, lane = tid & 63, quad = lane >> 4, m = lane & 15;
  const int m0 = blockIdx.y << 6, n0 = blockIdx.x << 6;
  const int srow = tid >> 2, sc0 = (tid & 3) << 4;
  const int reg2 = (n0 >= nsplit);
  const void* Wp = reg2 ? W2 : W;
  const int nbase = reg2 ? nsplit : 0;

  f32x4 acc[4];
  #pragma unroll
  for (int ct = 0; ct < 4; ++ct) acc[ct] = (f32x4){0.f,0.f,0.f,0.f};

  for (int k0 = 0; k0 < K; k0 += 64){
    {
      const float* ar = A + (long)(m0 + srow) * lda + k0 + sc0;
      #pragma unroll
      for (int g = 0; g < 2; ++g){
        float4 a0 = *(const float4*)(ar + g*8);
        float4 a1 = *(const float4*)(ar + g*8 + 4);
        if (act_gelu){
          a0.x=gelu_f(a0.x); a0.y=gelu_f(a0.y); a0.z=gelu_f(a0.z); a0.w=gelu_f(a0.w);
          a1.x=gelu_f(a1.x); a1.y=gelu_f(a1.y); a1.z=gelu_f(a1.z); a1.w=gelu_f(a1.w);
        }
        union { u16 h[8]; uint4 v; } pk;
        pk.h[0]=f2bf(a0.x); pk.h[1]=f2bf(a0.y); pk.h[2]=f2bf(a0.z); pk.h[3]=f2bf(a0.w);
        pk.h[4]=f2bf(a1.x); pk.h[5]=f2bf(a1.y); pk.h[6]=f2bf(a1.z); pk.h[7]=f2bf(a1.w);
        *(uint4*)&As[srow*72 + sc0 + g*8] = pk.v;
      }
    }
    {
      long wb = (long)(n0 + srow - nbase) * K + k0 + sc0;
      #pragma unroll
      for (int g = 0; g < 2; ++g){
        float4 b0 = ldw4(Wp, wb + g*8, fl);
        float4 b1 = ldw4(Wp, wb + g*8 + 4, fl);
        union { u16 h[8]; uint4 v; } pk;
        pk.h[0]=f2bf(b0.x); pk.h[1]=f2bf(b0.y); pk.h[2]=f2bf(b0.z); pk.h[3]=f2bf(b0.w);
        pk.h[4]=f2bf(b1.x); pk.h[5]=f2bf(b1.y); pk.h[6]=f2bf(b1.z); pk.h[7]=f2bf(b1.w);
        *(uint4*)&Bs[srow*72 + sc0 + g*8] = pk.v;
      }
    }
    __syncthreads();

    s16x8 av[2];
    #pragma unroll
    for (int s = 0; s < 2; ++s)
      av[s] = *(const s16x8*)&As[(w*16 + m)*72 + s*32 + quad*8];
    #pragma unroll
    for (int ct = 0; ct < 4; ++ct)
      #pragma unroll
      for (int s = 0; s < 2; ++s){
        s16x8 bv = *(const s16x8*)&Bs[(ct*16 + m)*72 + s*32 + quad*8];
        acc[ct] = __builtin_amdgcn_mfma_f32_16x16x32_bf16(av[s], bv, acc[ct], 0, 0, 0);
      }
    __syncthreads();
  }

  #pragma unroll
  for (int r = 0; r < 4; ++r){
    int gm = m0 + w*16 + quad*4 + r;
    #pragma unroll
    for (int ct = 0; ct < 4; ++ct){
      int gn = n0 + ct*16 + m;
      float v = acc[ct][r];
      if (reg2){
        C2[(long)gm * ldc2 + (gn - nsplit)] = v;
      } else {
        if (bias) v += ldw(bias, gn, fl);
        v *= oscale;
        if (resid) v += resid[(long)gm * ldr + gn];
        long off = (long)gm * ldc + gn;
        if (outmode == 2){
          if (fl) Cb[off] = f2bf(v); else Cf[off] = v;
        } else {
          Cf[off] = v;
        }
        if (cdst) cdst[(long)gm * ldc + gn] = csrc[(long)gm * 256 + gn];
      }
    }
  }
}

// ---------------- z-batched MFMA GEMM (up to 4 independent problems) ----------------
struct GB4 {
  const float* A[4]; const void* W[4]; const void* bias[4];
  float* Cf[4]; u16* Cb[4]; const float* resid[4];
  const float* csrc[4]; float* cdst[4]; float osc[4];
};

__global__ __launch_bounds__(256) void k_gemmb(
  GB4 gb, int lda, int K, int N, int ldc, int ldr,
  int act_gelu, int outmode, const int* __restrict__ flagp)
{
  const int fl = *flagp;
  const int z = blockIdx.z;
  const float* A = gb.A[z]; const void* W = gb.W[z]; const void* bias = gb.bias[z];
  float* Cf = gb.Cf[z]; u16* Cb = gb.Cb[z]; const float* resid = gb.resid[z];
  const float* csrc = gb.csrc[z]; float* cdst = gb.cdst[z];
  const float osc = gb.osc[z];

  __shared__ u16 As[64*72];
  __shared__ u16 Bs[64*72];
  const int tid = threadIdx.x;
  const int w = tid >> 6, lane = tid & 63, quad = lane >> 4, m = lane & 15;
  const int m0 = blockIdx.y << 6, n0 = blockIdx.x << 6;
  const int srow = tid >> 2, sc0 = (tid & 3) << 4;

  f32x4 acc[4];
  #pragma unroll
  for (int ct = 0; ct < 4; ++ct) acc[ct] = (f32x4){0.f,0.f,0.f,0.f};

  for (int k0 = 0; k0 < K; k0 += 64){
    {
      const float* ar = A + (long)(m0 + srow) * lda + k0 + sc0;
      #pragma unroll
      for (int g = 0; g < 2; ++g){
        float4 a0 = *(const float4*)(ar + g*8);
        float4 a1 = *(const float4*)(ar + g*8 + 4);
        if (act_gelu){
          a0.x=gelu_f(a0.x); a0.y=gelu_f(a0.y); a0.z=gelu_f(a0.z); a0.w=gelu_f(a0.w);
          a1.x=gelu_f(a1.x); a1.y=gelu_f(a1.y); a1.z=gelu_f(a1.z); a1.w=gelu_f(a1.w);
        }
        union { u16 h[8]; uint4 v; } pk;
        pk.h[0]=f2bf(a0.x); pk.h[1]=f2bf(a0.y); pk.h[2]=f2bf(a0.z); pk.h[3]=f2bf(a0.w);
        pk.h[4]=f2bf(a1.x); pk.h[5]=f2bf(a1.y); pk.h[6]=f2bf(a1.z); pk.h[7]=f2bf(a1.w);
        *(uint4*)&As[srow*72 + sc0 + g*8] = pk.v;
      }
    }
    {
      long wb = (long)(n0 + srow) * K + k0 + sc0;
      #pragma unroll
      for (int g = 0; g < 2; ++g){
        float4 b0 = ldw4(W, wb + g*8, fl);
        float4 b1 = ldw4(W, wb + g*8 + 4, fl);
        union { u16 h[8]; uint4 v; } pk;
        pk.h[0]=f2bf(b0.x); pk.h[1]=f2bf(b0.y); pk.h[2]=f2bf(b0.z); pk.h[3]=f2bf(b0.w);
        pk.h[4]=f2bf(b1.x); pk.h[5]=f2bf(b1.y); pk.h[6]=f2bf(b1.z); pk.h[7]=f2bf(b1.w);
        *(uint4*)&Bs[srow*72 + sc0 + g*8] = pk.v;
      }
    }
    __syncthreads();

    s16x8 av[2];
    #pragma unroll
    for (int s = 0; s < 2; ++s)
      av[s] = *(const s16x8*)&As[(w*16 + m)*72 + s*32 + quad*8];
    #pragma unroll
    for (int ct = 0; ct < 4; ++ct)
      #pragma unroll
      for (int s = 0; s < 2; ++s){
        s16x8 bv = *(const s16x8*)&Bs[(ct*16 + m)*72 + s*32 + quad*8];
        acc[ct] = __builtin_amdgcn_mfma_f32_16x16x32_bf16(av[s], bv, acc[ct], 0, 0, 0);
      }
    __syncthreads();
  }

  #pragma unroll
  for (int r = 0; r < 4; ++r){
    int gm = m0 + w*16 + quad*4 + r;
    #pragma unroll
    for (int ct = 0; ct < 4; ++ct){
      int gn = n0 + ct*16 + m;
      float v = acc[ct][r];
      if (bias) v += ldw(bias, gn, fl);
      v *= osc;
      if (resid) v += resid[(long)gm * ldr + gn];
      long off = (long)gm * ldc + gn;
      if (outmode == 2){
        if (fl) Cb[off] = f2bf(v); else Cf[off] = v;
      } else {
        Cf[off] = v;
      }
      if (cdst) cdst[(long)gm * ldc + gn] = csrc[(long)gm * 256 + gn];
    }
  }
}

// ---------------- QKV extract + rotary ----------------
__global__ __launch_bounds__(256) void k_rope(
  const float* __restrict__ qkv, const void* __restrict__ pe,
  float* __restrict__ q, float* __restrict__ k, float* __restrict__ v,
  int L, int B, int H, const int* __restrict__ flagp)
{
  int fl = *flagp;
  int tid = threadIdx.x;
  int lq = tid >> 6, d = tid & 63;
  int l = blockIdx.x * 4 + lq;
  int bh = blockIdx.y; int b = bh / H; int h = bh % H;
  const float* row = qkv + ((long)b * L + l) * 768 + h * 192;
  float qv = row[d*3+0], kv = row[d*3+1], vv = row[d*3+2];
  int dn = (d & 1) ? (d - 1) : (d + 1);
  float qn = row[dn*3+0], kn = row[dn*3+1];
  float rq = (d & 1) ? qn : -qn;
  float rk = (d & 1) ? kn : -kn;
  long peo = ((long)b * L + l) * 64 + d;
  float p0 = ldw(pe, peo, fl);
  float p1 = ldw(pe, (long)B * L * 64 + peo, fl);
  long o = ((long)bh * L + l) * 64 + d;
  q[o] = qv * p0 + rq * p1;
  k[o] = kv * p0 + rk * p1;
  v[o] = vv;
}

// ---------------- MFMA flash attention with K-split, DH=64 ----------------
__global__ __launch_bounds__(256) void k_attn_mfma(
  const float* __restrict__ Q, long qsb, long qsh, long qsl,
  const float* __restrict__ Kp, long ksb, long ksh, long ksl,
  const float* __restrict__ Vp, long vsb, long vsh, long vsl,
  float* __restrict__ Opart, float* __restrict__ mpart, float* __restrict__ lpart,
  float scale, int L, int H, int kchunk)
{
  __shared__ u16 Kt[64*72];     // K tile; re-used as P tile after QK phase
  __shared__ u16 Vt[64*72];
  u16* Ps = Kt;
  const int tid  = threadIdx.x;
  const int w    = tid >> 6;
  const int lane = tid & 63;
  const int quad = lane >> 4;
  const int m    = lane & 15;
  const int bh = blockIdx.y, b = bh / H, h = bh % H;
  const int iq0 = blockIdx.x * 64;
  const int z = blockIdx.z;
  const long BHL = (long)gridDim.y * L;

  const float* Qb = Q  + b*qsb + h*qsh;
  const float* Kb = Kp + b*ksb + h*ksh;
  const float* Vb = Vp + b*vsb + h*vsh;

  s16x8 aq[2];
  {
    const float* qr = Qb + (long)(iq0 + w*16 + m) * qsl + quad*8;
    #pragma unroll
    for (int s = 0; s < 2; ++s){
      float4 a0 = *(const float4*)(qr + s*32);
      float4 a1 = *(const float4*)(qr + s*32 + 4);
      s16x8 t;
      t[0]=(s16)f2bf(a0.x*scale); t[1]=(s16)f2bf(a0.y*scale);
      t[2]=(s16)f2bf(a0.z*scale); t[3]=(s16)f2bf(a0.w*scale);
      t[4]=(s16)f2bf(a1.x*scale); t[5]=(s16)f2bf(a1.y*scale);
      t[6]=(s16)f2bf(a1.z*scale); t[7]=(s16)f2bf(a1.w*scale);
      aq[s] = t;
    }
  }

  f32x4 o_acc[4];
  #pragma unroll
  for (int nt = 0; nt < 4; ++nt) o_acc[nt] = (f32x4){0.f,0.f,0.f,0.f};
  float mrow[4] = {-1e30f,-1e30f,-1e30f,-1e30f};
  float lrow[4] = {0.f,0.f,0.f,0.f};

  const int srow = tid >> 2, sc0 = (tid & 3) << 4;
  const int jend = (z + 1) * kchunk;

  for (int j0 = z * kchunk; j0 < jend; j0 += 64){
    {
      const float* kr = Kb + (long)(j0 + srow) * ksl + sc0;
      #pragma unroll
      for (int g = 0; g < 2; ++g){
        float4 a0 = *(const float4*)(kr + g*8);
        float4 a1 = *(const float4*)(kr + g*8 + 4);
        union { u16 h[8]; uint4 v; } pk;
        pk.h[0]=f2bf(a0.x); pk.h[1]=f2bf(a0.y); pk.h[2]=f2bf(a0.z); pk.h[3]=f2bf(a0.w);
        pk.h[4]=f2bf(a1.x); pk.h[5]=f2bf(a1.y); pk.h[6]=f2bf(a1.z); pk.h[7]=f2bf(a1.w);
        *(uint4*)&Kt[srow*72 + sc0 + g*8] = pk.v;
      }
      const float* vr = Vb + (long)(j0 + srow) * vsl + sc0;
      #pragma unroll
      for (int g = 0; g < 4; ++g){
        float4 a0 = *(const float4*)(vr + g*4);
        Vt[(sc0 + g*4 + 0)*72 + srow] = f2bf(a0.x);
        Vt[(sc0 + g*4 + 1)*72 + srow] = f2bf(a0.y);
        Vt[(sc0 + g*4 + 2)*72 + srow] = f2bf(a0.z);
        Vt[(sc0 + g*4 + 3)*72 + srow] = f2bf(a0.w);
      }
    }
    __syncthreads();

    float sv[4][4];
    #pragma unroll
    for (int ct = 0; ct < 4; ++ct){
      f32x4 acc = (f32x4){0.f,0.f,0.f,0.f};
      #pragma unroll
      for (int s = 0; s < 2; ++s){
        s16x8 bk = *(const s16x8*)&Kt[(ct*16 + m)*72 + s*32 + quad*8];
        acc = __builtin_amdgcn_mfma_f32_16x16x32_bf16(aq[s], bk, acc, 0, 0, 0);
      }
      #pragma unroll
      for (int r = 0; r < 4; ++r) sv[ct][r] = acc[r];
    }

    float mn[4], alpha[4], rsum[4];
    #pragma unroll
    for (int r = 0; r < 4; ++r){
      float v0 = fmaxf(fmaxf(sv[0][r], sv[1][r]), fmaxf(sv[2][r], sv[3][r]));
      v0 = fmaxf(v0, __shfl_xor(v0, 1));
      v0 = fmaxf(v0, __shfl_xor(v0, 2));
      v0 = fmaxf(v0, __shfl_xor(v0, 4));
      v0 = fmaxf(v0, __shfl_xor(v0, 8));
      mn[r] = fmaxf(mrow[r], v0);
      alpha[r] = __expf(mrow[r] - mn[r]);
      mrow[r] = mn[r];
      rsum[r] = 0.f;
    }
    #pragma unroll
    for (int ct = 0; ct < 4; ++ct)
      #pragma unroll
      for (int r = 0; r < 4; ++r){
        float p = __expf(sv[ct][r] - mn[r]);
        sv[ct][r] = p;
        rsum[r] += p;
      }
    #pragma unroll
    for (int r = 0; r < 4; ++r){
      float s = rsum[r];
      s += __shfl_xor(s, 1);
      s += __shfl_xor(s, 2);
      s += __shfl_xor(s, 4);
      s += __shfl_xor(s, 8);
      lrow[r] = lrow[r] * alpha[r] + s;
    }
    #pragma unroll
    for (int nt = 0; nt < 4; ++nt)
      #pragma unroll
      for (int r = 0; r < 4; ++r) o_acc[nt][r] *= alpha[r];

    __syncthreads();   // all waves done reading Kt before P overwrites it

    #pragma unroll
    for (int ct = 0; ct < 4; ++ct)
      #pragma unroll
      for (int r = 0; r < 4; ++r)
        Ps[(w*16 + quad*4 + r)*72 + ct*16 + m] = f2bf(sv[ct][r]);
    asm volatile("s_waitcnt lgkmcnt(0)" ::: "memory");  // own-wave rows RAW

    s16x8 ap[2];
    #pragma unroll
    for (int s = 0; s < 2; ++s)
      ap[s] = *(const s16x8*)&Ps[(w*16 + m)*72 + s*32 + quad*8];
    #pragma unroll
    for (int nt = 0; nt < 4; ++nt)
      #pragma unroll
      for (int s = 0; s < 2; ++s){
        s16x8 bv = *(const s16x8*)&Vt[(nt*16 + m)*72 + s*32 + quad*8];
        o_acc[nt] = __builtin_amdgcn_mfma_f32_16x16x32_bf16(ap[s], bv, o_acc[nt], 0, 0, 0);
      }
    __syncthreads();
  }

  const long zOoff = (long)z * BHL * 64;
  #pragma unroll
  for (int r = 0; r < 4; ++r){
    int iq = iq0 + w*16 + quad*4 + r;
    long rowid = ((long)b*L + iq) * H + h;
    #pragma unroll
    for (int nt = 0; nt < 4; ++nt)
      Opart[zOoff + rowid*64 + nt*16 + m] = o_acc[nt][r];
    if (m == 0){
      mpart[(long)z*BHL + rowid] = mrow[r];
      lpart[(long)z*BHL + rowid] = lrow[r];
    }
  }
}

// ---------------- attention split combine ----------------
__global__ __launch_bounds__(256) void k_attn_comb(
  const float* __restrict__ Opart, const float* __restrict__ mpart,
  const float* __restrict__ lpart, float* __restrict__ O, long BHL)
{
  long i = (long)blockIdx.x * 256 + threadIdx.x;
  long row = i >> 6;
  float m0 = mpart[row],         m1 = mpart[BHL + row];
  float m2 = mpart[2*BHL + row], m3 = mpart[3*BHL + row];
  float M = fmaxf(fmaxf(m0, m1), fmaxf(m2, m3));
  float w0 = __expf(m0 - M), w1 = __expf(m1 - M);
  float w2 = __expf(m2 - M), w3 = __expf(m3 - M);
  float T = lpart[row]*w0 + lpart[BHL+row]*w1 + lpart[2*BHL+row]*w2 + lpart[3*BHL+row]*w3;
  long N64 = BHL * 64;
  float acc = Opart[i]*w0 + Opart[N64 + i]*w1 + Opart[2*N64 + i]*w2 + Opart[3*N64 + i]*w3;
  O[i] = acc / T;
}

// ---------------- depthwise conv K=5 SAME + silu (+optional concat copy) ----
__global__ __launch_bounds__(256) void k_conv(
  const float* __restrict__ xz, int choff, const void* __restrict__ w,
  float* __restrict__ out, int L, const int* __restrict__ flagp)
{
  int fl = *flagp;
  int c = threadIdx.x;
  int bl = blockIdx.x; int b = bl / L, l = bl % L;
  const float* base = xz + ((long)b * L) * 512 + choff + c;
  float s = 0.f;
  #pragma unroll
  for (int kk = 0; kk < 5; ++kk){
    int ll = l + kk - 2;
    if (ll >= 0 && ll < L) s += base[(long)ll * 512] * ldw(w, c*5 + kk, fl);
  }
  out[((long)b * L + l) * 256 + c] = s / (1.f + __expf(-s));   // silu
}

// ---------------- softplus precompute ----------------
__global__ __launch_bounds__(256) void k_sp(
  float* __restrict__ dt, const float* __restrict__ xc,
  float* __restrict__ dxc, const void* __restrict__ dtb,
  const int* __restrict__ flagp)
{
  int fl = *flagp;
  long i = (long)blockIdx.x * 256 + threadIdx.x;
  int d = (int)(i & 255);
  float dl = dt[i] + ldw(dtb, d, fl);
  float delta = (dl > 20.f) ? dl : __logf(1.f + __expf(dl));
  dt[i] = delta;
  dxc[i] = delta * xc[i];
}

// ---------------- chunk-parallel selective scan ----------------
#define SC_CS 64
#define SC_NC 32

__global__ __launch_bounds__(256) void k_scan1(
  const float* __restrict__ delta, const float* __restrict__ dxc,
  const float* __restrict__ xdbl, const void* __restrict__ Alog,
  float* __restrict__ E_out, float* __restrict__ F_out,
  int L, const int* __restrict__ flagp)
{
  int fl = *flagp;
  int tid = threadIdx.x;
  int g = tid >> 4, n = tid & 15;
  int gid = blockIdx.x * 16 + g;
  int chunk = gid & (SC_NC - 1);
  int p = gid >> 5;
  int b = p >> 8, d = p & 255;
  float A = -__expf(ldw(Alog, d*16 + n, fl));
  const float* dtp = delta + (long)b*L*256 + d;
  const float* dxp = dxc   + (long)b*L*256 + d;
  const float* xdb = xdbl + (long)b*L*48;
  int l0 = chunk * SC_CS;
  float E = 1.f, F = 0.f;
  for (int i = 0; i < SC_CS; i += 4){
    float e[4], u[4];
    #pragma unroll
    for (int j = 0; j < 4; ++j){
      int l = l0 + i + j;
      e[j] = __expf(dtp[(long)l*256] * A);
      u[j] = dxp[(long)l*256] * xdb[l*48 + 16 + n];
    }
    F = e[0]*F + u[0]; F = e[1]*F + u[1];
    F = e[2]*F + u[2]; F = e[3]*F + u[3];
    E *= (e[0]*e[1]) * (e[2]*e[3]);
  }
  long idx = (long)(p*16 + n) * SC_NC + chunk;
  E_out[idx] = E; F_out[idx] = F;
}

__global__ __launch_bounds__(256) void k_scan2(
  const float* __restrict__ E, const float* __restrict__ F,
  float* __restrict__ Hin)
{
  int pn = blockIdx.x * 256 + threadIdx.x;
  const float* Ep = E + (long)pn * SC_NC;
  const float* Fp = F + (long)pn * SC_NC;
  float* Hp = Hin + (long)pn * SC_NC;
  float h = 0.f;
  #pragma unroll
  for (int c = 0; c < SC_NC; ++c){
    Hp[c] = h;
    h = Ep[c] * h + Fp[c];
  }
}

__global__ __launch_bounds__(256) void k_scan3(
  const float* __restrict__ delta, const float* __restrict__ dxc,
  const float* __restrict__ xc, const float* __restrict__ xdbl,
  const void* __restrict__ Alog, const void* __restrict__ Dp,
  const float* __restrict__ Hin, float* __restrict__ y,
  int L, const int* __restrict__ flagp)
{
  int fl = *flagp;
  int tid = threadIdx.x;
  int g = tid >> 4, n = tid & 15;
  int gid = blockIdx.x * 16 + g;
  int chunk = gid & (SC_NC - 1);
  int p = gid >> 5;
  int b = p >> 8, d = p & 255;
  float A = -__expf(ldw(Alog, d*16 + n, fl));
  float Dv = ldw(Dp, d, fl);
  const float* dtp = delta + (long)b*L*256 + d;
  const float* dxp = dxc   + (long)b*L*256 + d;
  const float* xcb = xc    + (long)b*L*256 + d;
  const float* xdb = xdbl + (long)b*L*48;
  float* yb = y + (long)b*L*256 + d;
  long idx = (long)(p*16 + n) * SC_NC + chunk;
  float h = Hin[idx];
  int l0 = chunk * SC_CS;
  for (int i = 0; i < SC_CS; i += 4){
    float e[4], u[4], cm[4], xv[4];
    #pragma unroll
    for (int j = 0; j < 4; ++j){
      int l = l0 + i + j;
      e[j]  = __expf(dtp[(long)l*256] * A);
      u[j]  = dxp[(long)l*256] * xdb[l*48 + 16 + n];
      cm[j] = xdb[l*48 + 32 + n];
      xv[j] = xcb[(long)l*256];
    }
    float s0, s1, s2, s3;
    h = e[0]*h + u[0]; s0 = h * cm[0];
    h = e[1]*h + u[1]; s1 = h * cm[1];
    h = e[2]*h + u[2]; s2 = h * cm[2];
    h = e[3]*h + u[3]; s3 = h * cm[3];
    // 4 independent interleaved butterflies (latency-hidden)
    s0 += __shfl_xor(s0, 1, 16); s1 += __shfl_xor(s1, 1, 16);
    s2 += __shfl_xor(s2, 1, 16); s3 += __shfl_xor(s3, 1, 16);
    s0 += __shfl_xor(s0, 2, 16); s1 += __shfl_xor(s1, 2, 16);
    s2 += __shfl_xor(s2, 2, 16); s3 += __shfl_xor(s3, 2, 16);
    s0 += __shfl_xor(s0, 4, 16); s1 += __shfl_xor(s1, 4, 16);
    s2 += __shfl_xor(s2, 4, 16); s3 += __shfl_xor(s3, 4, 16);
    s0 += __shfl_xor(s0, 8, 16); s1 += __shfl_xor(s1, 8, 16);
    s2 += __shfl_xor(s2, 8, 16); s3 += __shfl_xor(s3, 8, 16);
    if (n < 4){
      float out = (n == 0) ? s0 + Dv*xv[0] : (n == 1) ? s1 + Dv*xv[1]
                : (n == 2) ? s2 + Dv*xv[2] : s3 + Dv*xv[3];
      yb[(long)(l0 + i + n)*256] = out;
    }
  }
}

// ---------------- LayerNorm over rows of 512 (in place) ----------------
__global__ __launch_bounds__(256) void k_ln(float* __restrict__ h,
                                            const void* __restrict__ g,
                                            const void* __restrict__ beta,
                                            const int* __restrict__ flagp)
{
  int fl = *flagp;
  int row = blockIdx.x * 4 + (threadIdx.x >> 6);
  int lane = threadIdx.x & 63;
  float* hr = h + (long)row * 512;
  float v[8]; float s = 0.f, ss = 0.f;
  #pragma unroll
  for (int i = 0; i < 8; ++i){ v[i] = hr[lane + 64*i]; s += v[i]; ss += v[i]*v[i]; }
  #pragma unroll
  for (int off = 1; off < 64; off <<= 1){ s += __shfl_xor(s, off); ss += __shfl_xor(ss, off); }
  float mean = s * (1.f/512.f);
  float var  = ss * (1.f/512.f) - mean * mean;
  float rs = rsqrtf(var + 1e-5f);
  #pragma unroll
  for (int i = 0; i < 8; ++i){
    int c = lane + 64*i;
    hr[c] = (v[i] - mean) * rs * ldw(g, c, fl) + ldw(beta, c, fl);
  }
}

// two-buffer LN (cross-attn i=0/1 batched)
__global__ __launch_bounds__(256) void k_ln2(float* __restrict__ hA, float* __restrict__ hB,
                                             const void* __restrict__ g,
                                             const void* __restrict__ beta,
                                             const int* __restrict__ flagp)
{
  int fl = *flagp;
  int r = blockIdx.x * 4 + (threadIdx.x >> 6);
  float* hbase = (r < 4096) ? hA : hB;
  int row = r & 4095;
  int lane = threadIdx.x & 63;
  float* hr = hbase + (long)row * 512;
  float v[8]; float s = 0.f, ss = 0.f;
  #pragma unroll
  for (int i = 0; i < 8; ++i){ v[i] = hr[lane + 64*i]; s += v[i]; ss += v[i]*v[i]; }
  #pragma unroll
  for (int off = 1; off < 64; off <<= 1){ s += __shfl_xor(s, off); ss += __shfl_xor(ss, off); }
  float mean = s * (1.f/512.f);
  float var  = ss * (1.f/512.f) - mean * mean;
  float rs = rsqrtf(var + 1e-5f);
  #pragma unroll
  for (int i = 0; i < 8; ++i){
    int c = lane + 64*i;
    hr[c] = (v[i] - mean) * rs * ldw(g, c, fl) + ldw(beta, c, fl);
  }
}

extern "C" void kernel_launch(void* const* d_in, const int* in_sizes, int n_in,
                              void* d_out, int out_size, void* d_ws, size_t ws_size,
                              hipStream_t stream)
{
  const int B_ = 2, L_ = 2048, H_ = 4;
  const long BLE = (long)B_ * L_ * 256;       // 1,048,576
  const long BHL = (long)B_ * H_ * L_;        // 16,384
  int* flagp = (int*)d_ws;
  float* base = (float*)d_ws + 64;
  float* x    = base + 0*BLE;
  float* dbuf[2] = { base + 1*BLE, base + 2*BLE };
  float* cat  = base + 3*BLE;                 // 4 BLE; qkv staging + attn O-partials + ca concat
  float* qb   = base + 7*BLE;                 // also dt/delta; also ca hidden B (qb+kb = 2 BLE)
  float* kb   = base + 8*BLE;                 // also scan y output
  float* vb   = base + 9*BLE;                 // also scan scratch (E/F/Hin)
  float* ob   = base + 10*BLE;
  float* hbuf = base + 11*BLE;                // 2 BLE; xz + dxc + FFN hidden
  float* xcb  = base + 13*BLE;
  float* zcb  = base + 14*BLE;
  float* xdbl = base + 15*BLE;                // 196,608 floats
  float* mml  = xdbl + 196608;                // 4*BHL
  float* mll  = mml + 4*BHL;                  // 4*BHL

  const long SCN = (long)2 * 256 * 16 * SC_NC;
  float* scE = vb;
  float* scF = vb + SCN;
  float* scH = vb + 2*SCN;
  float* dxc = hbuf;                  // hbuf free between conv and FFN
  float* catA = cat;                  // 2 BLE (4096 x 512)
  float* catB = cat + 2*BLE;
  float* hbufB = qb;                  // 2 BLE spanning qb+kb

  const void* in[35];
  for (int i = 0; i < 35 && i < n_in; ++i) in[i] = d_in[i];

  k_sniff<<<1, 256, 0, stream>>>((const unsigned int*)in[0], 2048, flagp);

  const int BIG = 1 << 30;
  auto gemm = [&](const float* A, int lda, int K, int N, const void* W,
                  const void* bias, float* Cf, u16* Cb, int ldc,
                  const float* resid, int ldr, float oscale, int act, int om,
                  const float* csrc, float* cdst){
    dim3 g(N >> 6, 64);
    k_gemm_mfma<<<g, 256, 0, stream>>>(A, lda, K, N, W, nullptr, BIG, bias,
                                       Cf, Cb, ldc, nullptr, 0, resid, ldr,
                                       csrc, cdst, oscale, act, om, flagp);
  };

  const long sbP = (long)H_ * L_ * 64, shP = (long)L_ * 64, slP = 64;   // (B,H,L,64)
  const long sbF = (long)L_ * 256,     shF = 64,            slF = 256;  // (B,L,256)
  const dim3 gAttn(L_/64, B_*H_, 4);
  const int kchunk = L_ / 4;

  // ---------------- per-descriptor: mamba_attention ----------------
  for (int i = 0; i < 2; ++i){
    float* d = dbuf[i];
    k_cvt<<<(int)(BLE/256), 256, 0, stream>>>(in[i], x, BLE, flagp);
    // merged qkv (N 0..767 -> cat ld 768) + xz (768..1279 -> hbuf ld 512)
    k_gemm_mfma<<<dim3(20, 64), 256, 0, stream>>>(
        x, 256, 256, 1280, in[4], in[14], 768, in[5],
        cat, nullptr, 768, hbuf, 512, nullptr, 0, nullptr, nullptr,
        1.f, 0, 0, flagp);
    k_rope<<<dim3(L_/4, B_*H_), 256, 0, stream>>>(cat, in[2+i], qb, kb, vb, L_, B_, H_, flagp);
    k_attn_mfma<<<gAttn, 256, 0, stream>>>(qb, sbP, shP, slP,
                                           kb, sbP, shP, slP,
                                           vb, sbP, shP, slP,
                                           cat, mml, mll, 0.125f, L_, H_, kchunk);
    k_attn_comb<<<(int)(BLE/256), 256, 0, stream>>>(cat, mml, mll, ob, BHL);
    k_conv<<<B_*L_, 256, 0, stream>>>(hbuf, 0,   in[15], xcb, L_, flagp);
    k_conv<<<B_*L_, 256, 0, stream>>>(hbuf, 256, in[16], zcb, L_, flagp);
    k_gemm<<<dim3(1, 64), 256, 0, stream>>>(xcb, 256, 256, 48, in[17], nullptr,
                                            xdbl, 48, flagp);
    k_gemm<<<dim3(4, 64), 256, 0, stream>>>(xdbl, 48, 16, 256, in[18], in[19],
                                            qb, 256, flagp);
    k_sp<<<(int)(BLE/256), 256, 0, stream>>>(qb, xcb, dxc, in[19], flagp);
    k_scan1<<<1024, 256, 0, stream>>>(qb, dxc, xdbl, in[20], scE, scF, L_, flagp);
    k_scan2<<<32, 256, 0, stream>>>(scE, scF, scH);
    k_scan3<<<1024, 256, 0, stream>>>(qb, dxc, xcb, xdbl, in[20], in[21], scH, kb, L_, flagp);
    // batched s_x / c_x into cat cols 512/768 (ld 1024)
    {
      GB4 gb = {};
      gb.A[0] = kb;  gb.W[0] = in[22]; gb.Cf[0] = cat + 512; gb.osc[0] = 1.f;
      gb.A[1] = zcb; gb.W[1] = in[22]; gb.Cf[1] = cat + 768; gb.osc[1] = 1.f;
      k_gemmb<<<dim3(4, 64, 2), 256, 0, stream>>>(gb, 256, 256, 256, 1024, 0, 0, 0, flagp);
    }
    // o-proj into cat+256 (ld 1024) + fused x->cat cols 0..255 copy
    gemm(ob, 256, 256, 256, in[6], in[7], cat + 256, nullptr, 1024,
         nullptr, 0, 1.f, 0, 0, x, cat);
    gemm(cat, 1024, 1024, 512, in[8], in[9], hbuf, nullptr, 512,
         nullptr, 0, 1.f, 0, 0, nullptr, nullptr);
    k_ln<<<1024, 256, 0, stream>>>(hbuf, in[10], in[11], flagp);
    gemm(hbuf, 512, 512, 256, in[12], in[13], d, nullptr, 256,
         x, 256, 1.f, 1, 0, nullptr, nullptr);
  }

  // ---------------- cross attention ----------------
  const float s4 = 0.35355339059327373f;  // 64^-0.25
  {
    GB4 gb = {};
    gb.A[0] = dbuf[0]; gb.W[0] = in[23]; gb.bias[0] = in[24]; gb.Cf[0] = qb; gb.osc[0] = s4;
    gb.A[1] = dbuf[1]; gb.W[1] = in[23]; gb.bias[1] = in[24]; gb.Cf[1] = kb; gb.osc[1] = s4;
    gb.A[2] = dbuf[0]; gb.W[2] = in[25]; gb.bias[2] = in[26]; gb.Cf[2] = vb; gb.osc[2] = 1.f;
    gb.A[3] = dbuf[1]; gb.W[3] = in[25]; gb.bias[3] = in[26]; gb.Cf[3] = ob; gb.osc[3] = 1.f;
    k_gemmb<<<dim3(4, 64, 4), 256, 0, stream>>>(gb, 256, 256, 256, 256, 0, 0, 0, flagp);
  }
  k_attn_mfma<<<gAttn, 256, 0, stream>>>(qb, sbF, shF, slF, kb, sbF, shF, slF,
                                         ob, sbF, shF, slF, cat, mml, mll, 1.f, L_, H_, kchunk);
  k_attn_comb<<<(int)(BLE/256), 256, 0, stream>>>(cat, mml, mll, xcb, BHL);
  k_attn_mfma<<<gAttn, 256, 0, stream>>>(kb, sbF, shF, slF, qb, sbF, shF, slF,
                                         vb, sbF, shF, slF, cat, mml, mll, 1.f, L_, H_, kchunk);
  k_attn_comb<<<(int)(BLE/256), 256, 0, stream>>>(cat, mml, mll, zcb, BHL);
  // batched mi-proj (+fused dbuf->cat copy), ffn1, ln, ffn2 for i=0/1
  {
    GB4 gb = {};
    gb.A[0] = xcb; gb.W[0] = in[27]; gb.bias[0] = in[28]; gb.Cf[0] = catA + 256;
    gb.csrc[0] = dbuf[0]; gb.cdst[0] = catA; gb.osc[0] = 1.f;
    gb.A[1] = zcb; gb.W[1] = in[27]; gb.bias[1] = in[28]; gb.Cf[1] = catB + 256;
    gb.csrc[1] = dbuf[1]; gb.cdst[1] = catB; gb.osc[1] = 1.f;
    k_gemmb<<<dim3(4, 64, 2), 256, 0, stream>>>(gb, 256, 256, 256, 512, 0, 0, 0, flagp);
  }
  {
    GB4 gb = {};
    gb.A[0] = catA; gb.W[0] = in[29]; gb.bias[0] = in[30]; gb.Cf[0] = hbuf;  gb.osc[0] = 1.f;
    gb.A[1] = catB; gb.W[1] = in[29]; gb.bias[1] = in[30]; gb.Cf[1] = hbufB; gb.osc[1] = 1.f;
    k_gemmb<<<dim3(8, 64, 2), 256, 0, stream>>>(gb, 512, 512, 512, 512, 0, 0, 0, flagp);
  }
  k_ln2<<<2048, 256, 0, stream>>>(hbuf, hbufB, in[31], in[32], flagp);
  {
    GB4 gb = {};
    gb.A[0] = hbuf;  gb.W[0] = in[33]; gb.bias[0] = in[34]; gb.resid[0] = dbuf[0];
    gb.Cf[0] = (float*)d_out; gb.Cb[0] = (u16*)d_out; gb.osc[0] = 1.f;
    gb.A[1] = hbufB; gb.W[1] = in[33]; gb.bias[1] = in[34]; gb.resid[1] = dbuf[1];
    gb.Cf[1] = (float*)d_out + BLE; gb.Cb[1] = (u16*)d_out + BLE; gb.osc[1] = 1.f;
    k_gemmb<<<dim3(4, 64, 2), 256, 0, stream>>>(gb, 512, 512, 256, 256, 256, 1, 2, flagp);
  }
}